// Round 3
// baseline (1081.894 us; speedup 1.0000x reference)
//
#include <hip/hip_runtime.h>
#include <stdint.h>

#define NN 50000
#define NP 50048          // padded to 64 for the MFMA LSTM kernel
#define EE 400000
#define TT 7
#define NB3 3125          // NN/16
#define LN_EPS 1e-5f

typedef __attribute__((ext_vector_type(8))) short bf16x8;
typedef __attribute__((ext_vector_type(4))) float f32x4;

__device__ __forceinline__ float leaky01(float x){ return x > 0.f ? x : 0.01f*x; }
__device__ __forceinline__ float sigmoidf(float x){ return 1.f/(1.f+__expf(-x)); }
__device__ __forceinline__ float tanhfast(float x){ float e=__expf(2.f*x); return 1.f - 2.f/(e+1.f); }
__device__ __forceinline__ unsigned bf16rne(float f){
  unsigned u = __float_as_uint(f);
  return (u + 0x7fffu + ((u>>16)&1u)) >> 16;
}
__device__ __forceinline__ float bfu(unsigned u){ return __uint_as_float(u<<16); }

// ---------------- graph norm / CSR build ----------------
__global__ void k_init_deg(float* deg){
  int i = blockIdx.x*blockDim.x + threadIdx.x;
  if (i < NN) deg[i] = 1.0f;                // self-loop weight
}
__global__ void k_edge_count(const int* __restrict__ src, const int* __restrict__ dst,
                             const float* __restrict__ ew, float* deg, int* counts){
  int e = blockIdx.x*blockDim.x + threadIdx.x;
  if (e < EE){
    int d = dst[e];
    atomicAdd(&deg[d], ew[e]);
    atomicAdd(&counts[d], 1);
  }
}
__global__ void k_dinv(float* deg){
  int i = blockIdx.x*blockDim.x + threadIdx.x;
  if (i < NN) deg[i] = rsqrtf(deg[i]);      // deg >= 1 always
}
// hierarchical scan: per-block inclusive (196 blocks) -> top scan -> fixup
__global__ __launch_bounds__(256) void k_scan_blk(const int* __restrict__ counts,
                                                  int* locincl, int* bsum){
  int tid = threadIdx.x; int i = blockIdx.x*256 + tid;
  int v = (i < NN) ? counts[i] : 0;
  int lane = tid & 63;
  int val = v;
  #pragma unroll
  for (int off = 1; off < 64; off <<= 1){
    int u = __shfl_up(val, off, 64);
    if (lane >= off) val += u;
  }
  __shared__ int wsum[4];
  if (lane == 63) wsum[tid>>6] = val;
  __syncthreads();
  int w = tid >> 6, pre = 0;
  #pragma unroll
  for (int k = 0; k < 4; ++k) if (k < w) pre += wsum[k];
  int incl = val + pre;
  if (i < NN) locincl[i] = incl;
  if (tid == 255) bsum[blockIdx.x] = incl;
}
__global__ __launch_bounds__(256) void k_scan_top(const int* __restrict__ bsum, int* boff){
  int tid = threadIdx.x;
  int v = (tid < 196) ? bsum[tid] : 0;
  int lane = tid & 63;
  int val = v;
  #pragma unroll
  for (int off = 1; off < 64; off <<= 1){
    int u = __shfl_up(val, off, 64);
    if (lane >= off) val += u;
  }
  __shared__ int wsum[4];
  if (lane == 63) wsum[tid>>6] = val;
  __syncthreads();
  int w = tid >> 6, pre = 0;
  #pragma unroll
  for (int k = 0; k < 4; ++k) if (k < w) pre += wsum[k];
  if (tid < 196) boff[tid] = val + pre - v;   // exclusive prefix
}
__global__ __launch_bounds__(256) void k_scan_fix(const int* __restrict__ locincl,
        const int* __restrict__ boff, const int* __restrict__ counts,
        int* rowptr, int* cursor){
  int i = blockIdx.x*256 + threadIdx.x;
  if (i < NN){
    int r = locincl[i] + boff[blockIdx.x];
    rowptr[i+1] = r;
    cursor[i] = r - counts[i];
  }
  if (i == 0) rowptr[0] = 0;
}
__global__ void k_scatter(const int* __restrict__ src, const int* __restrict__ dst,
                          const float* __restrict__ ew, const float* __restrict__ dinv,
                          int* cursor, int* colsrc, float* enorm){
  int e = blockIdx.x*blockDim.x + threadIdx.x;
  if (e < EE){
    int s = src[e], d = dst[e];
    float nv = dinv[s]*ew[e]*dinv[d];
    int slot = atomicAdd(&cursor[d], 1);
    colsrc[slot] = s;
    enorm[slot] = nv;
  }
}

// ---------------- LSTM weight packing (B-fragment order) ----------------
__global__ void k_prep_wf(const float* __restrict__ Wih0, const float* __restrict__ Whh0,
                          const float* __restrict__ Wih1, const float* __restrict__ Whh1,
                          uint4* WF){
  int idx = blockIdx.x*blockDim.x + threadIdx.x;
  if (idx >= 8192) return;
  int L = idx >> 12;
  int r = idx & 4095;
  int lane = r & 63;
  int e = r >> 6;
  int which = e & 1;
  int cs = e >> 1;
  int s = cs & 1, ct = cs >> 1;
  int row = ct*16 + (lane & 15);
  int kb = s*32 + (lane >> 4)*8;
  const float* W = L ? (which ? Whh1 : Wih1) : (which ? Whh0 : Wih0);
  const float* p = W + row*64 + kb;
  uint4 v;
  v.x = bf16rne(p[0]) | (bf16rne(p[1])<<16);
  v.y = bf16rne(p[2]) | (bf16rne(p[3])<<16);
  v.z = bf16rne(p[4]) | (bf16rne(p[5])<<16);
  v.w = bf16rne(p[6]) | (bf16rne(p[7])<<16);
  WF[idx] = v;
}
__global__ void k_prep_bias(const float* bih0, const float* bhh0,
                            const float* bih1, const float* bhh1, float* BS){
  int j = threadIdx.x; int L = blockIdx.x;
  if (j < 256) BS[L*256+j] = L ? (bih1[j]+bhh1[j]) : (bih0[j]+bhh0[j]);
}

// ---------------- GCN ----------------
__global__ __launch_bounds__(256) void k_agg_x(const float* __restrict__ x,
        const float* __restrict__ dinv, const int* __restrict__ rowptr,
        const int* __restrict__ colsrc, const float* __restrict__ enorm,
        float* __restrict__ AX){
  int lane = threadIdx.x & 63, w = threadIdx.x >> 6;
  int i = blockIdx.x*4 + w;
  int beg = rowptr[i], end = rowptr[i+1];
  float di = dinv[i];
  float acc = 0.f;
  if (lane < 49) acc = di*di*x[(size_t)i*49 + lane];
  for (int s = beg; s < end; ++s){
    int cs = colsrc[s]; float wv = enorm[s];
    if (lane < 49) acc += wv * x[(size_t)cs*49 + lane];
  }
  if (lane < 49) AX[(size_t)i*49 + lane] = acc;
}
// Batched over t: H1 = leaky(AX_t @ Wg1 + bg1); Z2 = bf16(H1 @ Wg2).  16 nodes/block.
// Z2b layout: [node][t][64] bf16
__global__ __launch_bounds__(256) void k_gcn2_all(const float* __restrict__ AX,
        const float* __restrict__ Wg1, const float* __restrict__ bg1,
        const float* __restrict__ Wg2, ushort* __restrict__ Z2b){
  int t = blockIdx.x / NB3;
  int nb = blockIdx.x % NB3;
  __shared__ float sw1[7*64];
  __shared__ float sb1[64];
  __shared__ float sw2[64*64];
  __shared__ float sax[16*8];
  __shared__ __align__(16) float sr[16*64];
  int tid = threadIdx.x;
  const float4* w4 = (const float4*)Wg2;
  float4* sw4 = (float4*)sw2;
  #pragma unroll
  for (int i = 0; i < 4; ++i) sw4[tid + i*256] = w4[tid + i*256];
  for (int i = tid; i < 448; i += 256) sw1[i] = Wg1[i];
  if (tid < 64) sb1[tid] = bg1[tid];
  int base = nb*16;
  if (tid < 112){
    int n = tid / 7, k = tid % 7;
    sax[n*8 + k] = AX[(size_t)(base+n)*49 + t*7 + k];
  }
  __syncthreads();
  #pragma unroll
  for (int i = 0; i < 4; ++i){
    int idx = i*256 + tid;
    int n = idx >> 6, c = idx & 63;
    float acc = sb1[c];
    #pragma unroll
    for (int k = 0; k < 7; ++k) acc += sax[n*8+k]*sw1[k*64+c];
    sr[idx] = leaky01(acc);
  }
  __syncthreads();
  int c = tid & 63, w = tid >> 6;
  float a0=0.f, a1=0.f, a2=0.f, a3=0.f;
  const float* r = sr + w*256;
  for (int k = 0; k < 64; ++k){
    float wv = sw2[k*64+c];
    a0 += r[k]*wv; a1 += r[64+k]*wv; a2 += r[128+k]*wv; a3 += r[192+k]*wv;
  }
  size_t o = (size_t)(base + w*4)*448 + (size_t)t*64 + c;
  Z2b[o]      = (ushort)bf16rne(a0);
  Z2b[o+448]  = (ushort)bf16rne(a1);
  Z2b[o+896]  = (ushort)bf16rne(a2);
  Z2b[o+1344] = (ushort)bf16rne(a3);
}
// Batched aggregation + LN over all 7 t. One wave per node; lane = feature.
// XT layout: [t][NP][64] bf16
__global__ __launch_bounds__(256) void k_agg_ln_all(const ushort* __restrict__ Z2b,
        const float* __restrict__ dinv, const int* __restrict__ rowptr,
        const int* __restrict__ colsrc, const float* __restrict__ enorm,
        const float* __restrict__ bg2, const float* __restrict__ lng,
        const float* __restrict__ lnb, ushort* __restrict__ XT){
  int lane = threadIdx.x & 63, w = threadIdx.x >> 6;
  int i = blockIdx.x*4 + w;
  int beg = rowptr[i], end = rowptr[i+1];
  float di = dinv[i];
  float swt = di*di;
  float acc[7];
  const ushort* zi = Z2b + (size_t)i*448 + lane;
  #pragma unroll
  for (int t = 0; t < 7; ++t) acc[t] = swt * bfu(zi[t*64]);
  for (int s = beg; s < end; ++s){
    int cs = colsrc[s]; float wv = enorm[s];
    const ushort* zc = Z2b + (size_t)cs*448 + lane;
    #pragma unroll
    for (int t = 0; t < 7; ++t) acc[t] += wv * bfu(zc[t*64]);
  }
  float b2 = bg2[lane], gl = lng[lane], bl = lnb[lane];
  #pragma unroll
  for (int t = 0; t < 7; ++t){
    float a = leaky01(acc[t] + b2);
    float sum = a;
    #pragma unroll
    for (int off = 32; off >= 1; off >>= 1) sum += __shfl_xor(sum, off, 64);
    float mu = sum * (1.f/64.f);
    float d = a - mu;
    float vs = d*d;
    #pragma unroll
    for (int off = 32; off >= 1; off >>= 1) vs += __shfl_xor(vs, off, 64);
    float rs = rsqrtf(vs*(1.f/64.f) + LN_EPS);
    XT[(size_t)t*NP*64 + (size_t)i*64 + lane] = (ushort)bf16rne(d*rs*gl + bl);
  }
}

// ---------------- LSTM: one layer, ALL 7 timesteps, state in registers ----------------
// Wave = 32 nodes (2 m-tiles of 16). Block = 128 thr = 64 nodes. Grid = NP/64.
// mode 0: write h to outbuf[t][NP][64] every t (layer-0 -> XT1)
// mode 1: write h to outbuf[NP][64] only at t==6 (layer-1 final)
__global__ __launch_bounds__(128) void k_lstm_seq(const ushort* __restrict__ xin,
        ushort* __restrict__ outbuf, const uint4* __restrict__ WF,
        const float* __restrict__ BS, int mode){
  __shared__ __align__(16) ushort tr[2][32][72];   // pad 72 kills b128 bank conflicts
  int lane = threadIdx.x & 63, wave = threadIdx.x >> 6;
  int base = blockIdx.x*64 + wave*32;
  int col = lane & 15, quad = lane >> 4;
  f32x4 cst[2][4];
  #pragma unroll
  for (int mt = 0; mt < 2; ++mt)
    #pragma unroll
    for (int cp = 0; cp < 4; ++cp) cst[mt][cp] = (f32x4){0.f,0.f,0.f,0.f};
  bf16x8 hfr[2][2];
  #pragma unroll
  for (int mt = 0; mt < 2; ++mt)
    #pragma unroll
    for (int s = 0; s < 2; ++s) hfr[mt][s] = (bf16x8){0,0,0,0,0,0,0,0};

  for (int t = 0; t < 7; ++t){
    bf16x8 ax[2][2];
    #pragma unroll
    for (int mt = 0; mt < 2; ++mt)
      #pragma unroll
      for (int s = 0; s < 2; ++s)
        ax[mt][s] = *(const bf16x8*)(xin + (size_t)t*NP*64
                        + (size_t)(base + mt*16 + col)*64 + s*32 + quad*8);
    f32x4 acc[2][16];
    #pragma unroll
    for (int ct = 0; ct < 16; ++ct){
      float b = BS[ct*16 + col];
      acc[0][ct] = (f32x4){b,b,b,b};
      acc[1][ct] = (f32x4){b,b,b,b};
    }
    #pragma unroll 4
    for (int ct = 0; ct < 16; ++ct){
      #pragma unroll
      for (int s = 0; s < 2; ++s){
        uint4 wi = WF[((ct*2+s)*2+0)*64 + lane];
        uint4 wh = WF[((ct*2+s)*2+1)*64 + lane];
        bf16x8 bwi = *(bf16x8*)&wi;
        bf16x8 bwh = *(bf16x8*)&wh;
        #pragma unroll
        for (int mt = 0; mt < 2; ++mt){
          acc[mt][ct] = __builtin_amdgcn_mfma_f32_16x16x32_bf16(ax[mt][s], bwi, acc[mt][ct], 0,0,0);
          acc[mt][ct] = __builtin_amdgcn_mfma_f32_16x16x32_bf16(hfr[mt][s], bwh, acc[mt][ct], 0,0,0);
        }
      }
    }
    // epilogue: gates, cell update, h -> LDS (for C->A transpose) + optional global store
    #pragma unroll
    for (int mt = 0; mt < 2; ++mt){
      #pragma unroll
      for (int cp = 0; cp < 4; ++cp){
        #pragma unroll
        for (int r = 0; r < 4; ++r){
          float ig = sigmoidf(acc[mt][cp][r]);
          float fg = sigmoidf(acc[mt][cp+4][r]);
          float gg = tanhfast(acc[mt][cp+8][r]);
          float og = sigmoidf(acc[mt][cp+12][r]);
          float cn = fg*cst[mt][cp][r] + ig*gg;
          cst[mt][cp][r] = cn;
          ushort hb = (ushort)bf16rne(og*tanhfast(cn));
          int node = mt*16 + quad*4 + r;
          tr[wave][node][cp*16 + col] = hb;
          if (mode == 0)
            outbuf[(size_t)t*NP*64 + (size_t)(base+node)*64 + cp*16 + col] = hb;
          else if (t == 6)
            outbuf[(size_t)(base+node)*64 + cp*16 + col] = hb;
        }
      }
    }
    __syncthreads();
    #pragma unroll
    for (int mt = 0; mt < 2; ++mt)
      #pragma unroll
      for (int s = 0; s < 2; ++s)
        hfr[mt][s] = *(const bf16x8*)&tr[wave][mt*16 + col][s*32 + quad*8];
    __syncthreads();
  }
}

// ---------------- heads ----------------
__global__ __launch_bounds__(256) void k_heads(const ushort* __restrict__ f,
        const float* __restrict__ Wm1, const float* __restrict__ bm1,
        const float* __restrict__ Wm2, const float* __restrict__ bm2,
        const float* __restrict__ Wd1, const float* __restrict__ bd1,
        const float* __restrict__ Wd2, const float* __restrict__ bd2,
        float* __restrict__ out){
  __shared__ float swm1[64*32];
  __shared__ float swm2[32*4];
  __shared__ float swd1[64*16];
  __shared__ float swd2[16*4];
  __shared__ float sbm1[32], sbm2[4], sbd1[16], sbd2[4];
  int tid = threadIdx.x;
  for (int i = tid; i < 2048; i += 256) swm1[i] = Wm1[i];
  for (int i = tid; i < 1024; i += 256) swd1[i] = Wd1[i];
  if (tid < 128) swm2[tid] = Wm2[tid];
  if (tid < 64) swd2[tid] = Wd2[tid];
  if (tid < 32) sbm1[tid] = bm1[tid];
  if (tid < 16) sbd1[tid] = bd1[tid];
  if (tid < 4){ sbm2[tid] = bm2[tid]; sbd2[tid] = bd2[tid]; }
  __syncthreads();
  int n = blockIdx.x*256 + tid;
  if (n >= NN) return;
  float fr[64];
  const uint* f2 = (const uint*)(f + (size_t)n*64);
  #pragma unroll
  for (int i = 0; i < 32; ++i){ uint u = f2[i]; fr[2*i] = bfu(u & 0xffffu); fr[2*i+1] = __uint_as_float(u & 0xffff0000u); }
  float m1[32];
  #pragma unroll
  for (int c2 = 0; c2 < 32; ++c2) m1[c2] = sbm1[c2];
  for (int k = 0; k < 64; ++k){
    float fv = fr[k];
    #pragma unroll
    for (int c2 = 0; c2 < 32; ++c2) m1[c2] += fv*swm1[k*32+c2];
  }
  #pragma unroll
  for (int c2 = 0; c2 < 32; ++c2) m1[c2] = leaky01(m1[c2]);
  float mo[4];
  #pragma unroll
  for (int o = 0; o < 4; ++o) mo[o] = sbm2[o];
  for (int c2 = 0; c2 < 32; ++c2){
    float mv = m1[c2];
    #pragma unroll
    for (int o = 0; o < 4; ++o) mo[o] += mv*swm2[c2*4+o];
  }
  float d1[16];
  #pragma unroll
  for (int c2 = 0; c2 < 16; ++c2) d1[c2] = sbd1[c2];
  for (int k = 0; k < 64; ++k){
    float fv = fr[k];
    #pragma unroll
    for (int c2 = 0; c2 < 16; ++c2) d1[c2] += fv*swd1[k*16+c2];
  }
  #pragma unroll
  for (int c2 = 0; c2 < 16; ++c2) d1[c2] = fmaxf(d1[c2], 0.f);
  float dv[4];
  #pragma unroll
  for (int o = 0; o < 4; ++o) dv[o] = sbd2[o];
  for (int c2 = 0; c2 < 16; ++c2){
    float xv = d1[c2];
    #pragma unroll
    for (int o = 0; o < 4; ++o) dv[o] += xv*swd2[c2*4+o];
  }
  float4* o4 = (float4*)out;
  o4[n] = make_float4(fmaxf(mo[0],0.f)+1e-4f, fmaxf(mo[1],0.f)+1e-4f,
                      fmaxf(mo[2],0.f)+1e-4f, fmaxf(mo[3],0.f)+1e-4f);
  o4[NN + n] = make_float4(dv[0], dv[1], dv[2], dv[3]);
}

extern "C" void kernel_launch(void* const* d_in, const int* in_sizes, int n_in,
                              void* d_out, int out_size, void* d_ws, size_t ws_size,
                              hipStream_t stream){
  const float* x    = (const float*)d_in[0];
  const int*   eidx = (const int*)d_in[1];
  const float* ew   = (const float*)d_in[2];
  const float* Wg1  = (const float*)d_in[3];
  const float* bg1  = (const float*)d_in[4];
  const float* Wg2  = (const float*)d_in[5];
  const float* bg2  = (const float*)d_in[6];
  const float* lng  = (const float*)d_in[7];
  const float* lnb  = (const float*)d_in[8];
  const float* Wih0 = (const float*)d_in[9];
  const float* Whh0 = (const float*)d_in[10];
  const float* bih0 = (const float*)d_in[11];
  const float* bhh0 = (const float*)d_in[12];
  const float* Wih1 = (const float*)d_in[13];
  const float* Whh1 = (const float*)d_in[14];
  const float* bih1 = (const float*)d_in[15];
  const float* bhh1 = (const float*)d_in[16];
  const float* Wm1  = (const float*)d_in[17];
  const float* bm1  = (const float*)d_in[18];
  const float* Wm2  = (const float*)d_in[19];
  const float* bm2  = (const float*)d_in[20];
  const float* Wd1  = (const float*)d_in[21];
  const float* bd1  = (const float*)d_in[22];
  const float* Wd2  = (const float*)d_in[23];
  const float* bd2  = (const float*)d_in[24];
  const int* src = eidx;
  const int* dst = eidx + EE;
  float* out = (float*)d_out;

  char* p = (char*)d_ws;
  auto alloc = [&](size_t bytes)->char*{ char* r = p; p += (bytes + 255) & ~(size_t)255; return r; };
  // persistent-through-call buffers
  float*  deg     = (float*)alloc((size_t)NN*4);       // becomes dinv
  float*  enorm   = (float*)alloc((size_t)EE*4);
  int*    counts  = (int*)  alloc((size_t)NN*4);
  int*    rowptr  = (int*)  alloc((size_t)(NN+1)*4);
  int*    cursor  = (int*)  alloc((size_t)NN*4);
  int*    colsrc  = (int*)  alloc((size_t)EE*4);
  int*    locincl = (int*)  alloc((size_t)NN*4);
  int*    bsum    = (int*)  alloc((size_t)256*4);
  int*    boff    = (int*)  alloc((size_t)256*4);
  uint4*  WF      = (uint4*)alloc((size_t)2*4096*16);
  float*  BS      = (float*)alloc((size_t)2*256*4);
  ushort* h1b     = (ushort*)alloc((size_t)NP*64*2);
  ushort* XT      = (ushort*)alloc((size_t)TT*NP*64*2);
  // phase buffers; XT1 aliases AX+Z2b (both dead before XT1 is written)
  char*   phase   = alloc((size_t)NN*49*4 + (size_t)NN*448*2);
  float*  AX      = (float*)phase;
  ushort* Z2b     = (ushort*)(phase + (size_t)NN*49*4);
  ushort* XT1     = (ushort*)phase;    // needs TT*NP*64*2 = 44.8MB <= 54.4MB phase

  hipMemsetAsync(counts, 0, (size_t)NN*4, stream);
  k_init_deg<<<(NN+255)/256, 256, 0, stream>>>(deg);
  k_edge_count<<<(EE+255)/256, 256, 0, stream>>>(src, dst, ew, deg, counts);
  k_dinv<<<(NN+255)/256, 256, 0, stream>>>(deg);
  k_scan_blk<<<196, 256, 0, stream>>>(counts, locincl, bsum);
  k_scan_top<<<1, 256, 0, stream>>>(bsum, boff);
  k_scan_fix<<<196, 256, 0, stream>>>(locincl, boff, counts, rowptr, cursor);
  k_scatter<<<(EE+255)/256, 256, 0, stream>>>(src, dst, ew, deg, cursor, colsrc, enorm);
  k_prep_wf<<<32, 256, 0, stream>>>(Wih0, Whh0, Wih1, Whh1, WF);
  k_prep_bias<<<2, 256, 0, stream>>>(bih0, bhh0, bih1, bhh1, BS);
  k_agg_x<<<NN/4, 256, 0, stream>>>(x, deg, rowptr, colsrc, enorm, AX);

  k_gcn2_all<<<TT*NB3, 256, 0, stream>>>(AX, Wg1, bg1, Wg2, Z2b);
  k_agg_ln_all<<<NN/4, 256, 0, stream>>>(Z2b, deg, rowptr, colsrc, enorm, bg2, lng, lnb, XT);
  k_lstm_seq<<<NP/64, 128, 0, stream>>>(XT,  XT1, WF,        BS,       0);
  k_lstm_seq<<<NP/64, 128, 0, stream>>>(XT1, h1b, WF + 4096, BS + 256, 1);
  k_heads<<<(NN+255)/256, 256, 0, stream>>>(h1b, Wm1, bm1, Wm2, bm2, Wd1, bd1, Wd2, bd2, out);
}

// Round 4
// 585.347 us; speedup vs baseline: 1.8483x; 1.8483x over previous
//
#include <hip/hip_runtime.h>
#include <stdint.h>

#define NN 50000
#define NP 50048          // padded to 64 for the MFMA LSTM kernel
#define EE 400000
#define TT 7
#define NB3 3125          // NN/16
#define LN_EPS 1e-5f

typedef __attribute__((ext_vector_type(8))) short bf16x8;
typedef __attribute__((ext_vector_type(4))) float f32x4;

__device__ __forceinline__ float leaky01(float x){ return x > 0.f ? x : 0.01f*x; }
__device__ __forceinline__ float sigmoidf(float x){ return 1.f/(1.f+__expf(-x)); }
__device__ __forceinline__ float tanhfast(float x){ float e=__expf(2.f*x); return 1.f - 2.f/(e+1.f); }
__device__ __forceinline__ unsigned bf16rne(float f){
  unsigned u = __float_as_uint(f);
  return (u + 0x7fffu + ((u>>16)&1u)) >> 16;
}
__device__ __forceinline__ float bfu(unsigned u){ return __uint_as_float(u<<16); }

// ---------------- graph norm / CSR build ----------------
__global__ void k_init_deg(float* deg){
  int i = blockIdx.x*blockDim.x + threadIdx.x;
  if (i < NN) deg[i] = 1.0f;                // self-loop weight
}
__global__ void k_edge_count(const int* __restrict__ src, const int* __restrict__ dst,
                             const float* __restrict__ ew, float* deg, int* counts){
  int e = blockIdx.x*blockDim.x + threadIdx.x;
  if (e < EE){
    int d = dst[e];
    atomicAdd(&deg[d], ew[e]);
    atomicAdd(&counts[d], 1);
  }
}
__global__ void k_dinv(float* deg){
  int i = blockIdx.x*blockDim.x + threadIdx.x;
  if (i < NN) deg[i] = rsqrtf(deg[i]);      // deg >= 1 always
}
// hierarchical scan: per-block inclusive (196 blocks) -> top scan -> fixup
__global__ __launch_bounds__(256) void k_scan_blk(const int* __restrict__ counts,
                                                  int* locincl, int* bsum){
  int tid = threadIdx.x; int i = blockIdx.x*256 + tid;
  int v = (i < NN) ? counts[i] : 0;
  int lane = tid & 63;
  int val = v;
  #pragma unroll
  for (int off = 1; off < 64; off <<= 1){
    int u = __shfl_up(val, off, 64);
    if (lane >= off) val += u;
  }
  __shared__ int wsum[4];
  if (lane == 63) wsum[tid>>6] = val;
  __syncthreads();
  int w = tid >> 6, pre = 0;
  #pragma unroll
  for (int k = 0; k < 4; ++k) if (k < w) pre += wsum[k];
  int incl = val + pre;
  if (i < NN) locincl[i] = incl;
  if (tid == 255) bsum[blockIdx.x] = incl;
}
__global__ __launch_bounds__(256) void k_scan_top(const int* __restrict__ bsum, int* boff){
  int tid = threadIdx.x;
  int v = (tid < 196) ? bsum[tid] : 0;
  int lane = tid & 63;
  int val = v;
  #pragma unroll
  for (int off = 1; off < 64; off <<= 1){
    int u = __shfl_up(val, off, 64);
    if (lane >= off) val += u;
  }
  __shared__ int wsum[4];
  if (lane == 63) wsum[tid>>6] = val;
  __syncthreads();
  int w = tid >> 6, pre = 0;
  #pragma unroll
  for (int k = 0; k < 4; ++k) if (k < w) pre += wsum[k];
  if (tid < 196) boff[tid] = val + pre - v;   // exclusive prefix
}
__global__ __launch_bounds__(256) void k_scan_fix(const int* __restrict__ locincl,
        const int* __restrict__ boff, const int* __restrict__ counts,
        int* rowptr, int* cursor){
  int i = blockIdx.x*256 + threadIdx.x;
  if (i < NN){
    int r = locincl[i] + boff[blockIdx.x];
    rowptr[i+1] = r;
    cursor[i] = r - counts[i];
  }
  if (i == 0) rowptr[0] = 0;
}
__global__ void k_scatter(const int* __restrict__ src, const int* __restrict__ dst,
                          const float* __restrict__ ew, const float* __restrict__ dinv,
                          int* cursor, int* colsrc, float* enorm){
  int e = blockIdx.x*blockDim.x + threadIdx.x;
  if (e < EE){
    int s = src[e], d = dst[e];
    float nv = dinv[s]*ew[e]*dinv[d];
    int slot = atomicAdd(&cursor[d], 1);
    colsrc[slot] = s;
    enorm[slot] = nv;
  }
}

// ---------------- LSTM weight packing (B-fragment order) ----------------
__global__ void k_prep_wf(const float* __restrict__ Wih0, const float* __restrict__ Whh0,
                          const float* __restrict__ Wih1, const float* __restrict__ Whh1,
                          uint4* WF){
  int idx = blockIdx.x*blockDim.x + threadIdx.x;
  if (idx >= 8192) return;
  int L = idx >> 12;
  int r = idx & 4095;
  int lane = r & 63;
  int e = r >> 6;
  int which = e & 1;
  int cs = e >> 1;
  int s = cs & 1, ct = cs >> 1;
  int row = ct*16 + (lane & 15);
  int kb = s*32 + (lane >> 4)*8;
  const float* W = L ? (which ? Whh1 : Wih1) : (which ? Whh0 : Wih0);
  const float* p = W + row*64 + kb;
  uint4 v;
  v.x = bf16rne(p[0]) | (bf16rne(p[1])<<16);
  v.y = bf16rne(p[2]) | (bf16rne(p[3])<<16);
  v.z = bf16rne(p[4]) | (bf16rne(p[5])<<16);
  v.w = bf16rne(p[6]) | (bf16rne(p[7])<<16);
  WF[idx] = v;
}
__global__ void k_prep_bias(const float* bih0, const float* bhh0,
                            const float* bih1, const float* bhh1, float* BS){
  int j = threadIdx.x; int L = blockIdx.x;
  if (j < 256) BS[L*256+j] = L ? (bih1[j]+bhh1[j]) : (bih0[j]+bhh0[j]);
}

// ---------------- GCN ----------------
__global__ __launch_bounds__(256) void k_agg_x(const float* __restrict__ x,
        const float* __restrict__ dinv, const int* __restrict__ rowptr,
        const int* __restrict__ colsrc, const float* __restrict__ enorm,
        float* __restrict__ AX){
  int lane = threadIdx.x & 63, w = threadIdx.x >> 6;
  int i = blockIdx.x*4 + w;
  int beg = rowptr[i], end = rowptr[i+1];
  float di = dinv[i];
  float acc = 0.f;
  if (lane < 49) acc = di*di*x[(size_t)i*49 + lane];
  for (int s = beg; s < end; ++s){
    int cs = colsrc[s]; float wv = enorm[s];
    if (lane < 49) acc += wv * x[(size_t)cs*49 + lane];
  }
  if (lane < 49) AX[(size_t)i*49 + lane] = acc;
}
// Batched over t: H1 = leaky(AX_t @ Wg1 + bg1); Z2 = bf16(H1 @ Wg2).  16 nodes/block.
// Z2b layout: [node][t][64] bf16
__global__ __launch_bounds__(256) void k_gcn2_all(const float* __restrict__ AX,
        const float* __restrict__ Wg1, const float* __restrict__ bg1,
        const float* __restrict__ Wg2, ushort* __restrict__ Z2b){
  int t = blockIdx.x / NB3;
  int nb = blockIdx.x % NB3;
  __shared__ float sw1[7*64];
  __shared__ float sb1[64];
  __shared__ float sw2[64*64];
  __shared__ float sax[16*8];
  __shared__ __align__(16) float sr[16*64];
  int tid = threadIdx.x;
  const float4* w4 = (const float4*)Wg2;
  float4* sw4 = (float4*)sw2;
  #pragma unroll
  for (int i = 0; i < 4; ++i) sw4[tid + i*256] = w4[tid + i*256];
  for (int i = tid; i < 448; i += 256) sw1[i] = Wg1[i];
  if (tid < 64) sb1[tid] = bg1[tid];
  int base = nb*16;
  if (tid < 112){
    int n = tid / 7, k = tid % 7;
    sax[n*8 + k] = AX[(size_t)(base+n)*49 + t*7 + k];
  }
  __syncthreads();
  #pragma unroll
  for (int i = 0; i < 4; ++i){
    int idx = i*256 + tid;
    int n = idx >> 6, c = idx & 63;
    float acc = sb1[c];
    #pragma unroll
    for (int k = 0; k < 7; ++k) acc += sax[n*8+k]*sw1[k*64+c];
    sr[idx] = leaky01(acc);
  }
  __syncthreads();
  int c = tid & 63, w = tid >> 6;
  float a0=0.f, a1=0.f, a2=0.f, a3=0.f;
  const float* r = sr + w*256;
  for (int k = 0; k < 64; ++k){
    float wv = sw2[k*64+c];
    a0 += r[k]*wv; a1 += r[64+k]*wv; a2 += r[128+k]*wv; a3 += r[192+k]*wv;
  }
  size_t o = (size_t)(base + w*4)*448 + (size_t)t*64 + c;
  Z2b[o]      = (ushort)bf16rne(a0);
  Z2b[o+448]  = (ushort)bf16rne(a1);
  Z2b[o+896]  = (ushort)bf16rne(a2);
  Z2b[o+1344] = (ushort)bf16rne(a3);
}
// Batched aggregation + LN over all 7 t. One wave per node; lane = feature.
// XT layout: [t][NP][64] bf16
__global__ __launch_bounds__(256) void k_agg_ln_all(const ushort* __restrict__ Z2b,
        const float* __restrict__ dinv, const int* __restrict__ rowptr,
        const int* __restrict__ colsrc, const float* __restrict__ enorm,
        const float* __restrict__ bg2, const float* __restrict__ lng,
        const float* __restrict__ lnb, ushort* __restrict__ XT){
  int lane = threadIdx.x & 63, w = threadIdx.x >> 6;
  int i = blockIdx.x*4 + w;
  int beg = rowptr[i], end = rowptr[i+1];
  float di = dinv[i];
  float swt = di*di;
  float acc[7];
  const ushort* zi = Z2b + (size_t)i*448 + lane;
  #pragma unroll
  for (int t = 0; t < 7; ++t) acc[t] = swt * bfu(zi[t*64]);
  for (int s = beg; s < end; ++s){
    int cs = colsrc[s]; float wv = enorm[s];
    const ushort* zc = Z2b + (size_t)cs*448 + lane;
    #pragma unroll
    for (int t = 0; t < 7; ++t) acc[t] += wv * bfu(zc[t*64]);
  }
  float b2 = bg2[lane], gl = lng[lane], bl = lnb[lane];
  #pragma unroll
  for (int t = 0; t < 7; ++t){
    float a = leaky01(acc[t] + b2);
    float sum = a;
    #pragma unroll
    for (int off = 32; off >= 1; off >>= 1) sum += __shfl_xor(sum, off, 64);
    float mu = sum * (1.f/64.f);
    float d = a - mu;
    float vs = d*d;
    #pragma unroll
    for (int off = 32; off >= 1; off >>= 1) vs += __shfl_xor(vs, off, 64);
    float rs = rsqrtf(vs*(1.f/64.f) + LN_EPS);
    XT[(size_t)t*NP*64 + (size_t)i*64 + lane] = (ushort)bf16rne(d*rs*gl + bl);
  }
}

// ---------------- LSTM: one layer, ALL 7 timesteps, state in registers ----------------
// Block = 256 thr = 4 waves, covers 32 nodes (2 m-tiles of 16). Wave `cp` owns acc
// tiles {cp, cp+4, cp+8, cp+12} = complete i/f/g/o gates for units 16cp..16cp+16.
// acc[2][4] = 32 VGPRs -> no spills (round-3 version spilled ~500 MB/dispatch).
// h exchanged via LDS transpose buffer; output stored as contiguous b128.
// mode 0: write h to outbuf[t][NP][64] every t; mode 1: only t==6 to outbuf[NP][64].
__global__ __launch_bounds__(256) void k_lstm_seq(const ushort* __restrict__ xin,
        ushort* __restrict__ outbuf, const uint4* __restrict__ WF,
        const float* __restrict__ BS, int mode){
  __shared__ __align__(16) ushort tr[32][72];   // stride 144 B = 9*16 -> b128-aligned rows
  int tid = threadIdx.x;
  int lane = tid & 63, cp = tid >> 6;
  int base = blockIdx.x*32;
  int col = lane & 15, quad = lane >> 4;
  f32x4 cst[2];
  cst[0] = (f32x4){0.f,0.f,0.f,0.f};
  cst[1] = (f32x4){0.f,0.f,0.f,0.f};
  bf16x8 hfr[2][2];
  #pragma unroll
  for (int mt = 0; mt < 2; ++mt)
    #pragma unroll
    for (int s = 0; s < 2; ++s) hfr[mt][s] = (bf16x8){0,0,0,0,0,0,0,0};
  float bias[4];
  #pragma unroll
  for (int g = 0; g < 4; ++g) bias[g] = BS[(cp + 4*g)*16 + col];

  for (int t = 0; t < 7; ++t){
    bf16x8 ax[2][2];
    #pragma unroll
    for (int mt = 0; mt < 2; ++mt)
      #pragma unroll
      for (int s = 0; s < 2; ++s)
        ax[mt][s] = *(const bf16x8*)(xin + (size_t)t*NP*64
                        + (size_t)(base + mt*16 + col)*64 + s*32 + quad*8);
    f32x4 acc[2][4];
    #pragma unroll
    for (int g = 0; g < 4; ++g){
      float b = bias[g];
      acc[0][g] = (f32x4){b,b,b,b};
      acc[1][g] = (f32x4){b,b,b,b};
    }
    #pragma unroll
    for (int g = 0; g < 4; ++g){
      int ct = cp + 4*g;
      #pragma unroll
      for (int s = 0; s < 2; ++s){
        uint4 wi = WF[((ct*2+s)*2+0)*64 + lane];
        uint4 wh = WF[((ct*2+s)*2+1)*64 + lane];
        bf16x8 bwi = *(bf16x8*)&wi;
        bf16x8 bwh = *(bf16x8*)&wh;
        #pragma unroll
        for (int mt = 0; mt < 2; ++mt){
          acc[mt][g] = __builtin_amdgcn_mfma_f32_16x16x32_bf16(ax[mt][s], bwi, acc[mt][g], 0,0,0);
          acc[mt][g] = __builtin_amdgcn_mfma_f32_16x16x32_bf16(hfr[mt][s], bwh, acc[mt][g], 0,0,0);
        }
      }
    }
    // epilogue: complete gates in-lane for units u = 16cp+col, rows quad*4+r
    #pragma unroll
    for (int mt = 0; mt < 2; ++mt){
      #pragma unroll
      for (int r = 0; r < 4; ++r){
        float ig = sigmoidf(acc[mt][0][r]);
        float fg = sigmoidf(acc[mt][1][r]);
        float gg = tanhfast(acc[mt][2][r]);
        float og = sigmoidf(acc[mt][3][r]);
        float cn = fg*cst[mt][r] + ig*gg;
        cst[mt][r] = cn;
        tr[mt*16 + quad*4 + r][cp*16 + col] = (ushort)bf16rne(og*tanhfast(cn));
      }
    }
    __syncthreads();
    #pragma unroll
    for (int mt = 0; mt < 2; ++mt)
      #pragma unroll
      for (int s = 0; s < 2; ++s)
        hfr[mt][s] = *(const bf16x8*)&tr[mt*16 + col][s*32 + quad*8];
    if (mode == 0 || t == 6){
      int n2 = tid >> 3, off = (tid & 7)*8;          // 256 threads = 32 nodes x 4 chunks
      uint4 v = *(const uint4*)&tr[n2][off];
      size_t o = (mode == 0) ? ((size_t)t*NP*64 + (size_t)(base+n2)*64 + off)
                             : ((size_t)(base+n2)*64 + off);
      *(uint4*)(outbuf + o) = v;
    }
    __syncthreads();
  }
}

// ---------------- heads ----------------
__global__ __launch_bounds__(256) void k_heads(const ushort* __restrict__ f,
        const float* __restrict__ Wm1, const float* __restrict__ bm1,
        const float* __restrict__ Wm2, const float* __restrict__ bm2,
        const float* __restrict__ Wd1, const float* __restrict__ bd1,
        const float* __restrict__ Wd2, const float* __restrict__ bd2,
        float* __restrict__ out){
  __shared__ float swm1[64*32];
  __shared__ float swm2[32*4];
  __shared__ float swd1[64*16];
  __shared__ float swd2[16*4];
  __shared__ float sbm1[32], sbm2[4], sbd1[16], sbd2[4];
  int tid = threadIdx.x;
  for (int i = tid; i < 2048; i += 256) swm1[i] = Wm1[i];
  for (int i = tid; i < 1024; i += 256) swd1[i] = Wd1[i];
  if (tid < 128) swm2[tid] = Wm2[tid];
  if (tid < 64) swd2[tid] = Wd2[tid];
  if (tid < 32) sbm1[tid] = bm1[tid];
  if (tid < 16) sbd1[tid] = bd1[tid];
  if (tid < 4){ sbm2[tid] = bm2[tid]; sbd2[tid] = bd2[tid]; }
  __syncthreads();
  int n = blockIdx.x*256 + tid;
  if (n >= NN) return;
  float fr[64];
  const uint* f2 = (const uint*)(f + (size_t)n*64);
  #pragma unroll
  for (int i = 0; i < 32; ++i){ uint u = f2[i]; fr[2*i] = bfu(u & 0xffffu); fr[2*i+1] = __uint_as_float(u & 0xffff0000u); }
  float m1[32];
  #pragma unroll
  for (int c2 = 0; c2 < 32; ++c2) m1[c2] = sbm1[c2];
  for (int k = 0; k < 64; ++k){
    float fv = fr[k];
    #pragma unroll
    for (int c2 = 0; c2 < 32; ++c2) m1[c2] += fv*swm1[k*32+c2];
  }
  #pragma unroll
  for (int c2 = 0; c2 < 32; ++c2) m1[c2] = leaky01(m1[c2]);
  float mo[4];
  #pragma unroll
  for (int o = 0; o < 4; ++o) mo[o] = sbm2[o];
  for (int c2 = 0; c2 < 32; ++c2){
    float mv = m1[c2];
    #pragma unroll
    for (int o = 0; o < 4; ++o) mo[o] += mv*swm2[c2*4+o];
  }
  float d1[16];
  #pragma unroll
  for (int c2 = 0; c2 < 16; ++c2) d1[c2] = sbd1[c2];
  for (int k = 0; k < 64; ++k){
    float fv = fr[k];
    #pragma unroll
    for (int c2 = 0; c2 < 16; ++c2) d1[c2] += fv*swd1[k*16+c2];
  }
  #pragma unroll
  for (int c2 = 0; c2 < 16; ++c2) d1[c2] = fmaxf(d1[c2], 0.f);
  float dv[4];
  #pragma unroll
  for (int o = 0; o < 4; ++o) dv[o] = sbd2[o];
  for (int c2 = 0; c2 < 16; ++c2){
    float xv = d1[c2];
    #pragma unroll
    for (int o = 0; o < 4; ++o) dv[o] += xv*swd2[c2*4+o];
  }
  float4* o4 = (float4*)out;
  o4[n] = make_float4(fmaxf(mo[0],0.f)+1e-4f, fmaxf(mo[1],0.f)+1e-4f,
                      fmaxf(mo[2],0.f)+1e-4f, fmaxf(mo[3],0.f)+1e-4f);
  o4[NN + n] = make_float4(dv[0], dv[1], dv[2], dv[3]);
}

extern "C" void kernel_launch(void* const* d_in, const int* in_sizes, int n_in,
                              void* d_out, int out_size, void* d_ws, size_t ws_size,
                              hipStream_t stream){
  const float* x    = (const float*)d_in[0];
  const int*   eidx = (const int*)d_in[1];
  const float* ew   = (const float*)d_in[2];
  const float* Wg1  = (const float*)d_in[3];
  const float* bg1  = (const float*)d_in[4];
  const float* Wg2  = (const float*)d_in[5];
  const float* bg2  = (const float*)d_in[6];
  const float* lng  = (const float*)d_in[7];
  const float* lnb  = (const float*)d_in[8];
  const float* Wih0 = (const float*)d_in[9];
  const float* Whh0 = (const float*)d_in[10];
  const float* bih0 = (const float*)d_in[11];
  const float* bhh0 = (const float*)d_in[12];
  const float* Wih1 = (const float*)d_in[13];
  const float* Whh1 = (const float*)d_in[14];
  const float* bih1 = (const float*)d_in[15];
  const float* bhh1 = (const float*)d_in[16];
  const float* Wm1  = (const float*)d_in[17];
  const float* bm1  = (const float*)d_in[18];
  const float* Wm2  = (const float*)d_in[19];
  const float* bm2  = (const float*)d_in[20];
  const float* Wd1  = (const float*)d_in[21];
  const float* bd1  = (const float*)d_in[22];
  const float* Wd2  = (const float*)d_in[23];
  const float* bd2  = (const float*)d_in[24];
  const int* src = eidx;
  const int* dst = eidx + EE;
  float* out = (float*)d_out;

  char* p = (char*)d_ws;
  auto alloc = [&](size_t bytes)->char*{ char* r = p; p += (bytes + 255) & ~(size_t)255; return r; };
  // persistent-through-call buffers
  float*  deg     = (float*)alloc((size_t)NN*4);       // becomes dinv
  float*  enorm   = (float*)alloc((size_t)EE*4);
  int*    counts  = (int*)  alloc((size_t)NN*4);
  int*    rowptr  = (int*)  alloc((size_t)(NN+1)*4);
  int*    cursor  = (int*)  alloc((size_t)NN*4);
  int*    colsrc  = (int*)  alloc((size_t)EE*4);
  int*    locincl = (int*)  alloc((size_t)NN*4);
  int*    bsum    = (int*)  alloc((size_t)256*4);
  int*    boff    = (int*)  alloc((size_t)256*4);
  uint4*  WF      = (uint4*)alloc((size_t)2*4096*16);
  float*  BS      = (float*)alloc((size_t)2*256*4);
  ushort* h1b     = (ushort*)alloc((size_t)NP*64*2);
  ushort* XT      = (ushort*)alloc((size_t)TT*NP*64*2);
  // phase buffers; XT1 aliases AX+Z2b (both dead before XT1 is written)
  char*   phase   = alloc((size_t)NN*49*4 + (size_t)NN*448*2);
  float*  AX      = (float*)phase;
  ushort* Z2b     = (ushort*)(phase + (size_t)NN*49*4);
  ushort* XT1     = (ushort*)phase;    // needs TT*NP*64*2 = 44.8MB <= 54.4MB phase

  hipMemsetAsync(counts, 0, (size_t)NN*4, stream);
  k_init_deg<<<(NN+255)/256, 256, 0, stream>>>(deg);
  k_edge_count<<<(EE+255)/256, 256, 0, stream>>>(src, dst, ew, deg, counts);
  k_dinv<<<(NN+255)/256, 256, 0, stream>>>(deg);
  k_scan_blk<<<196, 256, 0, stream>>>(counts, locincl, bsum);
  k_scan_top<<<1, 256, 0, stream>>>(bsum, boff);
  k_scan_fix<<<196, 256, 0, stream>>>(locincl, boff, counts, rowptr, cursor);
  k_scatter<<<(EE+255)/256, 256, 0, stream>>>(src, dst, ew, deg, cursor, colsrc, enorm);
  k_prep_wf<<<32, 256, 0, stream>>>(Wih0, Whh0, Wih1, Whh1, WF);
  k_prep_bias<<<2, 256, 0, stream>>>(bih0, bhh0, bih1, bhh1, BS);
  k_agg_x<<<NN/4, 256, 0, stream>>>(x, deg, rowptr, colsrc, enorm, AX);

  k_gcn2_all<<<TT*NB3, 256, 0, stream>>>(AX, Wg1, bg1, Wg2, Z2b);
  k_agg_ln_all<<<NN/4, 256, 0, stream>>>(Z2b, deg, rowptr, colsrc, enorm, bg2, lng, lnb, XT);
  k_lstm_seq<<<NP/32, 256, 0, stream>>>(XT,  XT1, WF,        BS,       0);
  k_lstm_seq<<<NP/32, 256, 0, stream>>>(XT1, h1b, WF + 4096, BS + 256, 1);
  k_heads<<<(NN+255)/256, 256, 0, stream>>>(h1b, Wm1, bm1, Wm2, bm2, Wd1, bd1, Wd2, bd2, out);
}

// Round 5
// 516.733 us; speedup vs baseline: 2.0937x; 1.1328x over previous
//
#include <hip/hip_runtime.h>
#include <stdint.h>

#define NN 50000
#define NP 50048          // padded to 64 for the MFMA LSTM kernel
#define EE 400000
#define TT 7
#define NB3 3125          // NN/16
#define LN_EPS 1e-5f

typedef __attribute__((ext_vector_type(8))) short bf16x8;
typedef __attribute__((ext_vector_type(4))) float f32x4;

__device__ __forceinline__ float leaky01(float x){ return x > 0.f ? x : 0.01f*x; }
__device__ __forceinline__ float fastrcp(float x){ return __builtin_amdgcn_rcpf(x); }
// v_rcp_f32-based (full IEEE div = ~10 instrs; this is 1) — ~1ulp, fine vs 1.7e-3 budget
__device__ __forceinline__ float sigmoidf(float x){ return fastrcp(1.f+__expf(-x)); }
__device__ __forceinline__ float tanhfast(float x){ return 1.f - 2.f*fastrcp(__expf(2.f*x)+1.f); }
__device__ __forceinline__ unsigned bf16rne(float f){
  unsigned u = __float_as_uint(f);
  return (u + 0x7fffu + ((u>>16)&1u)) >> 16;
}
__device__ __forceinline__ float bfu(unsigned u){ return __uint_as_float(u<<16); }
__device__ __forceinline__ float bfhi(unsigned u){ return __uint_as_float(u & 0xffff0000u); }

// ---------------- graph norm / CSR build ----------------
__global__ void k_init_deg(float* deg){
  int i = blockIdx.x*blockDim.x + threadIdx.x;
  if (i < NN) deg[i] = 1.0f;                // self-loop weight
}
__global__ void k_edge_count(const int* __restrict__ src, const int* __restrict__ dst,
                             const float* __restrict__ ew, float* deg, int* counts){
  int e = blockIdx.x*blockDim.x + threadIdx.x;
  if (e < EE){
    int d = dst[e];
    atomicAdd(&deg[d], ew[e]);
    atomicAdd(&counts[d], 1);
  }
}
// hierarchical scan: per-block inclusive (196 blocks) -> top scan -> fixup
// (also fuses deg -> rsqrt(deg))
__global__ __launch_bounds__(256) void k_scan_blk(const int* __restrict__ counts,
                                                  int* locincl, int* bsum, float* deg){
  int tid = threadIdx.x; int i = blockIdx.x*256 + tid;
  if (i < NN) deg[i] = rsqrtf(deg[i]);      // deg >= 1 always
  int v = (i < NN) ? counts[i] : 0;
  int lane = tid & 63;
  int val = v;
  #pragma unroll
  for (int off = 1; off < 64; off <<= 1){
    int u = __shfl_up(val, off, 64);
    if (lane >= off) val += u;
  }
  __shared__ int wsum[4];
  if (lane == 63) wsum[tid>>6] = val;
  __syncthreads();
  int w = tid >> 6, pre = 0;
  #pragma unroll
  for (int k = 0; k < 4; ++k) if (k < w) pre += wsum[k];
  int incl = val + pre;
  if (i < NN) locincl[i] = incl;
  if (tid == 255) bsum[blockIdx.x] = incl;
}
__global__ __launch_bounds__(256) void k_scan_top(const int* __restrict__ bsum, int* boff){
  int tid = threadIdx.x;
  int v = (tid < 196) ? bsum[tid] : 0;
  int lane = tid & 63;
  int val = v;
  #pragma unroll
  for (int off = 1; off < 64; off <<= 1){
    int u = __shfl_up(val, off, 64);
    if (lane >= off) val += u;
  }
  __shared__ int wsum[4];
  if (lane == 63) wsum[tid>>6] = val;
  __syncthreads();
  int w = tid >> 6, pre = 0;
  #pragma unroll
  for (int k = 0; k < 4; ++k) if (k < w) pre += wsum[k];
  if (tid < 196) boff[tid] = val + pre - v;   // exclusive prefix
}
__global__ __launch_bounds__(256) void k_scan_fix(const int* __restrict__ locincl,
        const int* __restrict__ boff, const int* __restrict__ counts,
        int* rowptr, int* cursor){
  int i = blockIdx.x*256 + threadIdx.x;
  if (i < NN){
    int r = locincl[i] + boff[blockIdx.x];
    rowptr[i+1] = r;
    cursor[i] = r - counts[i];
  }
  if (i == 0) rowptr[0] = 0;
}
__global__ void k_scatter(const int* __restrict__ src, const int* __restrict__ dst,
                          const float* __restrict__ ew, const float* __restrict__ dinv,
                          int* cursor, int* colsrc, float* enorm){
  int e = blockIdx.x*blockDim.x + threadIdx.x;
  if (e < EE){
    int s = src[e], d = dst[e];
    float nv = dinv[s]*ew[e]*dinv[d];
    int slot = atomicAdd(&cursor[d], 1);
    colsrc[slot] = s;
    enorm[slot] = nv;
  }
}

// ---------------- LSTM weight packing (B-fragment order) ----------------
__global__ void k_prep_wf(const float* __restrict__ Wih0, const float* __restrict__ Whh0,
                          const float* __restrict__ Wih1, const float* __restrict__ Whh1,
                          uint4* WF){
  int idx = blockIdx.x*blockDim.x + threadIdx.x;
  if (idx >= 8192) return;
  int L = idx >> 12;
  int r = idx & 4095;
  int lane = r & 63;
  int e = r >> 6;
  int which = e & 1;
  int cs = e >> 1;
  int s = cs & 1, ct = cs >> 1;
  int row = ct*16 + (lane & 15);
  int kb = s*32 + (lane >> 4)*8;
  const float* W = L ? (which ? Whh1 : Wih1) : (which ? Whh0 : Wih0);
  const float* p = W + row*64 + kb;
  uint4 v;
  v.x = bf16rne(p[0]) | (bf16rne(p[1])<<16);
  v.y = bf16rne(p[2]) | (bf16rne(p[3])<<16);
  v.z = bf16rne(p[4]) | (bf16rne(p[5])<<16);
  v.w = bf16rne(p[6]) | (bf16rne(p[7])<<16);
  WF[idx] = v;
}
__global__ void k_prep_bias(const float* bih0, const float* bhh0,
                            const float* bih1, const float* bhh1, float* BS){
  int j = threadIdx.x; int L = blockIdx.x;
  if (j < 256) BS[L*256+j] = L ? (bih1[j]+bhh1[j]) : (bih0[j]+bhh0[j]);
}

// ---------------- GCN ----------------
__global__ __launch_bounds__(256) void k_agg_x(const float* __restrict__ x,
        const float* __restrict__ dinv, const int* __restrict__ rowptr,
        const int* __restrict__ colsrc, const float* __restrict__ enorm,
        float* __restrict__ AX){
  int lane = threadIdx.x & 63, w = threadIdx.x >> 6;
  int i = blockIdx.x*4 + w;
  int beg = rowptr[i], end = rowptr[i+1];
  float di = dinv[i];
  float acc = 0.f;
  if (lane < 49) acc = di*di*x[(size_t)i*49 + lane];
  for (int s = beg; s < end; ++s){
    int cs = colsrc[s]; float wv = enorm[s];
    if (lane < 49) acc += wv * x[(size_t)cs*49 + lane];
  }
  if (lane < 49) AX[(size_t)i*49 + lane] = acc;
}
// Batched over t: H1 = leaky(AX_t @ Wg1 + bg1); Z2 = bf16(H1 @ Wg2).  16 nodes/block.
// Z2p layout: [node][feat][8] bf16 (t in last, padded dim) -> agg gather is 1 b128/lane/edge
__global__ __launch_bounds__(256) void k_gcn2_all(const float* __restrict__ AX,
        const float* __restrict__ Wg1, const float* __restrict__ bg1,
        const float* __restrict__ Wg2, ushort* __restrict__ Z2p){
  int t = blockIdx.x / NB3;
  int nb = blockIdx.x % NB3;
  __shared__ float sw1[7*64];
  __shared__ float sb1[64];
  __shared__ float sw2[64*64];
  __shared__ float sax[16*8];
  __shared__ __align__(16) float sr[16*64];
  int tid = threadIdx.x;
  const float4* w4 = (const float4*)Wg2;
  float4* sw4 = (float4*)sw2;
  #pragma unroll
  for (int i = 0; i < 4; ++i) sw4[tid + i*256] = w4[tid + i*256];
  for (int i = tid; i < 448; i += 256) sw1[i] = Wg1[i];
  if (tid < 64) sb1[tid] = bg1[tid];
  int base = nb*16;
  if (tid < 112){
    int n = tid / 7, k = tid % 7;
    sax[n*8 + k] = AX[(size_t)(base+n)*49 + t*7 + k];
  }
  __syncthreads();
  #pragma unroll
  for (int i = 0; i < 4; ++i){
    int idx = i*256 + tid;
    int n = idx >> 6, c = idx & 63;
    float acc = sb1[c];
    #pragma unroll
    for (int k = 0; k < 7; ++k) acc += sax[n*8+k]*sw1[k*64+c];
    sr[idx] = leaky01(acc);
  }
  __syncthreads();
  int c = tid & 63, w = tid >> 6;
  float a0=0.f, a1=0.f, a2=0.f, a3=0.f;
  const float* r = sr + w*256;
  for (int k = 0; k < 64; ++k){
    float wv = sw2[k*64+c];
    a0 += r[k]*wv; a1 += r[64+k]*wv; a2 += r[128+k]*wv; a3 += r[192+k]*wv;
  }
  size_t o = ((size_t)(base + w*4)*64 + c)*8 + t;
  Z2p[o]      = (ushort)bf16rne(a0);
  Z2p[o+512]  = (ushort)bf16rne(a1);
  Z2p[o+1024] = (ushort)bf16rne(a2);
  Z2p[o+1536] = (ushort)bf16rne(a3);
}
// Batched aggregation + LN over all 7 t. One wave per node; lane = feature.
// Per edge: ONE uint4 load per lane (all 7 t), 7 FMAs. XT layout: [t][NP][64] bf16
__global__ __launch_bounds__(256) void k_agg_ln_all(const ushort* __restrict__ Z2p,
        const float* __restrict__ dinv, const int* __restrict__ rowptr,
        const int* __restrict__ colsrc, const float* __restrict__ enorm,
        const float* __restrict__ bg2, const float* __restrict__ lng,
        const float* __restrict__ lnb, ushort* __restrict__ XT){
  int lane = threadIdx.x & 63, w = threadIdx.x >> 6;
  int i = blockIdx.x*4 + w;
  int beg = rowptr[i], end = rowptr[i+1];
  float di = dinv[i];
  float swt = di*di;
  const uint4* zp = (const uint4*)Z2p;    // one uint4 per (node,feat)
  float acc[7];
  {
    uint4 v = zp[(size_t)i*64 + lane];
    acc[0] = swt*bfu(v.x); acc[1] = swt*bfhi(v.x);
    acc[2] = swt*bfu(v.y); acc[3] = swt*bfhi(v.y);
    acc[4] = swt*bfu(v.z); acc[5] = swt*bfhi(v.z);
    acc[6] = swt*bfu(v.w);
  }
  for (int s = beg; s < end; ++s){
    int cs = colsrc[s]; float wv = enorm[s];
    uint4 v = zp[(size_t)cs*64 + lane];
    acc[0] = fmaf(wv, bfu(v.x),  acc[0]);
    acc[1] = fmaf(wv, bfhi(v.x), acc[1]);
    acc[2] = fmaf(wv, bfu(v.y),  acc[2]);
    acc[3] = fmaf(wv, bfhi(v.y), acc[3]);
    acc[4] = fmaf(wv, bfu(v.z),  acc[4]);
    acc[5] = fmaf(wv, bfhi(v.z), acc[5]);
    acc[6] = fmaf(wv, bfu(v.w),  acc[6]);
  }
  float b2 = bg2[lane], gl = lng[lane], bl = lnb[lane];
  #pragma unroll
  for (int t = 0; t < 7; ++t){
    float a = leaky01(acc[t] + b2);
    float sum = a;
    #pragma unroll
    for (int off = 32; off >= 1; off >>= 1) sum += __shfl_xor(sum, off, 64);
    float mu = sum * (1.f/64.f);
    float d = a - mu;
    float vs = d*d;
    #pragma unroll
    for (int off = 32; off >= 1; off >>= 1) vs += __shfl_xor(vs, off, 64);
    float rs = rsqrtf(vs*(1.f/64.f) + LN_EPS);
    XT[(size_t)t*NP*64 + (size_t)i*64 + lane] = (ushort)bf16rne(d*rs*gl + bl);
  }
}

// ---------------- LSTM: one layer, ALL 7 timesteps, state in registers ----------------
// Block = 256 thr = 4 waves, covers 32 nodes (2 m-tiles of 16). Wave `cp` owns acc
// tiles {cp, cp+4, cp+8, cp+12} = complete i/f/g/o gates for units 16cp..16cp+16.
// Weight fragments (16 x uint4 = 64 VGPRs) preloaded ONCE -> zero WF traffic in t-loop.
// tr double-buffered -> 1 barrier per t. Gates use v_rcp (no IEEE div sequences).
__global__ __launch_bounds__(256) void k_lstm_seq(const ushort* __restrict__ xin,
        ushort* __restrict__ outbuf, const uint4* __restrict__ WF,
        const float* __restrict__ BS, int mode){
  __shared__ __align__(16) ushort tr[2][32][72];   // stride 144 B, b128-aligned rows
  int tid = threadIdx.x;
  int lane = tid & 63, cp = tid >> 6;
  int base = blockIdx.x*32;
  int col = lane & 15, quad = lane >> 4;
  bf16x8 bwi[4][2], bwh[4][2];
  #pragma unroll
  for (int g = 0; g < 4; ++g){
    int ct = cp + 4*g;
    #pragma unroll
    for (int s = 0; s < 2; ++s){
      uint4 wi = WF[((ct*2+s)*2+0)*64 + lane];
      uint4 wh = WF[((ct*2+s)*2+1)*64 + lane];
      bwi[g][s] = *(bf16x8*)&wi;
      bwh[g][s] = *(bf16x8*)&wh;
    }
  }
  f32x4 cst[2];
  cst[0] = (f32x4){0.f,0.f,0.f,0.f};
  cst[1] = (f32x4){0.f,0.f,0.f,0.f};
  bf16x8 hfr[2][2];
  #pragma unroll
  for (int mt = 0; mt < 2; ++mt)
    #pragma unroll
    for (int s = 0; s < 2; ++s) hfr[mt][s] = (bf16x8){0,0,0,0,0,0,0,0};
  float bias[4];
  #pragma unroll
  for (int g = 0; g < 4; ++g) bias[g] = BS[(cp + 4*g)*16 + col];

  for (int t = 0; t < 7; ++t){
    int p = t & 1;
    bf16x8 ax[2][2];
    #pragma unroll
    for (int mt = 0; mt < 2; ++mt)
      #pragma unroll
      for (int s = 0; s < 2; ++s)
        ax[mt][s] = *(const bf16x8*)(xin + (size_t)t*NP*64
                        + (size_t)(base + mt*16 + col)*64 + s*32 + quad*8);
    f32x4 acc[2][4];
    #pragma unroll
    for (int g = 0; g < 4; ++g){
      float b = bias[g];
      acc[0][g] = (f32x4){b,b,b,b};
      acc[1][g] = (f32x4){b,b,b,b};
    }
    #pragma unroll
    for (int g = 0; g < 4; ++g){
      #pragma unroll
      for (int s = 0; s < 2; ++s){
        #pragma unroll
        for (int mt = 0; mt < 2; ++mt){
          acc[mt][g] = __builtin_amdgcn_mfma_f32_16x16x32_bf16(ax[mt][s], bwi[g][s], acc[mt][g], 0,0,0);
          acc[mt][g] = __builtin_amdgcn_mfma_f32_16x16x32_bf16(hfr[mt][s], bwh[g][s], acc[mt][g], 0,0,0);
        }
      }
    }
    // epilogue: complete gates in-lane for units u = 16cp+col, rows quad*4+r
    #pragma unroll
    for (int mt = 0; mt < 2; ++mt){
      #pragma unroll
      for (int r = 0; r < 4; ++r){
        float ig = sigmoidf(acc[mt][0][r]);
        float fg = sigmoidf(acc[mt][1][r]);
        float gg = tanhfast(acc[mt][2][r]);
        float og = sigmoidf(acc[mt][3][r]);
        float cn = fg*cst[mt][r] + ig*gg;
        cst[mt][r] = cn;
        tr[p][mt*16 + quad*4 + r][cp*16 + col] = (ushort)bf16rne(og*tanhfast(cn));
      }
    }
    __syncthreads();
    #pragma unroll
    for (int mt = 0; mt < 2; ++mt)
      #pragma unroll
      for (int s = 0; s < 2; ++s)
        hfr[mt][s] = *(const bf16x8*)&tr[p][mt*16 + col][s*32 + quad*8];
    if (mode == 0 || t == 6){
      int n2 = tid >> 3, off = (tid & 7)*8;          // 256 threads = 32 nodes x 4 chunks
      uint4 v = *(const uint4*)&tr[p][n2][off];
      size_t o = (mode == 0) ? ((size_t)t*NP*64 + (size_t)(base+n2)*64 + off)
                             : ((size_t)(base+n2)*64 + off);
      *(uint4*)(outbuf + o) = v;
    }
    // no trailing barrier: next iteration writes tr[1-p]; tr[p] rewritten only
    // after everyone passed the NEXT iteration's barrier.
  }
}

// ---------------- heads ----------------
__global__ __launch_bounds__(256) void k_heads(const ushort* __restrict__ f,
        const float* __restrict__ Wm1, const float* __restrict__ bm1,
        const float* __restrict__ Wm2, const float* __restrict__ bm2,
        const float* __restrict__ Wd1, const float* __restrict__ bd1,
        const float* __restrict__ Wd2, const float* __restrict__ bd2,
        float* __restrict__ out){
  __shared__ float swm1[64*32];
  __shared__ float swm2[32*4];
  __shared__ float swd1[64*16];
  __shared__ float swd2[16*4];
  __shared__ float sbm1[32], sbm2[4], sbd1[16], sbd2[4];
  int tid = threadIdx.x;
  for (int i = tid; i < 2048; i += 256) swm1[i] = Wm1[i];
  for (int i = tid; i < 1024; i += 256) swd1[i] = Wd1[i];
  if (tid < 128) swm2[tid] = Wm2[tid];
  if (tid < 64) swd2[tid] = Wd2[tid];
  if (tid < 32) sbm1[tid] = bm1[tid];
  if (tid < 16) sbd1[tid] = bd1[tid];
  if (tid < 4){ sbm2[tid] = bm2[tid]; sbd2[tid] = bd2[tid]; }
  __syncthreads();
  int n = blockIdx.x*256 + tid;
  if (n >= NN) return;
  float fr[64];
  const uint* f2 = (const uint*)(f + (size_t)n*64);
  #pragma unroll
  for (int i = 0; i < 32; ++i){ uint u = f2[i]; fr[2*i] = bfu(u); fr[2*i+1] = bfhi(u); }
  float m1[32];
  #pragma unroll
  for (int c2 = 0; c2 < 32; ++c2) m1[c2] = sbm1[c2];
  for (int k = 0; k < 64; ++k){
    float fv = fr[k];
    #pragma unroll
    for (int c2 = 0; c2 < 32; ++c2) m1[c2] += fv*swm1[k*32+c2];
  }
  #pragma unroll
  for (int c2 = 0; c2 < 32; ++c2) m1[c2] = leaky01(m1[c2]);
  float mo[4];
  #pragma unroll
  for (int o = 0; o < 4; ++o) mo[o] = sbm2[o];
  for (int c2 = 0; c2 < 32; ++c2){
    float mv = m1[c2];
    #pragma unroll
    for (int o = 0; o < 4; ++o) mo[o] += mv*swm2[c2*4+o];
  }
  float d1[16];
  #pragma unroll
  for (int c2 = 0; c2 < 16; ++c2) d1[c2] = sbd1[c2];
  for (int k = 0; k < 64; ++k){
    float fv = fr[k];
    #pragma unroll
    for (int c2 = 0; c2 < 16; ++c2) d1[c2] += fv*swd1[k*16+c2];
  }
  #pragma unroll
  for (int c2 = 0; c2 < 16; ++c2) d1[c2] = fmaxf(d1[c2], 0.f);
  float dv[4];
  #pragma unroll
  for (int o = 0; o < 4; ++o) dv[o] = sbd2[o];
  for (int c2 = 0; c2 < 16; ++c2){
    float xv = d1[c2];
    #pragma unroll
    for (int o = 0; o < 4; ++o) dv[o] += xv*swd2[c2*4+o];
  }
  float4* o4 = (float4*)out;
  o4[n] = make_float4(fmaxf(mo[0],0.f)+1e-4f, fmaxf(mo[1],0.f)+1e-4f,
                      fmaxf(mo[2],0.f)+1e-4f, fmaxf(mo[3],0.f)+1e-4f);
  o4[NN + n] = make_float4(dv[0], dv[1], dv[2], dv[3]);
}

extern "C" void kernel_launch(void* const* d_in, const int* in_sizes, int n_in,
                              void* d_out, int out_size, void* d_ws, size_t ws_size,
                              hipStream_t stream){
  const float* x    = (const float*)d_in[0];
  const int*   eidx = (const int*)d_in[1];
  const float* ew   = (const float*)d_in[2];
  const float* Wg1  = (const float*)d_in[3];
  const float* bg1  = (const float*)d_in[4];
  const float* Wg2  = (const float*)d_in[5];
  const float* bg2  = (const float*)d_in[6];
  const float* lng  = (const float*)d_in[7];
  const float* lnb  = (const float*)d_in[8];
  const float* Wih0 = (const float*)d_in[9];
  const float* Whh0 = (const float*)d_in[10];
  const float* bih0 = (const float*)d_in[11];
  const float* bhh0 = (const float*)d_in[12];
  const float* Wih1 = (const float*)d_in[13];
  const float* Whh1 = (const float*)d_in[14];
  const float* bih1 = (const float*)d_in[15];
  const float* bhh1 = (const float*)d_in[16];
  const float* Wm1  = (const float*)d_in[17];
  const float* bm1  = (const float*)d_in[18];
  const float* Wm2  = (const float*)d_in[19];
  const float* bm2  = (const float*)d_in[20];
  const float* Wd1  = (const float*)d_in[21];
  const float* bd1  = (const float*)d_in[22];
  const float* Wd2  = (const float*)d_in[23];
  const float* bd2  = (const float*)d_in[24];
  const int* src = eidx;
  const int* dst = eidx + EE;
  float* out = (float*)d_out;

  char* p = (char*)d_ws;
  auto alloc = [&](size_t bytes)->char*{ char* r = p; p += (bytes + 255) & ~(size_t)255; return r; };
  // persistent-through-call buffers
  float*  deg     = (float*)alloc((size_t)NN*4);       // becomes dinv
  float*  enorm   = (float*)alloc((size_t)EE*4);
  int*    counts  = (int*)  alloc((size_t)NN*4);
  int*    rowptr  = (int*)  alloc((size_t)(NN+1)*4);
  int*    cursor  = (int*)  alloc((size_t)NN*4);
  int*    colsrc  = (int*)  alloc((size_t)EE*4);
  int*    locincl = (int*)  alloc((size_t)NN*4);
  int*    bsum    = (int*)  alloc((size_t)256*4);
  int*    boff    = (int*)  alloc((size_t)256*4);
  uint4*  WF      = (uint4*)alloc((size_t)2*4096*16);
  float*  BS      = (float*)alloc((size_t)2*256*4);
  ushort* h1b     = (ushort*)alloc((size_t)NP*64*2);
  ushort* XT      = (ushort*)alloc((size_t)TT*NP*64*2);
  // phase buffers; XT1 aliases AX+Z2p (both dead before XT1 is written)
  char*   phase   = alloc((size_t)NN*49*4 + (size_t)NN*64*8*2);
  float*  AX      = (float*)phase;
  ushort* Z2p     = (ushort*)(phase + (size_t)NN*49*4);
  ushort* XT1     = (ushort*)phase;    // needs TT*NP*64*2 = 44.8MB <= 61MB phase

  hipMemsetAsync(counts, 0, (size_t)NN*4, stream);
  k_init_deg<<<(NN+255)/256, 256, 0, stream>>>(deg);
  k_edge_count<<<(EE+255)/256, 256, 0, stream>>>(src, dst, ew, deg, counts);
  k_scan_blk<<<196, 256, 0, stream>>>(counts, locincl, bsum, deg);
  k_scan_top<<<1, 256, 0, stream>>>(bsum, boff);
  k_scan_fix<<<196, 256, 0, stream>>>(locincl, boff, counts, rowptr, cursor);
  k_scatter<<<(EE+255)/256, 256, 0, stream>>>(src, dst, ew, deg, cursor, colsrc, enorm);
  k_prep_wf<<<32, 256, 0, stream>>>(Wih0, Whh0, Wih1, Whh1, WF);
  k_prep_bias<<<2, 256, 0, stream>>>(bih0, bhh0, bih1, bhh1, BS);
  k_agg_x<<<NN/4, 256, 0, stream>>>(x, deg, rowptr, colsrc, enorm, AX);

  k_gcn2_all<<<TT*NB3, 256, 0, stream>>>(AX, Wg1, bg1, Wg2, Z2p);
  k_agg_ln_all<<<NN/4, 256, 0, stream>>>(Z2p, deg, rowptr, colsrc, enorm, bg2, lng, lnb, XT);
  k_lstm_seq<<<NP/32, 256, 0, stream>>>(XT,  XT1, WF,        BS,       0);
  k_lstm_seq<<<NP/32, 256, 0, stream>>>(XT1, h1b, WF + 4096, BS + 256, 1);
  k_heads<<<(NN+255)/256, 256, 0, stream>>>(h1b, Wm1, bm1, Wm2, bm2, Wd1, bd1, Wd2, bd2, out);
}

// Round 6
// 461.336 us; speedup vs baseline: 2.3451x; 1.1201x over previous
//
#include <hip/hip_runtime.h>
#include <stdint.h>

#define NN 50000
#define NP 50048          // padded to 64 for the MFMA LSTM kernel
#define EE 400000
#define TT 7
#define LN_EPS 1e-5f

typedef __attribute__((ext_vector_type(8))) short bf16x8;
typedef __attribute__((ext_vector_type(4))) float f32x4;

__device__ __forceinline__ float leaky01(float x){ return x > 0.f ? x : 0.01f*x; }
__device__ __forceinline__ float fastrcp(float x){ return __builtin_amdgcn_rcpf(x); }
__device__ __forceinline__ float sigmoidf(float x){ return fastrcp(1.f+__expf(-x)); }
__device__ __forceinline__ float tanhfast(float x){ return 1.f - 2.f*fastrcp(__expf(2.f*x)+1.f); }
__device__ __forceinline__ unsigned bf16rne(float f){
  unsigned u = __float_as_uint(f);
  return (u + 0x7fffu + ((u>>16)&1u)) >> 16;
}
__device__ __forceinline__ float bfu(unsigned u){ return __uint_as_float(u<<16); }
__device__ __forceinline__ float bfhi(unsigned u){ return __uint_as_float(u & 0xffff0000u); }

// ---------------- graph norm / CSR build ----------------
__global__ void k_init_deg(float* deg){
  int i = blockIdx.x*blockDim.x + threadIdx.x;
  if (i < NN) deg[i] = 1.0f;                // self-loop weight
}
__global__ void k_edge_count(const int* __restrict__ src, const int* __restrict__ dst,
                             const float* __restrict__ ew, float* deg, int* counts){
  int e = blockIdx.x*blockDim.x + threadIdx.x;
  if (e < EE){
    int d = dst[e];
    atomicAdd(&deg[d], ew[e]);
    atomicAdd(&counts[d], 1);
  }
}
// hierarchical scan: per-block inclusive (196 blocks) -> top scan -> fixup
// (also fuses deg -> rsqrt(deg))
__global__ __launch_bounds__(256) void k_scan_blk(const int* __restrict__ counts,
                                                  int* locincl, int* bsum, float* deg){
  int tid = threadIdx.x; int i = blockIdx.x*256 + tid;
  if (i < NN) deg[i] = rsqrtf(deg[i]);      // deg >= 1 always
  int v = (i < NN) ? counts[i] : 0;
  int lane = tid & 63;
  int val = v;
  #pragma unroll
  for (int off = 1; off < 64; off <<= 1){
    int u = __shfl_up(val, off, 64);
    if (lane >= off) val += u;
  }
  __shared__ int wsum[4];
  if (lane == 63) wsum[tid>>6] = val;
  __syncthreads();
  int w = tid >> 6, pre = 0;
  #pragma unroll
  for (int k = 0; k < 4; ++k) if (k < w) pre += wsum[k];
  int incl = val + pre;
  if (i < NN) locincl[i] = incl;
  if (tid == 255) bsum[blockIdx.x] = incl;
}
__global__ __launch_bounds__(256) void k_scan_top(const int* __restrict__ bsum, int* boff){
  int tid = threadIdx.x;
  int v = (tid < 196) ? bsum[tid] : 0;
  int lane = tid & 63;
  int val = v;
  #pragma unroll
  for (int off = 1; off < 64; off <<= 1){
    int u = __shfl_up(val, off, 64);
    if (lane >= off) val += u;
  }
  __shared__ int wsum[4];
  if (lane == 63) wsum[tid>>6] = val;
  __syncthreads();
  int w = tid >> 6, pre = 0;
  #pragma unroll
  for (int k = 0; k < 4; ++k) if (k < w) pre += wsum[k];
  if (tid < 196) boff[tid] = val + pre - v;   // exclusive prefix
}
__global__ __launch_bounds__(256) void k_scan_fix(const int* __restrict__ locincl,
        const int* __restrict__ boff, const int* __restrict__ counts,
        int* rowptr, int* cursor){
  int i = blockIdx.x*256 + threadIdx.x;
  if (i < NN){
    int r = locincl[i] + boff[blockIdx.x];
    rowptr[i+1] = r;
    cursor[i] = r - counts[i];
  }
  if (i == 0) rowptr[0] = 0;
}
__global__ void k_scatter(const int* __restrict__ src, const int* __restrict__ dst,
                          const float* __restrict__ ew, const float* __restrict__ dinv,
                          int* cursor, int* colsrc, float* enorm){
  int e = blockIdx.x*blockDim.x + threadIdx.x;
  if (e < EE){
    int s = src[e], d = dst[e];
    float nv = dinv[s]*ew[e]*dinv[d];
    int slot = atomicAdd(&cursor[d], 1);
    colsrc[slot] = s;
    enorm[slot] = nv;
  }
}

// ---------------- LSTM weight packing (B-fragment order) ----------------
__global__ void k_prep_wf(const float* __restrict__ Wih0, const float* __restrict__ Whh0,
                          const float* __restrict__ Wih1, const float* __restrict__ Whh1,
                          uint4* WF){
  int idx = blockIdx.x*blockDim.x + threadIdx.x;
  if (idx >= 8192) return;
  int L = idx >> 12;
  int r = idx & 4095;
  int lane = r & 63;
  int e = r >> 6;
  int which = e & 1;
  int cs = e >> 1;
  int s = cs & 1, ct = cs >> 1;
  int row = ct*16 + (lane & 15);
  int kb = s*32 + (lane >> 4)*8;
  const float* W = L ? (which ? Whh1 : Wih1) : (which ? Whh0 : Wih0);
  const float* p = W + row*64 + kb;
  uint4 v;
  v.x = bf16rne(p[0]) | (bf16rne(p[1])<<16);
  v.y = bf16rne(p[2]) | (bf16rne(p[3])<<16);
  v.z = bf16rne(p[4]) | (bf16rne(p[5])<<16);
  v.w = bf16rne(p[6]) | (bf16rne(p[7])<<16);
  WF[idx] = v;
}
// Wg2 ([64 k][64 c] row-major) -> B-frag layout: frag (ct,s,lane): B[n=ct*16+(lane&15)][k]
__global__ void k_prep_wg2(const float* __restrict__ Wg2, uint4* WG2F){
  int idx = blockIdx.x*blockDim.x + threadIdx.x;
  if (idx >= 512) return;
  int lane = idx & 63, e = idx >> 6;   // e = ct*2+s
  int s = e & 1, ct = e >> 1;
  int kb = s*32 + (lane>>4)*8;
  int c = ct*16 + (lane&15);
  uint4 v;
  v.x = bf16rne(Wg2[(kb+0)*64+c]) | (bf16rne(Wg2[(kb+1)*64+c])<<16);
  v.y = bf16rne(Wg2[(kb+2)*64+c]) | (bf16rne(Wg2[(kb+3)*64+c])<<16);
  v.z = bf16rne(Wg2[(kb+4)*64+c]) | (bf16rne(Wg2[(kb+5)*64+c])<<16);
  v.w = bf16rne(Wg2[(kb+6)*64+c]) | (bf16rne(Wg2[(kb+7)*64+c])<<16);
  WG2F[idx] = v;
}
__global__ void k_prep_bias(const float* bih0, const float* bhh0,
                            const float* bih1, const float* bhh1, float* BS){
  int j = threadIdx.x; int L = blockIdx.x;
  if (j < 256) BS[L*256+j] = L ? (bih1[j]+bhh1[j]) : (bih0[j]+bhh0[j]);
}

// ---------------- GCN ----------------
__global__ __launch_bounds__(256) void k_agg_x(const float* __restrict__ x,
        const float* __restrict__ dinv, const int* __restrict__ rowptr,
        const int* __restrict__ colsrc, const float* __restrict__ enorm,
        float* __restrict__ AX){
  int lane = threadIdx.x & 63, w = threadIdx.x >> 6;
  int i = blockIdx.x*4 + w;
  int beg = rowptr[i], end = rowptr[i+1];
  float di = dinv[i];
  float acc = 0.f;
  if (lane < 49) acc = di*di*x[(size_t)i*49 + lane];
  for (int s = beg; s < end; ++s){
    int cs = colsrc[s]; float wv = enorm[s];
    if (lane < 49) acc += wv * x[(size_t)cs*49 + lane];
  }
  if (lane < 49) AX[(size_t)i*49 + lane] = acc;
}
// GCN layer 1+2 for ALL 7 t in one block (8 nodes/block, 64 rows = node*8+t).
// H1 by VALU into LDS (bf16), Z2 = H1 @ Wg2 by MFMA (B-frags in regs).
// Each (node,feat) 16-B Z2p group written exactly once, coalesced -> no write amp.
__global__ __launch_bounds__(256) void k_gcn2_mfma(const float* __restrict__ AX,
        const float* __restrict__ Wg1, const float* __restrict__ bg1,
        const uint4* __restrict__ WG2F, ushort* __restrict__ Z2p){
  __shared__ float sw1[448];
  __shared__ float sb1[64];
  __shared__ float sax[8*56];
  __shared__ __align__(16) ushort srb[64*68];   // stride 68: 2-way max on writes
  int tid = threadIdx.x;
  int lane = tid & 63, w = tid >> 6;
  // B-frags (Wg2), loaded once
  bf16x8 bw[4][2];
  #pragma unroll
  for (int ct = 0; ct < 4; ++ct)
    #pragma unroll
    for (int s = 0; s < 2; ++s){
      uint4 v = WG2F[(ct*2+s)*64 + lane];
      bw[ct][s] = *(bf16x8*)&v;
    }
  for (int i = tid; i < 448; i += 256) sw1[i] = Wg1[i];
  if (tid < 64) sb1[tid] = bg1[tid];
  int nbase = blockIdx.x*8;
  for (int i = tid; i < 448; i += 256){
    int n = i/56, c = i%56;
    sax[i] = (c < 49) ? AX[(size_t)(nbase+n)*49 + c] : 0.f;
  }
  __syncthreads();
  // H1: row = lane (node=lane>>3, t=lane&7; t==7 pad -> unused junk), k in [16w,16w+16)
  {
    int node = lane >> 3, t = lane & 7;
    float a[7];
    #pragma unroll
    for (int kk = 0; kk < 7; ++kk) a[kk] = sax[node*56 + t*7 + kk];  // t=7 reads zero pad
    ushort hv[16];
    #pragma unroll
    for (int j = 0; j < 16; ++j){
      int k = w*16 + j;
      float acc = sb1[k];
      #pragma unroll
      for (int kk = 0; kk < 7; ++kk) acc += a[kk]*sw1[kk*64+k];  // sw1 broadcast across lanes
      hv[j] = (ushort)bf16rne(leaky01(acc));
    }
    uint2* dst = (uint2*)&srb[lane*68 + w*16];
    #pragma unroll
    for (int q = 0; q < 4; ++q){
      uint2 v;
      v.x = (uint)hv[q*4+0] | ((uint)hv[q*4+1]<<16);
      v.y = (uint)hv[q*4+2] | ((uint)hv[q*4+3]<<16);
      dst[q] = v;
    }
  }
  __syncthreads();
  // A-frags for m-tile w (block-local rows 16w..16w+15)
  int col = lane & 15, quad = lane >> 4;
  bf16x8 afr[2];
  #pragma unroll
  for (int s = 0; s < 2; ++s){
    const ushort* pr = &srb[(w*16 + col)*68 + s*32 + quad*8];
    uint2 lo = *(const uint2*)pr;
    uint2 hi = *(const uint2*)(pr + 4);
    union { uint u[4]; bf16x8 b; } cv;
    cv.u[0]=lo.x; cv.u[1]=lo.y; cv.u[2]=hi.x; cv.u[3]=hi.y;
    afr[s] = cv.b;
  }
  f32x4 acc[4];
  #pragma unroll
  for (int ct = 0; ct < 4; ++ct) acc[ct] = (f32x4){0.f,0.f,0.f,0.f};
  #pragma unroll
  for (int ct = 0; ct < 4; ++ct)
    #pragma unroll
    for (int s = 0; s < 2; ++s)
      acc[ct] = __builtin_amdgcn_mfma_f32_16x16x32_bf16(afr[s], bw[ct][s], acc[ct], 0,0,0);
  // epilogue: C row m=quad*4+r -> node_local = 2w+(quad>>1), t = (quad&1)*4+r
  int node = nbase + w*2 + (quad>>1);
  #pragma unroll
  for (int ct = 0; ct < 4; ++ct){
    uint2 v;
    v.x = bf16rne(acc[ct][0]) | (bf16rne(acc[ct][1])<<16);
    v.y = bf16rne(acc[ct][2]) | (bf16rne(acc[ct][3])<<16);
    size_t o = ((size_t)node*64 + ct*16 + col)*8 + (quad&1)*4;
    *(uint2*)(Z2p + o) = v;
  }
}
// Batched aggregation + LN over all 7 t. One wave per node; lane = feature.
// Per edge: ONE uint4 load per lane (all 7 t), 7 FMAs. XT layout: [t][NP][64] bf16
__global__ __launch_bounds__(256) void k_agg_ln_all(const ushort* __restrict__ Z2p,
        const float* __restrict__ dinv, const int* __restrict__ rowptr,
        const int* __restrict__ colsrc, const float* __restrict__ enorm,
        const float* __restrict__ bg2, const float* __restrict__ lng,
        const float* __restrict__ lnb, ushort* __restrict__ XT){
  int lane = threadIdx.x & 63, w = threadIdx.x >> 6;
  int i = blockIdx.x*4 + w;
  int beg = rowptr[i], end = rowptr[i+1];
  float di = dinv[i];
  float swt = di*di;
  const uint4* zp = (const uint4*)Z2p;    // one uint4 per (node,feat)
  float acc[7];
  {
    uint4 v = zp[(size_t)i*64 + lane];
    acc[0] = swt*bfu(v.x); acc[1] = swt*bfhi(v.x);
    acc[2] = swt*bfu(v.y); acc[3] = swt*bfhi(v.y);
    acc[4] = swt*bfu(v.z); acc[5] = swt*bfhi(v.z);
    acc[6] = swt*bfu(v.w);
  }
  for (int s = beg; s < end; ++s){
    int cs = colsrc[s]; float wv = enorm[s];
    uint4 v = zp[(size_t)cs*64 + lane];
    acc[0] = fmaf(wv, bfu(v.x),  acc[0]);
    acc[1] = fmaf(wv, bfhi(v.x), acc[1]);
    acc[2] = fmaf(wv, bfu(v.y),  acc[2]);
    acc[3] = fmaf(wv, bfhi(v.y), acc[3]);
    acc[4] = fmaf(wv, bfu(v.z),  acc[4]);
    acc[5] = fmaf(wv, bfhi(v.z), acc[5]);
    acc[6] = fmaf(wv, bfu(v.w),  acc[6]);
  }
  float b2 = bg2[lane], gl = lng[lane], bl = lnb[lane];
  #pragma unroll
  for (int t = 0; t < 7; ++t){
    float a = leaky01(acc[t] + b2);
    float sum = a;
    #pragma unroll
    for (int off = 32; off >= 1; off >>= 1) sum += __shfl_xor(sum, off, 64);
    float mu = sum * (1.f/64.f);
    float d = a - mu;
    float vs = d*d;
    #pragma unroll
    for (int off = 32; off >= 1; off >>= 1) vs += __shfl_xor(vs, off, 64);
    float rs = rsqrtf(vs*(1.f/64.f) + LN_EPS);
    XT[(size_t)t*NP*64 + (size_t)i*64 + lane] = (ushort)bf16rne(d*rs*gl + bl);
  }
}

// ---------------- LSTM: one layer, ALL 7 timesteps, state in registers ----------------
__global__ __launch_bounds__(256) void k_lstm_seq(const ushort* __restrict__ xin,
        ushort* __restrict__ outbuf, const uint4* __restrict__ WF,
        const float* __restrict__ BS, int mode){
  __shared__ __align__(16) ushort tr[2][32][72];   // stride 144 B, b128-aligned rows
  int tid = threadIdx.x;
  int lane = tid & 63, cp = tid >> 6;
  int base = blockIdx.x*32;
  int col = lane & 15, quad = lane >> 4;
  bf16x8 bwi[4][2], bwh[4][2];
  #pragma unroll
  for (int g = 0; g < 4; ++g){
    int ct = cp + 4*g;
    #pragma unroll
    for (int s = 0; s < 2; ++s){
      uint4 wi = WF[((ct*2+s)*2+0)*64 + lane];
      uint4 wh = WF[((ct*2+s)*2+1)*64 + lane];
      bwi[g][s] = *(bf16x8*)&wi;
      bwh[g][s] = *(bf16x8*)&wh;
    }
  }
  f32x4 cst[2];
  cst[0] = (f32x4){0.f,0.f,0.f,0.f};
  cst[1] = (f32x4){0.f,0.f,0.f,0.f};
  bf16x8 hfr[2][2];
  #pragma unroll
  for (int mt = 0; mt < 2; ++mt)
    #pragma unroll
    for (int s = 0; s < 2; ++s) hfr[mt][s] = (bf16x8){0,0,0,0,0,0,0,0};
  float bias[4];
  #pragma unroll
  for (int g = 0; g < 4; ++g) bias[g] = BS[(cp + 4*g)*16 + col];

  for (int t = 0; t < 7; ++t){
    int p = t & 1;
    bf16x8 ax[2][2];
    #pragma unroll
    for (int mt = 0; mt < 2; ++mt)
      #pragma unroll
      for (int s = 0; s < 2; ++s)
        ax[mt][s] = *(const bf16x8*)(xin + (size_t)t*NP*64
                        + (size_t)(base + mt*16 + col)*64 + s*32 + quad*8);
    f32x4 acc[2][4];
    #pragma unroll
    for (int g = 0; g < 4; ++g){
      float b = bias[g];
      acc[0][g] = (f32x4){b,b,b,b};
      acc[1][g] = (f32x4){b,b,b,b};
    }
    #pragma unroll
    for (int g = 0; g < 4; ++g){
      #pragma unroll
      for (int s = 0; s < 2; ++s){
        #pragma unroll
        for (int mt = 0; mt < 2; ++mt){
          acc[mt][g] = __builtin_amdgcn_mfma_f32_16x16x32_bf16(ax[mt][s], bwi[g][s], acc[mt][g], 0,0,0);
          acc[mt][g] = __builtin_amdgcn_mfma_f32_16x16x32_bf16(hfr[mt][s], bwh[g][s], acc[mt][g], 0,0,0);
        }
      }
    }
    #pragma unroll
    for (int mt = 0; mt < 2; ++mt){
      #pragma unroll
      for (int r = 0; r < 4; ++r){
        float ig = sigmoidf(acc[mt][0][r]);
        float fg = sigmoidf(acc[mt][1][r]);
        float gg = tanhfast(acc[mt][2][r]);
        float og = sigmoidf(acc[mt][3][r]);
        float cn = fg*cst[mt][r] + ig*gg;
        cst[mt][r] = cn;
        tr[p][mt*16 + quad*4 + r][cp*16 + col] = (ushort)bf16rne(og*tanhfast(cn));
      }
    }
    __syncthreads();
    #pragma unroll
    for (int mt = 0; mt < 2; ++mt)
      #pragma unroll
      for (int s = 0; s < 2; ++s)
        hfr[mt][s] = *(const bf16x8*)&tr[p][mt*16 + col][s*32 + quad*8];
    if (mode == 0 || t == 6){
      int n2 = tid >> 3, off = (tid & 7)*8;          // 256 threads = 32 nodes x 4 chunks
      uint4 v = *(const uint4*)&tr[p][n2][off];
      size_t o = (mode == 0) ? ((size_t)t*NP*64 + (size_t)(base+n2)*64 + off)
                             : ((size_t)(base+n2)*64 + off);
      *(uint4*)(outbuf + o) = v;
    }
    // no trailing barrier: next iteration writes tr[1-p]
  }
}

// ---------------- heads ----------------
__global__ __launch_bounds__(256) void k_heads(const ushort* __restrict__ f,
        const float* __restrict__ Wm1, const float* __restrict__ bm1,
        const float* __restrict__ Wm2, const float* __restrict__ bm2,
        const float* __restrict__ Wd1, const float* __restrict__ bd1,
        const float* __restrict__ Wd2, const float* __restrict__ bd2,
        float* __restrict__ out){
  __shared__ float swm1[64*32];
  __shared__ float swm2[32*4];
  __shared__ float swd1[64*16];
  __shared__ float swd2[16*4];
  __shared__ float sbm1[32], sbm2[4], sbd1[16], sbd2[4];
  int tid = threadIdx.x;
  for (int i = tid; i < 2048; i += 256) swm1[i] = Wm1[i];
  for (int i = tid; i < 1024; i += 256) swd1[i] = Wd1[i];
  if (tid < 128) swm2[tid] = Wm2[tid];
  if (tid < 64) swd2[tid] = Wd2[tid];
  if (tid < 32) sbm1[tid] = bm1[tid];
  if (tid < 16) sbd1[tid] = bd1[tid];
  if (tid < 4){ sbm2[tid] = bm2[tid]; sbd2[tid] = bd2[tid]; }
  __syncthreads();
  int n = blockIdx.x*256 + tid;
  if (n >= NN) return;
  float fr[64];
  const uint* f2 = (const uint*)(f + (size_t)n*64);
  #pragma unroll
  for (int i = 0; i < 32; ++i){ uint u = f2[i]; fr[2*i] = bfu(u); fr[2*i+1] = bfhi(u); }
  float m1[32];
  #pragma unroll
  for (int c2 = 0; c2 < 32; ++c2) m1[c2] = sbm1[c2];
  for (int k = 0; k < 64; ++k){
    float fv = fr[k];
    #pragma unroll
    for (int c2 = 0; c2 < 32; ++c2) m1[c2] += fv*swm1[k*32+c2];
  }
  #pragma unroll
  for (int c2 = 0; c2 < 32; ++c2) m1[c2] = leaky01(m1[c2]);
  float mo[4];
  #pragma unroll
  for (int o = 0; o < 4; ++o) mo[o] = sbm2[o];
  for (int c2 = 0; c2 < 32; ++c2){
    float mv = m1[c2];
    #pragma unroll
    for (int o = 0; o < 4; ++o) mo[o] += mv*swm2[c2*4+o];
  }
  float d1[16];
  #pragma unroll
  for (int c2 = 0; c2 < 16; ++c2) d1[c2] = sbd1[c2];
  for (int k = 0; k < 64; ++k){
    float fv = fr[k];
    #pragma unroll
    for (int c2 = 0; c2 < 16; ++c2) d1[c2] += fv*swd1[k*16+c2];
  }
  #pragma unroll
  for (int c2 = 0; c2 < 16; ++c2) d1[c2] = fmaxf(d1[c2], 0.f);
  float dv[4];
  #pragma unroll
  for (int o = 0; o < 4; ++o) dv[o] = sbd2[o];
  for (int c2 = 0; c2 < 16; ++c2){
    float xv = d1[c2];
    #pragma unroll
    for (int o = 0; o < 4; ++o) dv[o] += xv*swd2[c2*4+o];
  }
  float4* o4 = (float4*)out;
  o4[n] = make_float4(fmaxf(mo[0],0.f)+1e-4f, fmaxf(mo[1],0.f)+1e-4f,
                      fmaxf(mo[2],0.f)+1e-4f, fmaxf(mo[3],0.f)+1e-4f);
  o4[NN + n] = make_float4(dv[0], dv[1], dv[2], dv[3]);
}

extern "C" void kernel_launch(void* const* d_in, const int* in_sizes, int n_in,
                              void* d_out, int out_size, void* d_ws, size_t ws_size,
                              hipStream_t stream){
  const float* x    = (const float*)d_in[0];
  const int*   eidx = (const int*)d_in[1];
  const float* ew   = (const float*)d_in[2];
  const float* Wg1  = (const float*)d_in[3];
  const float* bg1  = (const float*)d_in[4];
  const float* Wg2  = (const float*)d_in[5];
  const float* bg2  = (const float*)d_in[6];
  const float* lng  = (const float*)d_in[7];
  const float* lnb  = (const float*)d_in[8];
  const float* Wih0 = (const float*)d_in[9];
  const float* Whh0 = (const float*)d_in[10];
  const float* bih0 = (const float*)d_in[11];
  const float* bhh0 = (const float*)d_in[12];
  const float* Wih1 = (const float*)d_in[13];
  const float* Whh1 = (const float*)d_in[14];
  const float* bih1 = (const float*)d_in[15];
  const float* bhh1 = (const float*)d_in[16];
  const float* Wm1  = (const float*)d_in[17];
  const float* bm1  = (const float*)d_in[18];
  const float* Wm2  = (const float*)d_in[19];
  const float* bm2  = (const float*)d_in[20];
  const float* Wd1  = (const float*)d_in[21];
  const float* bd1  = (const float*)d_in[22];
  const float* Wd2  = (const float*)d_in[23];
  const float* bd2  = (const float*)d_in[24];
  const int* src = eidx;
  const int* dst = eidx + EE;
  float* out = (float*)d_out;

  char* p = (char*)d_ws;
  auto alloc = [&](size_t bytes)->char*{ char* r = p; p += (bytes + 255) & ~(size_t)255; return r; };
  // persistent-through-call buffers
  float*  deg     = (float*)alloc((size_t)NN*4);       // becomes dinv
  float*  enorm   = (float*)alloc((size_t)EE*4);
  int*    counts  = (int*)  alloc((size_t)NN*4);
  int*    rowptr  = (int*)  alloc((size_t)(NN+1)*4);
  int*    cursor  = (int*)  alloc((size_t)NN*4);
  int*    colsrc  = (int*)  alloc((size_t)EE*4);
  int*    locincl = (int*)  alloc((size_t)NN*4);
  int*    bsum    = (int*)  alloc((size_t)256*4);
  int*    boff    = (int*)  alloc((size_t)256*4);
  uint4*  WF      = (uint4*)alloc((size_t)2*4096*16);
  uint4*  WG2F    = (uint4*)alloc((size_t)512*16);
  float*  BS      = (float*)alloc((size_t)2*256*4);
  ushort* h1b     = (ushort*)alloc((size_t)NP*64*2);
  ushort* XT      = (ushort*)alloc((size_t)TT*NP*64*2);
  // phase buffers; XT1 aliases AX+Z2p (both dead before XT1 is written)
  char*   phase   = alloc((size_t)NN*49*4 + (size_t)NN*64*8*2);
  float*  AX      = (float*)phase;
  ushort* Z2p     = (ushort*)(phase + (size_t)NN*49*4);
  ushort* XT1     = (ushort*)phase;    // needs TT*NP*64*2 = 44.8MB <= 61MB phase

  hipMemsetAsync(counts, 0, (size_t)NN*4, stream);
  k_init_deg<<<(NN+255)/256, 256, 0, stream>>>(deg);
  k_edge_count<<<(EE+255)/256, 256, 0, stream>>>(src, dst, ew, deg, counts);
  k_scan_blk<<<196, 256, 0, stream>>>(counts, locincl, bsum, deg);
  k_scan_top<<<1, 256, 0, stream>>>(bsum, boff);
  k_scan_fix<<<196, 256, 0, stream>>>(locincl, boff, counts, rowptr, cursor);
  k_scatter<<<(EE+255)/256, 256, 0, stream>>>(src, dst, ew, deg, cursor, colsrc, enorm);
  k_prep_wf<<<32, 256, 0, stream>>>(Wih0, Whh0, Wih1, Whh1, WF);
  k_prep_wg2<<<2, 256, 0, stream>>>(Wg2, WG2F);
  k_prep_bias<<<2, 256, 0, stream>>>(bih0, bhh0, bih1, bhh1, BS);
  k_agg_x<<<NN/4, 256, 0, stream>>>(x, deg, rowptr, colsrc, enorm, AX);

  k_gcn2_mfma<<<NN/8, 256, 0, stream>>>(AX, Wg1, bg1, WG2F, Z2p);
  k_agg_ln_all<<<NN/4, 256, 0, stream>>>(Z2p, deg, rowptr, colsrc, enorm, bg2, lng, lnb, XT);
  k_lstm_seq<<<NP/32, 256, 0, stream>>>(XT,  XT1, WF,        BS,       0);
  k_lstm_seq<<<NP/32, 256, 0, stream>>>(XT1, h1b, WF + 4096, BS + 256, 1);
  k_heads<<<(NN+255)/256, 256, 0, stream>>>(h1b, Wm1, bm1, Wm2, bm2, Wd1, bd1, Wd2, bd2, out);
}

// Round 7
// 428.933 us; speedup vs baseline: 2.5223x; 1.0755x over previous
//
#include <hip/hip_runtime.h>
#include <stdint.h>

#define NN 50000
#define NP 50048          // padded to 64 for the MFMA LSTM kernel
#define EE 400000
#define TT 7
#define LN_EPS 1e-5f

typedef __attribute__((ext_vector_type(8))) short bf16x8;
typedef __attribute__((ext_vector_type(4))) float f32x4;

__device__ __forceinline__ float leaky01(float x){ return x > 0.f ? x : 0.01f*x; }
__device__ __forceinline__ float fastrcp(float x){ return __builtin_amdgcn_rcpf(x); }
__device__ __forceinline__ float sigmoidf(float x){ return fastrcp(1.f+__expf(-x)); }
__device__ __forceinline__ float tanhfast(float x){ return 1.f - 2.f*fastrcp(__expf(2.f*x)+1.f); }
__device__ __forceinline__ unsigned bf16rne(float f){
  unsigned u = __float_as_uint(f);
  return (u + 0x7fffu + ((u>>16)&1u)) >> 16;
}
__device__ __forceinline__ float bfu(unsigned u){ return __uint_as_float(u<<16); }
__device__ __forceinline__ float bfhi(unsigned u){ return __uint_as_float(u & 0xffff0000u); }

// ---------------- one-shot prep: weight packing + inits + x->bf16 ----------------
__global__ __launch_bounds__(256) void k_prep_all(
    const float* __restrict__ Wih0, const float* __restrict__ Whh0,
    const float* __restrict__ Wih1, const float* __restrict__ Whh1,
    const float* __restrict__ Wg2,
    const float* __restrict__ bih0, const float* __restrict__ bhh0,
    const float* __restrict__ bih1, const float* __restrict__ bhh1,
    const float* __restrict__ x,
    uint4* __restrict__ WF, uint4* __restrict__ WG2F, float* __restrict__ BS,
    ushort* __restrict__ xb, float* __restrict__ deg, int* __restrict__ counts){
  int b = blockIdx.x, tid = threadIdx.x;
  if (b < 32){
    // LSTM weights -> B-fragment order
    int idx = b*256 + tid;
    int L = idx >> 12;
    int r = idx & 4095;
    int lane = r & 63;
    int e = r >> 6;
    int which = e & 1;
    int cs = e >> 1;
    int s = cs & 1, ct = cs >> 1;
    int row = ct*16 + (lane & 15);
    int kb = s*32 + (lane >> 4)*8;
    const float* W = L ? (which ? Whh1 : Wih1) : (which ? Whh0 : Wih0);
    const float* p = W + row*64 + kb;
    uint4 v;
    v.x = bf16rne(p[0]) | (bf16rne(p[1])<<16);
    v.y = bf16rne(p[2]) | (bf16rne(p[3])<<16);
    v.z = bf16rne(p[4]) | (bf16rne(p[5])<<16);
    v.w = bf16rne(p[6]) | (bf16rne(p[7])<<16);
    WF[idx] = v;
  } else if (b < 34){
    // Wg2 -> B-fragment order
    int idx = (b-32)*256 + tid;   // 0..511
    int lane = idx & 63, e = idx >> 6;   // e = ct*2+s
    int s = e & 1, ct = e >> 1;
    int kb = s*32 + (lane>>4)*8;
    int c = ct*16 + (lane&15);
    uint4 v;
    v.x = bf16rne(Wg2[(kb+0)*64+c]) | (bf16rne(Wg2[(kb+1)*64+c])<<16);
    v.y = bf16rne(Wg2[(kb+2)*64+c]) | (bf16rne(Wg2[(kb+3)*64+c])<<16);
    v.z = bf16rne(Wg2[(kb+4)*64+c]) | (bf16rne(Wg2[(kb+5)*64+c])<<16);
    v.w = bf16rne(Wg2[(kb+6)*64+c]) | (bf16rne(Wg2[(kb+7)*64+c])<<16);
    WG2F[idx] = v;
  } else if (b < 36){
    int L = b - 34;
    BS[L*256+tid] = L ? (bih1[tid]+bhh1[tid]) : (bih0[tid]+bhh0[tid]);
  } else if (b < 232){
    int i = (b-36)*256 + tid;
    if (i < NN){ deg[i] = 1.0f; counts[i] = 0; }   // self-loop weight; zero counts
  } else {
    int i = (b-232)*256 + tid;
    if (i < NN*49) xb[i] = (ushort)bf16rne(x[i]);
  }
}

// ---------------- graph norm / CSR build ----------------
__global__ void k_edge_count(const int* __restrict__ src, const int* __restrict__ dst,
                             const float* __restrict__ ew, float* deg, int* counts){
  int e = blockIdx.x*blockDim.x + threadIdx.x;
  if (e < EE){
    int d = dst[e];
    atomicAdd(&deg[d], ew[e]);
    atomicAdd(&counts[d], 1);
  }
}
// hierarchical scan: per-block inclusive (196 blocks) -> top scan -> fixup
// (also fuses deg -> rsqrt(deg))
__global__ __launch_bounds__(256) void k_scan_blk(const int* __restrict__ counts,
                                                  int* locincl, int* bsum, float* deg){
  int tid = threadIdx.x; int i = blockIdx.x*256 + tid;
  if (i < NN) deg[i] = rsqrtf(deg[i]);      // deg >= 1 always
  int v = (i < NN) ? counts[i] : 0;
  int lane = tid & 63;
  int val = v;
  #pragma unroll
  for (int off = 1; off < 64; off <<= 1){
    int u = __shfl_up(val, off, 64);
    if (lane >= off) val += u;
  }
  __shared__ int wsum[4];
  if (lane == 63) wsum[tid>>6] = val;
  __syncthreads();
  int w = tid >> 6, pre = 0;
  #pragma unroll
  for (int k = 0; k < 4; ++k) if (k < w) pre += wsum[k];
  int incl = val + pre;
  if (i < NN) locincl[i] = incl;
  if (tid == 255) bsum[blockIdx.x] = incl;
}
__global__ __launch_bounds__(256) void k_scan_top(const int* __restrict__ bsum, int* boff){
  int tid = threadIdx.x;
  int v = (tid < 196) ? bsum[tid] : 0;
  int lane = tid & 63;
  int val = v;
  #pragma unroll
  for (int off = 1; off < 64; off <<= 1){
    int u = __shfl_up(val, off, 64);
    if (lane >= off) val += u;
  }
  __shared__ int wsum[4];
  if (lane == 63) wsum[tid>>6] = val;
  __syncthreads();
  int w = tid >> 6, pre = 0;
  #pragma unroll
  for (int k = 0; k < 4; ++k) if (k < w) pre += wsum[k];
  if (tid < 196) boff[tid] = val + pre - v;   // exclusive prefix
}
__global__ __launch_bounds__(256) void k_scan_fix(const int* __restrict__ locincl,
        const int* __restrict__ boff, const int* __restrict__ counts,
        int* rowptr, int* cursor){
  int i = blockIdx.x*256 + threadIdx.x;
  if (i < NN){
    int r = locincl[i] + boff[blockIdx.x];
    rowptr[i+1] = r;
    cursor[i] = r - counts[i];
  }
  if (i == 0) rowptr[0] = 0;
}
// packed edge record: {src, norm-bits} -> one 8B random store / one 8B uniform load
__global__ void k_scatter(const int* __restrict__ src, const int* __restrict__ dst,
                          const float* __restrict__ ew, const float* __restrict__ dinv,
                          int* cursor, uint2* e2){
  int e = blockIdx.x*blockDim.x + threadIdx.x;
  if (e < EE){
    int s = src[e], d = dst[e];
    float nv = dinv[s]*ew[e]*dinv[d];
    int slot = atomicAdd(&cursor[d], 1);
    e2[slot] = make_uint2((uint)s, __float_as_uint(nv));
  }
}

// ---------------- GCN ----------------
// AX = A @ X over all 49 features; x pre-compressed to bf16 (98 B/row gather)
__global__ __launch_bounds__(256) void k_agg_x(const ushort* __restrict__ xb,
        const float* __restrict__ dinv, const int* __restrict__ rowptr,
        const uint2* __restrict__ e2, float* __restrict__ AX){
  int lane = threadIdx.x & 63, w = threadIdx.x >> 6;
  int i = blockIdx.x*4 + w;
  int beg = rowptr[i], end = rowptr[i+1];
  float di = dinv[i];
  float acc = 0.f;
  if (lane < 49) acc = di*di*bfu(xb[(size_t)i*49 + lane]);
  for (int s = beg; s < end; ++s){
    uint2 e = e2[s];
    int cs = (int)e.x; float wv = __uint_as_float(e.y);
    if (lane < 49) acc += wv * bfu(xb[(size_t)cs*49 + lane]);
  }
  if (lane < 49) AX[(size_t)i*49 + lane] = acc;
}
// GCN layer 1+2 for ALL 7 t in one block (8 nodes/block, 64 rows = node*8+t).
// H1 by VALU into LDS (bf16), Z2 = H1 @ Wg2 by MFMA (B-frags in regs).
__global__ __launch_bounds__(256) void k_gcn2_mfma(const float* __restrict__ AX,
        const float* __restrict__ Wg1, const float* __restrict__ bg1,
        const uint4* __restrict__ WG2F, ushort* __restrict__ Z2p){
  __shared__ float sw1[448];
  __shared__ float sb1[64];
  __shared__ float sax[8*56];
  __shared__ __align__(16) ushort srb[64*68];
  int tid = threadIdx.x;
  int lane = tid & 63, w = tid >> 6;
  bf16x8 bw[4][2];
  #pragma unroll
  for (int ct = 0; ct < 4; ++ct)
    #pragma unroll
    for (int s = 0; s < 2; ++s){
      uint4 v = WG2F[(ct*2+s)*64 + lane];
      bw[ct][s] = *(bf16x8*)&v;
    }
  for (int i = tid; i < 448; i += 256) sw1[i] = Wg1[i];
  if (tid < 64) sb1[tid] = bg1[tid];
  int nbase = blockIdx.x*8;
  for (int i = tid; i < 448; i += 256){
    int n = i/56, c = i%56;
    sax[i] = (c < 49) ? AX[(size_t)(nbase+n)*49 + c] : 0.f;
  }
  __syncthreads();
  {
    int node = lane >> 3, t = lane & 7;
    float a[7];
    #pragma unroll
    for (int kk = 0; kk < 7; ++kk) a[kk] = sax[node*56 + t*7 + kk];
    ushort hv[16];
    #pragma unroll
    for (int j = 0; j < 16; ++j){
      int k = w*16 + j;
      float acc = sb1[k];
      #pragma unroll
      for (int kk = 0; kk < 7; ++kk) acc += a[kk]*sw1[kk*64+k];
      hv[j] = (ushort)bf16rne(leaky01(acc));
    }
    uint2* dst = (uint2*)&srb[lane*68 + w*16];
    #pragma unroll
    for (int q = 0; q < 4; ++q){
      uint2 v;
      v.x = (uint)hv[q*4+0] | ((uint)hv[q*4+1]<<16);
      v.y = (uint)hv[q*4+2] | ((uint)hv[q*4+3]<<16);
      dst[q] = v;
    }
  }
  __syncthreads();
  int col = lane & 15, quad = lane >> 4;
  bf16x8 afr[2];
  #pragma unroll
  for (int s = 0; s < 2; ++s){
    const ushort* pr = &srb[(w*16 + col)*68 + s*32 + quad*8];
    uint2 lo = *(const uint2*)pr;
    uint2 hi = *(const uint2*)(pr + 4);
    union { uint u[4]; bf16x8 b; } cv;
    cv.u[0]=lo.x; cv.u[1]=lo.y; cv.u[2]=hi.x; cv.u[3]=hi.y;
    afr[s] = cv.b;
  }
  f32x4 acc[4];
  #pragma unroll
  for (int ct = 0; ct < 4; ++ct) acc[ct] = (f32x4){0.f,0.f,0.f,0.f};
  #pragma unroll
  for (int ct = 0; ct < 4; ++ct)
    #pragma unroll
    for (int s = 0; s < 2; ++s)
      acc[ct] = __builtin_amdgcn_mfma_f32_16x16x32_bf16(afr[s], bw[ct][s], acc[ct], 0,0,0);
  int node = nbase + w*2 + (quad>>1);
  #pragma unroll
  for (int ct = 0; ct < 4; ++ct){
    uint2 v;
    v.x = bf16rne(acc[ct][0]) | (bf16rne(acc[ct][1])<<16);
    v.y = bf16rne(acc[ct][2]) | (bf16rne(acc[ct][3])<<16);
    size_t o = ((size_t)node*64 + ct*16 + col)*8 + (quad&1)*4;
    *(uint2*)(Z2p + o) = v;
  }
}
// Batched aggregation + LN over all 7 t. One wave per node; lane = feature.
__global__ __launch_bounds__(256) void k_agg_ln_all(const ushort* __restrict__ Z2p,
        const float* __restrict__ dinv, const int* __restrict__ rowptr,
        const uint2* __restrict__ e2,
        const float* __restrict__ bg2, const float* __restrict__ lng,
        const float* __restrict__ lnb, ushort* __restrict__ XT){
  int lane = threadIdx.x & 63, w = threadIdx.x >> 6;
  int i = blockIdx.x*4 + w;
  int beg = rowptr[i], end = rowptr[i+1];
  float di = dinv[i];
  float swt = di*di;
  const uint4* zp = (const uint4*)Z2p;
  float acc[7];
  {
    uint4 v = zp[(size_t)i*64 + lane];
    acc[0] = swt*bfu(v.x); acc[1] = swt*bfhi(v.x);
    acc[2] = swt*bfu(v.y); acc[3] = swt*bfhi(v.y);
    acc[4] = swt*bfu(v.z); acc[5] = swt*bfhi(v.z);
    acc[6] = swt*bfu(v.w);
  }
  for (int s = beg; s < end; ++s){
    uint2 e = e2[s];
    int cs = (int)e.x; float wv = __uint_as_float(e.y);
    uint4 v = zp[(size_t)cs*64 + lane];
    acc[0] = fmaf(wv, bfu(v.x),  acc[0]);
    acc[1] = fmaf(wv, bfhi(v.x), acc[1]);
    acc[2] = fmaf(wv, bfu(v.y),  acc[2]);
    acc[3] = fmaf(wv, bfhi(v.y), acc[3]);
    acc[4] = fmaf(wv, bfu(v.z),  acc[4]);
    acc[5] = fmaf(wv, bfhi(v.z), acc[5]);
    acc[6] = fmaf(wv, bfu(v.w),  acc[6]);
  }
  float b2 = bg2[lane], gl = lng[lane], bl = lnb[lane];
  #pragma unroll
  for (int t = 0; t < 7; ++t){
    float a = leaky01(acc[t] + b2);
    float sum = a;
    #pragma unroll
    for (int off = 32; off >= 1; off >>= 1) sum += __shfl_xor(sum, off, 64);
    float mu = sum * (1.f/64.f);
    float d = a - mu;
    float vs = d*d;
    #pragma unroll
    for (int off = 32; off >= 1; off >>= 1) vs += __shfl_xor(vs, off, 64);
    float rs = rsqrtf(vs*(1.f/64.f) + LN_EPS);
    XT[(size_t)t*NP*64 + (size_t)i*64 + lane] = (ushort)bf16rne(d*rs*gl + bl);
  }
}

// ---------------- LSTM: BOTH layers, all 7 t, one kernel ----------------
// Block = 4 waves = 32 nodes. Layer-0 h sequence parked in LDS planes XL[t][32][72];
// layer 1 consumes planes in place (h1 overwrites h0 per plane, barrier-protected).
// Eliminates the 44.8 MB XT1 write + read of the 2-kernel version.
__global__ __launch_bounds__(256) void k_lstm_both(const ushort* __restrict__ xin,
        ushort* __restrict__ h1out, const uint4* __restrict__ WF,
        const float* __restrict__ BS){
  __shared__ __align__(16) ushort XL[7][32][72];   // 31.5 KB
  int tid = threadIdx.x;
  int lane = tid & 63, cp = tid >> 6;
  int base = blockIdx.x*32;
  int col = lane & 15, quad = lane >> 4;
  for (int L = 0; L < 2; ++L){
    bf16x8 bwi[4][2], bwh[4][2];
    const uint4* wf = WF + L*4096;
    #pragma unroll
    for (int g = 0; g < 4; ++g){
      int ct = cp + 4*g;
      #pragma unroll
      for (int s = 0; s < 2; ++s){
        uint4 wi = wf[((ct*2+s)*2+0)*64 + lane];
        uint4 wh = wf[((ct*2+s)*2+1)*64 + lane];
        bwi[g][s] = *(bf16x8*)&wi;
        bwh[g][s] = *(bf16x8*)&wh;
      }
    }
    float bias[4];
    #pragma unroll
    for (int g = 0; g < 4; ++g) bias[g] = BS[L*256 + (cp + 4*g)*16 + col];
    f32x4 cst[2];
    cst[0] = (f32x4){0.f,0.f,0.f,0.f};
    cst[1] = (f32x4){0.f,0.f,0.f,0.f};
    bf16x8 hfr[2][2];
    #pragma unroll
    for (int mt = 0; mt < 2; ++mt)
      #pragma unroll
      for (int s = 0; s < 2; ++s) hfr[mt][s] = (bf16x8){0,0,0,0,0,0,0,0};

    for (int t = 0; t < 7; ++t){
      bf16x8 ax[2][2];
      if (L == 0){
        #pragma unroll
        for (int mt = 0; mt < 2; ++mt)
          #pragma unroll
          for (int s = 0; s < 2; ++s)
            ax[mt][s] = *(const bf16x8*)(xin + (size_t)t*NP*64
                            + (size_t)(base + mt*16 + col)*64 + s*32 + quad*8);
      } else {
        #pragma unroll
        for (int mt = 0; mt < 2; ++mt)
          #pragma unroll
          for (int s = 0; s < 2; ++s)
            ax[mt][s] = *(const bf16x8*)&XL[t][mt*16 + col][s*32 + quad*8];
      }
      f32x4 acc[2][4];
      #pragma unroll
      for (int g = 0; g < 4; ++g){
        float b = bias[g];
        acc[0][g] = (f32x4){b,b,b,b};
        acc[1][g] = (f32x4){b,b,b,b};
      }
      #pragma unroll
      for (int g = 0; g < 4; ++g){
        #pragma unroll
        for (int s = 0; s < 2; ++s){
          #pragma unroll
          for (int mt = 0; mt < 2; ++mt){
            acc[mt][g] = __builtin_amdgcn_mfma_f32_16x16x32_bf16(ax[mt][s], bwi[g][s], acc[mt][g], 0,0,0);
            acc[mt][g] = __builtin_amdgcn_mfma_f32_16x16x32_bf16(hfr[mt][s], bwh[g][s], acc[mt][g], 0,0,0);
          }
        }
      }
      __syncthreads();   // (L=1) all reads of plane t done before overwrite
      #pragma unroll
      for (int mt = 0; mt < 2; ++mt){
        #pragma unroll
        for (int r = 0; r < 4; ++r){
          float ig = sigmoidf(acc[mt][0][r]);
          float fg = sigmoidf(acc[mt][1][r]);
          float gg = tanhfast(acc[mt][2][r]);
          float og = sigmoidf(acc[mt][3][r]);
          float cn = fg*cst[mt][r] + ig*gg;
          cst[mt][r] = cn;
          XL[t][mt*16 + quad*4 + r][cp*16 + col] = (ushort)bf16rne(og*tanhfast(cn));
        }
      }
      __syncthreads();
      #pragma unroll
      for (int mt = 0; mt < 2; ++mt)
        #pragma unroll
        for (int s = 0; s < 2; ++s)
          hfr[mt][s] = *(const bf16x8*)&XL[t][mt*16 + col][s*32 + quad*8];
    }
  }
  // plane 6 holds layer-1 h(t=6); contiguous b128 store
  int n2 = tid >> 3, off = (tid & 7)*8;
  uint4 v = *(const uint4*)&XL[6][n2][off];
  *(uint4*)(h1out + (size_t)(base+n2)*64 + off) = v;
}

// ---------------- heads ----------------
__global__ __launch_bounds__(256) void k_heads(const ushort* __restrict__ f,
        const float* __restrict__ Wm1, const float* __restrict__ bm1,
        const float* __restrict__ Wm2, const float* __restrict__ bm2,
        const float* __restrict__ Wd1, const float* __restrict__ bd1,
        const float* __restrict__ Wd2, const float* __restrict__ bd2,
        float* __restrict__ out){
  __shared__ float swm1[64*32];
  __shared__ float swm2[32*4];
  __shared__ float swd1[64*16];
  __shared__ float swd2[16*4];
  __shared__ float sbm1[32], sbm2[4], sbd1[16], sbd2[4];
  int tid = threadIdx.x;
  for (int i = tid; i < 2048; i += 256) swm1[i] = Wm1[i];
  for (int i = tid; i < 1024; i += 256) swd1[i] = Wd1[i];
  if (tid < 128) swm2[tid] = Wm2[tid];
  if (tid < 64) swd2[tid] = Wd2[tid];
  if (tid < 32) sbm1[tid] = bm1[tid];
  if (tid < 16) sbd1[tid] = bd1[tid];
  if (tid < 4){ sbm2[tid] = bm2[tid]; sbd2[tid] = bd2[tid]; }
  __syncthreads();
  int n = blockIdx.x*256 + tid;
  if (n >= NN) return;
  float fr[64];
  const uint* f2 = (const uint*)(f + (size_t)n*64);
  #pragma unroll
  for (int i = 0; i < 32; ++i){ uint u = f2[i]; fr[2*i] = bfu(u); fr[2*i+1] = bfhi(u); }
  float m1[32];
  #pragma unroll
  for (int c2 = 0; c2 < 32; ++c2) m1[c2] = sbm1[c2];
  for (int k = 0; k < 64; ++k){
    float fv = fr[k];
    #pragma unroll
    for (int c2 = 0; c2 < 32; ++c2) m1[c2] += fv*swm1[k*32+c2];
  }
  #pragma unroll
  for (int c2 = 0; c2 < 32; ++c2) m1[c2] = leaky01(m1[c2]);
  float mo[4];
  #pragma unroll
  for (int o = 0; o < 4; ++o) mo[o] = sbm2[o];
  for (int c2 = 0; c2 < 32; ++c2){
    float mv = m1[c2];
    #pragma unroll
    for (int o = 0; o < 4; ++o) mo[o] += mv*swm2[c2*4+o];
  }
  float d1[16];
  #pragma unroll
  for (int c2 = 0; c2 < 16; ++c2) d1[c2] = sbd1[c2];
  for (int k = 0; k < 64; ++k){
    float fv = fr[k];
    #pragma unroll
    for (int c2 = 0; c2 < 16; ++c2) d1[c2] += fv*swd1[k*16+c2];
  }
  #pragma unroll
  for (int c2 = 0; c2 < 16; ++c2) d1[c2] = fmaxf(d1[c2], 0.f);
  float dv[4];
  #pragma unroll
  for (int o = 0; o < 4; ++o) dv[o] = sbd2[o];
  for (int c2 = 0; c2 < 16; ++c2){
    float xv = d1[c2];
    #pragma unroll
    for (int o = 0; o < 4; ++o) dv[o] += xv*swd2[c2*4+o];
  }
  float4* o4 = (float4*)out;
  o4[n] = make_float4(fmaxf(mo[0],0.f)+1e-4f, fmaxf(mo[1],0.f)+1e-4f,
                      fmaxf(mo[2],0.f)+1e-4f, fmaxf(mo[3],0.f)+1e-4f);
  o4[NN + n] = make_float4(dv[0], dv[1], dv[2], dv[3]);
}

extern "C" void kernel_launch(void* const* d_in, const int* in_sizes, int n_in,
                              void* d_out, int out_size, void* d_ws, size_t ws_size,
                              hipStream_t stream){
  const float* x    = (const float*)d_in[0];
  const int*   eidx = (const int*)d_in[1];
  const float* ew   = (const float*)d_in[2];
  const float* Wg1  = (const float*)d_in[3];
  const float* bg1  = (const float*)d_in[4];
  const float* Wg2  = (const float*)d_in[5];
  const float* bg2  = (const float*)d_in[6];
  const float* lng  = (const float*)d_in[7];
  const float* lnb  = (const float*)d_in[8];
  const float* Wih0 = (const float*)d_in[9];
  const float* Whh0 = (const float*)d_in[10];
  const float* bih0 = (const float*)d_in[11];
  const float* bhh0 = (const float*)d_in[12];
  const float* Wih1 = (const float*)d_in[13];
  const float* Whh1 = (const float*)d_in[14];
  const float* bih1 = (const float*)d_in[15];
  const float* bhh1 = (const float*)d_in[16];
  const float* Wm1  = (const float*)d_in[17];
  const float* bm1  = (const float*)d_in[18];
  const float* Wm2  = (const float*)d_in[19];
  const float* bm2  = (const float*)d_in[20];
  const float* Wd1  = (const float*)d_in[21];
  const float* bd1  = (const float*)d_in[22];
  const float* Wd2  = (const float*)d_in[23];
  const float* bd2  = (const float*)d_in[24];
  const int* src = eidx;
  const int* dst = eidx + EE;
  float* out = (float*)d_out;

  char* p = (char*)d_ws;
  auto alloc = [&](size_t bytes)->char*{ char* r = p; p += (bytes + 255) & ~(size_t)255; return r; };
  float*  deg     = (float*)alloc((size_t)NN*4);       // becomes dinv
  int*    counts  = (int*)  alloc((size_t)NN*4);
  int*    rowptr  = (int*)  alloc((size_t)(NN+1)*4);
  int*    cursor  = (int*)  alloc((size_t)NN*4);
  int*    locincl = (int*)  alloc((size_t)NN*4);
  int*    bsum    = (int*)  alloc((size_t)256*4);
  int*    boff    = (int*)  alloc((size_t)256*4);
  uint2*  e2      = (uint2*)alloc((size_t)EE*8);
  uint4*  WF      = (uint4*)alloc((size_t)2*4096*16);
  uint4*  WG2F    = (uint4*)alloc((size_t)512*16);
  float*  BS      = (float*)alloc((size_t)2*256*4);
  ushort* xb      = (ushort*)alloc((size_t)NN*49*2);
  ushort* h1b     = (ushort*)alloc((size_t)NP*64*2);
  ushort* XT      = (ushort*)alloc((size_t)TT*NP*64*2);
  float*  AX      = (float*)alloc((size_t)NN*49*4);
  ushort* Z2p     = (ushort*)alloc((size_t)NN*64*8*2);

  int xblocks = (NN*49 + 255)/256;                 // 9571
  k_prep_all<<<232 + xblocks, 256, 0, stream>>>(Wih0, Whh0, Wih1, Whh1, Wg2,
      bih0, bhh0, bih1, bhh1, x, WF, WG2F, BS, xb, deg, counts);
  k_edge_count<<<(EE+255)/256, 256, 0, stream>>>(src, dst, ew, deg, counts);
  k_scan_blk<<<196, 256, 0, stream>>>(counts, locincl, bsum, deg);
  k_scan_top<<<1, 256, 0, stream>>>(bsum, boff);
  k_scan_fix<<<196, 256, 0, stream>>>(locincl, boff, counts, rowptr, cursor);
  k_scatter<<<(EE+255)/256, 256, 0, stream>>>(src, dst, ew, deg, cursor, e2);
  k_agg_x<<<NN/4, 256, 0, stream>>>(xb, deg, rowptr, e2, AX);
  k_gcn2_mfma<<<NN/8, 256, 0, stream>>>(AX, Wg1, bg1, WG2F, Z2p);
  k_agg_ln_all<<<NN/4, 256, 0, stream>>>(Z2p, deg, rowptr, e2, bg2, lng, lnb, XT);
  k_lstm_both<<<NP/32, 256, 0, stream>>>(XT, h1b, WF, BS);
  k_heads<<<(NN+255)/256, 256, 0, stream>>>(h1b, Wm1, bm1, Wm2, bm2, Wd1, bd1, Wd2, bd2, out);
}

// Round 8
// 408.784 us; speedup vs baseline: 2.6466x; 1.0493x over previous
//
#include <hip/hip_runtime.h>
#include <stdint.h>

#define NN 50000
#define NP 50048          // padded to 64 for the MFMA LSTM kernel
#define EE 400000
#define TT 7
#define LN_EPS 1e-5f
#define SIG_SC (-1.4426950408889634f)   // -log2(e): sigmoid prescale
#define TANH_SC (2.8853900817779268f)   // +2*log2(e): tanh prescale

typedef __attribute__((ext_vector_type(8))) short bf16x8;
typedef __attribute__((ext_vector_type(4))) float f32x4;

__device__ __forceinline__ float leaky01(float x){ return x > 0.f ? x : 0.01f*x; }
__device__ __forceinline__ float fastrcp(float x){ return __builtin_amdgcn_rcpf(x); }
__device__ __forceinline__ float exp2fast(float x){ return __builtin_amdgcn_exp2f(x); }
__device__ __forceinline__ float sigmoidf(float x){ return fastrcp(1.f+__expf(-x)); }
__device__ __forceinline__ float tanhfast(float x){ return 1.f - 2.f*fastrcp(__expf(2.f*x)+1.f); }
__device__ __forceinline__ unsigned bf16rne(float f){
  unsigned u = __float_as_uint(f);
  return (u + 0x7fffu + ((u>>16)&1u)) >> 16;
}
__device__ __forceinline__ float bfu(unsigned u){ return __uint_as_float(u<<16); }
__device__ __forceinline__ float bfhi(unsigned u){ return __uint_as_float(u & 0xffff0000u); }

// ---------------- one-shot prep: weight packing + inits + x->bf16 ----------------
// LSTM weights/biases are PRE-SCALED by the activation's exp2 constant:
//   i/f/o rows (blocks 0,1,3): * SIG_SC ; g rows (block 2): * TANH_SC
// so the epilogue is rcp(1+exp2(y)) forms with no per-element scaling muls.
__global__ __launch_bounds__(256) void k_prep_all(
    const float* __restrict__ Wih0, const float* __restrict__ Whh0,
    const float* __restrict__ Wih1, const float* __restrict__ Whh1,
    const float* __restrict__ Wg2,
    const float* __restrict__ bih0, const float* __restrict__ bhh0,
    const float* __restrict__ bih1, const float* __restrict__ bhh1,
    const float* __restrict__ x,
    uint4* __restrict__ WF, uint4* __restrict__ WG2F, float* __restrict__ BS,
    ushort* __restrict__ xb, float* __restrict__ deg, int* __restrict__ counts){
  int b = blockIdx.x, tid = threadIdx.x;
  if (b < 32){
    int idx = b*256 + tid;
    int L = idx >> 12;
    int r = idx & 4095;
    int lane = r & 63;
    int e = r >> 6;
    int which = e & 1;
    int cs = e >> 1;
    int s = cs & 1, ct = cs >> 1;
    int row = ct*16 + (lane & 15);
    float sc = ((row >> 6) == 2) ? TANH_SC : SIG_SC;
    int kb = s*32 + (lane >> 4)*8;
    const float* W = L ? (which ? Whh1 : Wih1) : (which ? Whh0 : Wih0);
    const float* p = W + row*64 + kb;
    uint4 v;
    v.x = bf16rne(sc*p[0]) | (bf16rne(sc*p[1])<<16);
    v.y = bf16rne(sc*p[2]) | (bf16rne(sc*p[3])<<16);
    v.z = bf16rne(sc*p[4]) | (bf16rne(sc*p[5])<<16);
    v.w = bf16rne(sc*p[6]) | (bf16rne(sc*p[7])<<16);
    WF[idx] = v;
  } else if (b < 34){
    int idx = (b-32)*256 + tid;   // 0..511
    int lane = idx & 63, e = idx >> 6;   // e = ct*2+s
    int s = e & 1, ct = e >> 1;
    int kb = s*32 + (lane>>4)*8;
    int c = ct*16 + (lane&15);
    uint4 v;
    v.x = bf16rne(Wg2[(kb+0)*64+c]) | (bf16rne(Wg2[(kb+1)*64+c])<<16);
    v.y = bf16rne(Wg2[(kb+2)*64+c]) | (bf16rne(Wg2[(kb+3)*64+c])<<16);
    v.z = bf16rne(Wg2[(kb+4)*64+c]) | (bf16rne(Wg2[(kb+5)*64+c])<<16);
    v.w = bf16rne(Wg2[(kb+6)*64+c]) | (bf16rne(Wg2[(kb+7)*64+c])<<16);
    WG2F[idx] = v;
  } else if (b < 36){
    int L = b - 34;
    float sc = ((tid >> 6) == 2) ? TANH_SC : SIG_SC;
    BS[L*256+tid] = sc * (L ? (bih1[tid]+bhh1[tid]) : (bih0[tid]+bhh0[tid]));
  } else if (b < 232){
    int i = (b-36)*256 + tid;
    if (i < NN){ deg[i] = 1.0f; counts[i] = 0; }
  } else {
    int i = (b-232)*256 + tid;
    if (i < NN*49) xb[i] = (ushort)bf16rne(x[i]);
  }
}

// ---------------- graph norm / CSR build ----------------
__global__ void k_edge_count(const int* __restrict__ src, const int* __restrict__ dst,
                             const float* __restrict__ ew, float* deg, int* counts){
  int e = blockIdx.x*blockDim.x + threadIdx.x;
  if (e < EE){
    int d = dst[e];
    atomicAdd(&deg[d], ew[e]);
    atomicAdd(&counts[d], 1);
  }
}
__global__ __launch_bounds__(256) void k_scan_blk(const int* __restrict__ counts,
                                                  int* locincl, int* bsum, float* deg){
  int tid = threadIdx.x; int i = blockIdx.x*256 + tid;
  if (i < NN) deg[i] = rsqrtf(deg[i]);      // deg >= 1 always
  int v = (i < NN) ? counts[i] : 0;
  int lane = tid & 63;
  int val = v;
  #pragma unroll
  for (int off = 1; off < 64; off <<= 1){
    int u = __shfl_up(val, off, 64);
    if (lane >= off) val += u;
  }
  __shared__ int wsum[4];
  if (lane == 63) wsum[tid>>6] = val;
  __syncthreads();
  int w = tid >> 6, pre = 0;
  #pragma unroll
  for (int k = 0; k < 4; ++k) if (k < w) pre += wsum[k];
  int incl = val + pre;
  if (i < NN) locincl[i] = incl;
  if (tid == 255) bsum[blockIdx.x] = incl;
}
__global__ __launch_bounds__(256) void k_scan_top(const int* __restrict__ bsum, int* boff){
  int tid = threadIdx.x;
  int v = (tid < 196) ? bsum[tid] : 0;
  int lane = tid & 63;
  int val = v;
  #pragma unroll
  for (int off = 1; off < 64; off <<= 1){
    int u = __shfl_up(val, off, 64);
    if (lane >= off) val += u;
  }
  __shared__ int wsum[4];
  if (lane == 63) wsum[tid>>6] = val;
  __syncthreads();
  int w = tid >> 6, pre = 0;
  #pragma unroll
  for (int k = 0; k < 4; ++k) if (k < w) pre += wsum[k];
  if (tid < 196) boff[tid] = val + pre - v;   // exclusive prefix
}
__global__ __launch_bounds__(256) void k_scan_fix(const int* __restrict__ locincl,
        const int* __restrict__ boff, const int* __restrict__ counts,
        int* rowptr, int* cursor){
  int i = blockIdx.x*256 + threadIdx.x;
  if (i < NN){
    int r = locincl[i] + boff[blockIdx.x];
    rowptr[i+1] = r;
    cursor[i] = r - counts[i];
  }
  if (i == 0) rowptr[0] = 0;
}
__global__ void k_scatter(const int* __restrict__ src, const int* __restrict__ dst,
                          const float* __restrict__ ew, const float* __restrict__ dinv,
                          int* cursor, uint2* e2){
  int e = blockIdx.x*blockDim.x + threadIdx.x;
  if (e < EE){
    int s = src[e], d = dst[e];
    float nv = dinv[s]*ew[e]*dinv[d];
    int slot = atomicAdd(&cursor[d], 1);
    e2[slot] = make_uint2((uint)s, __float_as_uint(nv));
  }
}

// ---------------- GCN ----------------
__global__ __launch_bounds__(256) void k_agg_x(const ushort* __restrict__ xb,
        const float* __restrict__ dinv, const int* __restrict__ rowptr,
        const uint2* __restrict__ e2, float* __restrict__ AX){
  int lane = threadIdx.x & 63, w = threadIdx.x >> 6;
  int i = blockIdx.x*4 + w;
  int beg = rowptr[i], end = rowptr[i+1];
  float di = dinv[i];
  float acc = 0.f;
  if (lane < 49) acc = di*di*bfu(xb[(size_t)i*49 + lane]);
  for (int s = beg; s < end; ++s){
    uint2 e = e2[s];
    int cs = (int)e.x; float wv = __uint_as_float(e.y);
    if (lane < 49) acc += wv * bfu(xb[(size_t)cs*49 + lane]);
  }
  if (lane < 49) AX[(size_t)i*49 + lane] = acc;
}
__global__ __launch_bounds__(256) void k_gcn2_mfma(const float* __restrict__ AX,
        const float* __restrict__ Wg1, const float* __restrict__ bg1,
        const uint4* __restrict__ WG2F, ushort* __restrict__ Z2p){
  __shared__ float sw1[448];
  __shared__ float sb1[64];
  __shared__ float sax[8*56];
  __shared__ __align__(16) ushort srb[64*68];
  int tid = threadIdx.x;
  int lane = tid & 63, w = tid >> 6;
  bf16x8 bw[4][2];
  #pragma unroll
  for (int ct = 0; ct < 4; ++ct)
    #pragma unroll
    for (int s = 0; s < 2; ++s){
      uint4 v = WG2F[(ct*2+s)*64 + lane];
      bw[ct][s] = *(bf16x8*)&v;
    }
  for (int i = tid; i < 448; i += 256) sw1[i] = Wg1[i];
  if (tid < 64) sb1[tid] = bg1[tid];
  int nbase = blockIdx.x*8;
  for (int i = tid; i < 448; i += 256){
    int n = i/56, c = i%56;
    sax[i] = (c < 49) ? AX[(size_t)(nbase+n)*49 + c] : 0.f;
  }
  __syncthreads();
  {
    int node = lane >> 3, t = lane & 7;
    float a[7];
    #pragma unroll
    for (int kk = 0; kk < 7; ++kk) a[kk] = sax[node*56 + t*7 + kk];
    ushort hv[16];
    #pragma unroll
    for (int j = 0; j < 16; ++j){
      int k = w*16 + j;
      float acc = sb1[k];
      #pragma unroll
      for (int kk = 0; kk < 7; ++kk) acc += a[kk]*sw1[kk*64+k];
      hv[j] = (ushort)bf16rne(leaky01(acc));
    }
    uint2* dst = (uint2*)&srb[lane*68 + w*16];
    #pragma unroll
    for (int q = 0; q < 4; ++q){
      uint2 v;
      v.x = (uint)hv[q*4+0] | ((uint)hv[q*4+1]<<16);
      v.y = (uint)hv[q*4+2] | ((uint)hv[q*4+3]<<16);
      dst[q] = v;
    }
  }
  __syncthreads();
  int col = lane & 15, quad = lane >> 4;
  bf16x8 afr[2];
  #pragma unroll
  for (int s = 0; s < 2; ++s){
    const ushort* pr = &srb[(w*16 + col)*68 + s*32 + quad*8];
    uint2 lo = *(const uint2*)pr;
    uint2 hi = *(const uint2*)(pr + 4);
    union { uint u[4]; bf16x8 b; } cv;
    cv.u[0]=lo.x; cv.u[1]=lo.y; cv.u[2]=hi.x; cv.u[3]=hi.y;
    afr[s] = cv.b;
  }
  f32x4 acc[4];
  #pragma unroll
  for (int ct = 0; ct < 4; ++ct) acc[ct] = (f32x4){0.f,0.f,0.f,0.f};
  #pragma unroll
  for (int ct = 0; ct < 4; ++ct)
    #pragma unroll
    for (int s = 0; s < 2; ++s)
      acc[ct] = __builtin_amdgcn_mfma_f32_16x16x32_bf16(afr[s], bw[ct][s], acc[ct], 0,0,0);
  int node = nbase + w*2 + (quad>>1);
  #pragma unroll
  for (int ct = 0; ct < 4; ++ct){
    uint2 v;
    v.x = bf16rne(acc[ct][0]) | (bf16rne(acc[ct][1])<<16);
    v.y = bf16rne(acc[ct][2]) | (bf16rne(acc[ct][3])<<16);
    size_t o = ((size_t)node*64 + ct*16 + col)*8 + (quad&1)*4;
    *(uint2*)(Z2p + o) = v;
  }
}
__global__ __launch_bounds__(256) void k_agg_ln_all(const ushort* __restrict__ Z2p,
        const float* __restrict__ dinv, const int* __restrict__ rowptr,
        const uint2* __restrict__ e2,
        const float* __restrict__ bg2, const float* __restrict__ lng,
        const float* __restrict__ lnb, ushort* __restrict__ XT){
  int lane = threadIdx.x & 63, w = threadIdx.x >> 6;
  int i = blockIdx.x*4 + w;
  int beg = rowptr[i], end = rowptr[i+1];
  float di = dinv[i];
  float swt = di*di;
  const uint4* zp = (const uint4*)Z2p;
  float acc[7];
  {
    uint4 v = zp[(size_t)i*64 + lane];
    acc[0] = swt*bfu(v.x); acc[1] = swt*bfhi(v.x);
    acc[2] = swt*bfu(v.y); acc[3] = swt*bfhi(v.y);
    acc[4] = swt*bfu(v.z); acc[5] = swt*bfhi(v.z);
    acc[6] = swt*bfu(v.w);
  }
  for (int s = beg; s < end; ++s){
    uint2 e = e2[s];
    int cs = (int)e.x; float wv = __uint_as_float(e.y);
    uint4 v = zp[(size_t)cs*64 + lane];
    acc[0] = fmaf(wv, bfu(v.x),  acc[0]);
    acc[1] = fmaf(wv, bfhi(v.x), acc[1]);
    acc[2] = fmaf(wv, bfu(v.y),  acc[2]);
    acc[3] = fmaf(wv, bfhi(v.y), acc[3]);
    acc[4] = fmaf(wv, bfu(v.z),  acc[4]);
    acc[5] = fmaf(wv, bfhi(v.z), acc[5]);
    acc[6] = fmaf(wv, bfu(v.w),  acc[6]);
  }
  float b2 = bg2[lane], gl = lng[lane], bl = lnb[lane];
  #pragma unroll
  for (int t = 0; t < 7; ++t){
    float a = leaky01(acc[t] + b2);
    float sum = a;
    #pragma unroll
    for (int off = 32; off >= 1; off >>= 1) sum += __shfl_xor(sum, off, 64);
    float mu = sum * (1.f/64.f);
    float d = a - mu;
    float vs = d*d;
    #pragma unroll
    for (int off = 32; off >= 1; off >>= 1) vs += __shfl_xor(vs, off, 64);
    float rs = rsqrtf(vs*(1.f/64.f) + LN_EPS);
    XT[(size_t)t*NP*64 + (size_t)i*64 + lane] = (ushort)bf16rne(d*rs*gl + bl);
  }
}

// ---------------- LSTM: BOTH layers, all 7 t, 16 nodes/block ----------------
// 4 waves split the gate-column tiles (wave cp owns tiles {cp,cp+4,cp+8,cp+12} =
// full i/f/g/o for units 16cp..16cp+16). Per wave: 8 MFMA + 4-element epilogue/t.
// Weights prescaled (SIG_SC/TANH_SC) so gates = rcp(1+exp2(y)) forms.
// Layer-0 h sequence parked in LDS planes XL[t][16][72]; layer-1 consumes in place.
__global__ __launch_bounds__(256) void k_lstm_both(const ushort* __restrict__ xin,
        ushort* __restrict__ h1out, const uint4* __restrict__ WF,
        const float* __restrict__ BS){
  __shared__ __align__(16) ushort XL[7][16][72];   // 15.75 KB
  int tid = threadIdx.x;
  int lane = tid & 63, cp = tid >> 6;
  int base = blockIdx.x*16;
  int col = lane & 15, quad = lane >> 4;
  for (int L = 0; L < 2; ++L){
    bf16x8 bwi[4][2], bwh[4][2];
    const uint4* wf = WF + L*4096;
    #pragma unroll
    for (int g = 0; g < 4; ++g){
      int ct = cp + 4*g;
      #pragma unroll
      for (int s = 0; s < 2; ++s){
        uint4 wi = wf[((ct*2+s)*2+0)*64 + lane];
        uint4 wh = wf[((ct*2+s)*2+1)*64 + lane];
        bwi[g][s] = *(bf16x8*)&wi;
        bwh[g][s] = *(bf16x8*)&wh;
      }
    }
    float bias[4];
    #pragma unroll
    for (int g = 0; g < 4; ++g) bias[g] = BS[L*256 + (cp + 4*g)*16 + col];
    f32x4 cst = (f32x4){0.f,0.f,0.f,0.f};
    bf16x8 hfr[2];
    hfr[0] = (bf16x8){0,0,0,0,0,0,0,0};
    hfr[1] = (bf16x8){0,0,0,0,0,0,0,0};

    for (int t = 0; t < 7; ++t){
      bf16x8 ax[2];
      if (L == 0){
        #pragma unroll
        for (int s = 0; s < 2; ++s)
          ax[s] = *(const bf16x8*)(xin + (size_t)t*NP*64
                          + (size_t)(base + col)*64 + s*32 + quad*8);
      } else {
        #pragma unroll
        for (int s = 0; s < 2; ++s)
          ax[s] = *(const bf16x8*)&XL[t][col][s*32 + quad*8];
      }
      f32x4 acc[4];
      #pragma unroll
      for (int g = 0; g < 4; ++g){
        float b = bias[g];
        acc[g] = (f32x4){b,b,b,b};
      }
      #pragma unroll
      for (int g = 0; g < 4; ++g){
        #pragma unroll
        for (int s = 0; s < 2; ++s){
          acc[g] = __builtin_amdgcn_mfma_f32_16x16x32_bf16(ax[s], bwi[g][s], acc[g], 0,0,0);
          acc[g] = __builtin_amdgcn_mfma_f32_16x16x32_bf16(hfr[s], bwh[g][s], acc[g], 0,0,0);
        }
      }
      __syncthreads();   // (L=1) all reads of plane t done before overwrite
      #pragma unroll
      for (int r = 0; r < 4; ++r){
        float ig = fastrcp(1.f + exp2fast(acc[0][r]));
        float fg = fastrcp(1.f + exp2fast(acc[1][r]));
        float gg = fmaf(-2.f, fastrcp(1.f + exp2fast(acc[2][r])), 1.f);
        float og = fastrcp(1.f + exp2fast(acc[3][r]));
        float cn = fmaf(fg, cst[r], ig*gg);
        cst[r] = cn;
        float tc = fmaf(-2.f, fastrcp(1.f + exp2fast(TANH_SC*cn)), 1.f);
        XL[t][quad*4 + r][cp*16 + col] = (ushort)bf16rne(og*tc);
      }
      __syncthreads();
      hfr[0] = *(const bf16x8*)&XL[t][col][quad*8];
      hfr[1] = *(const bf16x8*)&XL[t][col][32 + quad*8];
    }
  }
  // plane 6 holds layer-1 h(t=6); contiguous b128 store (16 nodes x 64 = 2 KB)
  if (tid < 128){
    int n2 = tid >> 3, off = (tid & 7)*8;
    uint4 v = *(const uint4*)&XL[6][n2][off];
    *(uint4*)(h1out + (size_t)(base+n2)*64 + off) = v;
  }
}

// ---------------- heads ----------------
__global__ __launch_bounds__(256) void k_heads(const ushort* __restrict__ f,
        const float* __restrict__ Wm1, const float* __restrict__ bm1,
        const float* __restrict__ Wm2, const float* __restrict__ bm2,
        const float* __restrict__ Wd1, const float* __restrict__ bd1,
        const float* __restrict__ Wd2, const float* __restrict__ bd2,
        float* __restrict__ out){
  __shared__ float swm1[64*32];
  __shared__ float swm2[32*4];
  __shared__ float swd1[64*16];
  __shared__ float swd2[16*4];
  __shared__ float sbm1[32], sbm2[4], sbd1[16], sbd2[4];
  int tid = threadIdx.x;
  for (int i = tid; i < 2048; i += 256) swm1[i] = Wm1[i];
  for (int i = tid; i < 1024; i += 256) swd1[i] = Wd1[i];
  if (tid < 128) swm2[tid] = Wm2[tid];
  if (tid < 64) swd2[tid] = Wd2[tid];
  if (tid < 32) sbm1[tid] = bm1[tid];
  if (tid < 16) sbd1[tid] = bd1[tid];
  if (tid < 4){ sbm2[tid] = bm2[tid]; sbd2[tid] = bd2[tid]; }
  __syncthreads();
  int n = blockIdx.x*256 + tid;
  if (n >= NN) return;
  float fr[64];
  const uint* f2 = (const uint*)(f + (size_t)n*64);
  #pragma unroll
  for (int i = 0; i < 32; ++i){ uint u = f2[i]; fr[2*i] = bfu(u); fr[2*i+1] = bfhi(u); }
  float m1[32];
  #pragma unroll
  for (int c2 = 0; c2 < 32; ++c2) m1[c2] = sbm1[c2];
  for (int k = 0; k < 64; ++k){
    float fv = fr[k];
    #pragma unroll
    for (int c2 = 0; c2 < 32; ++c2) m1[c2] += fv*swm1[k*32+c2];
  }
  #pragma unroll
  for (int c2 = 0; c2 < 32; ++c2) m1[c2] = leaky01(m1[c2]);
  float mo[4];
  #pragma unroll
  for (int o = 0; o < 4; ++o) mo[o] = sbm2[o];
  for (int c2 = 0; c2 < 32; ++c2){
    float mv = m1[c2];
    #pragma unroll
    for (int o = 0; o < 4; ++o) mo[o] += mv*swm2[c2*4+o];
  }
  float d1[16];
  #pragma unroll
  for (int c2 = 0; c2 < 16; ++c2) d1[c2] = sbd1[c2];
  for (int k = 0; k < 64; ++k){
    float fv = fr[k];
    #pragma unroll
    for (int c2 = 0; c2 < 16; ++c2) d1[c2] += fv*swd1[k*16+c2];
  }
  #pragma unroll
  for (int c2 = 0; c2 < 16; ++c2) d1[c2] = fmaxf(d1[c2], 0.f);
  float dv[4];
  #pragma unroll
  for (int o = 0; o < 4; ++o) dv[o] = sbd2[o];
  for (int c2 = 0; c2 < 16; ++c2){
    float xv = d1[c2];
    #pragma unroll
    for (int o = 0; o < 4; ++o) dv[o] += xv*swd2[c2*4+o];
  }
  float4* o4 = (float4*)out;
  o4[n] = make_float4(fmaxf(mo[0],0.f)+1e-4f, fmaxf(mo[1],0.f)+1e-4f,
                      fmaxf(mo[2],0.f)+1e-4f, fmaxf(mo[3],0.f)+1e-4f);
  o4[NN + n] = make_float4(dv[0], dv[1], dv[2], dv[3]);
}

extern "C" void kernel_launch(void* const* d_in, const int* in_sizes, int n_in,
                              void* d_out, int out_size, void* d_ws, size_t ws_size,
                              hipStream_t stream){
  const float* x    = (const float*)d_in[0];
  const int*   eidx = (const int*)d_in[1];
  const float* ew   = (const float*)d_in[2];
  const float* Wg1  = (const float*)d_in[3];
  const float* bg1  = (const float*)d_in[4];
  const float* Wg2  = (const float*)d_in[5];
  const float* bg2  = (const float*)d_in[6];
  const float* lng  = (const float*)d_in[7];
  const float* lnb  = (const float*)d_in[8];
  const float* Wih0 = (const float*)d_in[9];
  const float* Whh0 = (const float*)d_in[10];
  const float* bih0 = (const float*)d_in[11];
  const float* bhh0 = (const float*)d_in[12];
  const float* Wih1 = (const float*)d_in[13];
  const float* Whh1 = (const float*)d_in[14];
  const float* bih1 = (const float*)d_in[15];
  const float* bhh1 = (const float*)d_in[16];
  const float* Wm1  = (const float*)d_in[17];
  const float* bm1  = (const float*)d_in[18];
  const float* Wm2  = (const float*)d_in[19];
  const float* bm2  = (const float*)d_in[20];
  const float* Wd1  = (const float*)d_in[21];
  const float* bd1  = (const float*)d_in[22];
  const float* Wd2  = (const float*)d_in[23];
  const float* bd2  = (const float*)d_in[24];
  const int* src = eidx;
  const int* dst = eidx + EE;
  float* out = (float*)d_out;

  char* p = (char*)d_ws;
  auto alloc = [&](size_t bytes)->char*{ char* r = p; p += (bytes + 255) & ~(size_t)255; return r; };
  float*  deg     = (float*)alloc((size_t)NN*4);       // becomes dinv
  int*    counts  = (int*)  alloc((size_t)NN*4);
  int*    rowptr  = (int*)  alloc((size_t)(NN+1)*4);
  int*    cursor  = (int*)  alloc((size_t)NN*4);
  int*    locincl = (int*)  alloc((size_t)NN*4);
  int*    bsum    = (int*)  alloc((size_t)256*4);
  int*    boff    = (int*)  alloc((size_t)256*4);
  uint2*  e2      = (uint2*)alloc((size_t)EE*8);
  uint4*  WF      = (uint4*)alloc((size_t)2*4096*16);
  uint4*  WG2F    = (uint4*)alloc((size_t)512*16);
  float*  BS      = (float*)alloc((size_t)2*256*4);
  ushort* xb      = (ushort*)alloc((size_t)NN*49*2);
  ushort* h1b     = (ushort*)alloc((size_t)NP*64*2);
  ushort* XT      = (ushort*)alloc((size_t)TT*NP*64*2);
  float*  AX      = (float*)alloc((size_t)NN*49*4);
  ushort* Z2p     = (ushort*)alloc((size_t)NN*64*8*2);

  int xblocks = (NN*49 + 255)/256;                 // 9571
  k_prep_all<<<232 + xblocks, 256, 0, stream>>>(Wih0, Whh0, Wih1, Whh1, Wg2,
      bih0, bhh0, bih1, bhh1, x, WF, WG2F, BS, xb, deg, counts);
  k_edge_count<<<(EE+255)/256, 256, 0, stream>>>(src, dst, ew, deg, counts);
  k_scan_blk<<<196, 256, 0, stream>>>(counts, locincl, bsum, deg);
  k_scan_top<<<1, 256, 0, stream>>>(bsum, boff);
  k_scan_fix<<<196, 256, 0, stream>>>(locincl, boff, counts, rowptr, cursor);
  k_scatter<<<(EE+255)/256, 256, 0, stream>>>(src, dst, ew, deg, cursor, e2);
  k_agg_x<<<NN/4, 256, 0, stream>>>(xb, deg, rowptr, e2, AX);
  k_gcn2_mfma<<<NN/8, 256, 0, stream>>>(AX, Wg1, bg1, WG2F, Z2p);
  k_agg_ln_all<<<NN/4, 256, 0, stream>>>(Z2p, deg, rowptr, e2, bg2, lng, lnb, XT);
  k_lstm_both<<<NP/16, 256, 0, stream>>>(XT, h1b, WF, BS);
  k_heads<<<(NN+255)/256, 256, 0, stream>>>(h1b, Wm1, bm1, Wm2, bm2, Wd1, bd1, Wd2, bd2, out);
}

// Round 9
// 405.333 us; speedup vs baseline: 2.6691x; 1.0085x over previous
//
#include <hip/hip_runtime.h>
#include <stdint.h>

#define NN 50000
#define NP 50048          // padded to 64 for the MFMA LSTM kernel
#define EE 400000
#define TT 7
#define LN_EPS 1e-5f
#define SIG_SC (-1.4426950408889634f)   // -log2(e): sigmoid prescale
#define TANH_SC (2.8853900817779268f)   // +2*log2(e): tanh prescale

typedef __attribute__((ext_vector_type(8))) short bf16x8;
typedef __attribute__((ext_vector_type(4))) float f32x4;

__device__ __forceinline__ float leaky01(float x){ return x > 0.f ? x : 0.01f*x; }
__device__ __forceinline__ float fastrcp(float x){ return __builtin_amdgcn_rcpf(x); }
__device__ __forceinline__ float exp2fast(float x){ return __builtin_amdgcn_exp2f(x); }
__device__ __forceinline__ unsigned bf16rne(float f){
  unsigned u = __float_as_uint(f);
  return (u + 0x7fffu + ((u>>16)&1u)) >> 16;
}
__device__ __forceinline__ float bfu(unsigned u){ return __uint_as_float(u<<16); }
__device__ __forceinline__ float bfhi(unsigned u){ return __uint_as_float(u & 0xffff0000u); }

// ---------------- one-shot prep: weight packing + inits + x->bf16 ----------------
// LSTM weights/biases PRE-SCALED: i/f/o rows * SIG_SC, g rows * TANH_SC so the
// epilogue is pure rcp(1+exp2(y)) forms.
__global__ __launch_bounds__(256) void k_prep_all(
    const float* __restrict__ Wih0, const float* __restrict__ Whh0,
    const float* __restrict__ Wih1, const float* __restrict__ Whh1,
    const float* __restrict__ Wg2,
    const float* __restrict__ bih0, const float* __restrict__ bhh0,
    const float* __restrict__ bih1, const float* __restrict__ bhh1,
    const float* __restrict__ x,
    uint4* __restrict__ WF, uint4* __restrict__ WG2F, float* __restrict__ BS,
    ushort* __restrict__ xb, float* __restrict__ deg, int* __restrict__ counts){
  int b = blockIdx.x, tid = threadIdx.x;
  if (b < 32){
    int idx = b*256 + tid;
    int L = idx >> 12;
    int r = idx & 4095;
    int lane = r & 63;
    int e = r >> 6;
    int which = e & 1;
    int cs = e >> 1;
    int s = cs & 1, ct = cs >> 1;
    int row = ct*16 + (lane & 15);
    float sc = ((row >> 6) == 2) ? TANH_SC : SIG_SC;
    int kb = s*32 + (lane >> 4)*8;
    const float* W = L ? (which ? Whh1 : Wih1) : (which ? Whh0 : Wih0);
    const float* p = W + row*64 + kb;
    uint4 v;
    v.x = bf16rne(sc*p[0]) | (bf16rne(sc*p[1])<<16);
    v.y = bf16rne(sc*p[2]) | (bf16rne(sc*p[3])<<16);
    v.z = bf16rne(sc*p[4]) | (bf16rne(sc*p[5])<<16);
    v.w = bf16rne(sc*p[6]) | (bf16rne(sc*p[7])<<16);
    WF[idx] = v;
  } else if (b < 34){
    int idx = (b-32)*256 + tid;   // 0..511
    int lane = idx & 63, e = idx >> 6;   // e = ct*2+s
    int s = e & 1, ct = e >> 1;
    int kb = s*32 + (lane>>4)*8;
    int c = ct*16 + (lane&15);
    uint4 v;
    v.x = bf16rne(Wg2[(kb+0)*64+c]) | (bf16rne(Wg2[(kb+1)*64+c])<<16);
    v.y = bf16rne(Wg2[(kb+2)*64+c]) | (bf16rne(Wg2[(kb+3)*64+c])<<16);
    v.z = bf16rne(Wg2[(kb+4)*64+c]) | (bf16rne(Wg2[(kb+5)*64+c])<<16);
    v.w = bf16rne(Wg2[(kb+6)*64+c]) | (bf16rne(Wg2[(kb+7)*64+c])<<16);
    WG2F[idx] = v;
  } else if (b < 36){
    int L = b - 34;
    float sc = ((tid >> 6) == 2) ? TANH_SC : SIG_SC;
    BS[L*256+tid] = sc * (L ? (bih1[tid]+bhh1[tid]) : (bih0[tid]+bhh0[tid]));
  } else if (b < 232){
    int i = (b-36)*256 + tid;
    if (i < NN){ deg[i] = 1.0f; counts[i] = 0; }
  } else {
    int i = (b-232)*256 + tid;
    if (i < NN*49) xb[i] = (ushort)bf16rne(x[i]);
  }
}

// ---------------- graph norm / CSR build ----------------
__global__ void k_edge_count(const int* __restrict__ src, const int* __restrict__ dst,
                             const float* __restrict__ ew, float* deg, int* counts){
  int e = blockIdx.x*blockDim.x + threadIdx.x;
  if (e < EE){
    int d = dst[e];
    atomicAdd(&deg[d], ew[e]);
    atomicAdd(&counts[d], 1);
  }
}
__global__ __launch_bounds__(256) void k_scan_blk(const int* __restrict__ counts,
                                                  int* locincl, int* bsum, float* deg){
  int tid = threadIdx.x; int i = blockIdx.x*256 + tid;
  if (i < NN) deg[i] = rsqrtf(deg[i]);      // deg >= 1 always
  int v = (i < NN) ? counts[i] : 0;
  int lane = tid & 63;
  int val = v;
  #pragma unroll
  for (int off = 1; off < 64; off <<= 1){
    int u = __shfl_up(val, off, 64);
    if (lane >= off) val += u;
  }
  __shared__ int wsum[4];
  if (lane == 63) wsum[tid>>6] = val;
  __syncthreads();
  int w = tid >> 6, pre = 0;
  #pragma unroll
  for (int k = 0; k < 4; ++k) if (k < w) pre += wsum[k];
  int incl = val + pre;
  if (i < NN) locincl[i] = incl;
  if (tid == 255) bsum[blockIdx.x] = incl;
}
__global__ __launch_bounds__(256) void k_scan_top(const int* __restrict__ bsum, int* boff){
  int tid = threadIdx.x;
  int v = (tid < 196) ? bsum[tid] : 0;
  int lane = tid & 63;
  int val = v;
  #pragma unroll
  for (int off = 1; off < 64; off <<= 1){
    int u = __shfl_up(val, off, 64);
    if (lane >= off) val += u;
  }
  __shared__ int wsum[4];
  if (lane == 63) wsum[tid>>6] = val;
  __syncthreads();
  int w = tid >> 6, pre = 0;
  #pragma unroll
  for (int k = 0; k < 4; ++k) if (k < w) pre += wsum[k];
  if (tid < 196) boff[tid] = val + pre - v;   // exclusive prefix
}
__global__ __launch_bounds__(256) void k_scan_fix(const int* __restrict__ locincl,
        const int* __restrict__ boff, const int* __restrict__ counts,
        int* rowptr, int* cursor){
  int i = blockIdx.x*256 + threadIdx.x;
  if (i < NN){
    int r = locincl[i] + boff[blockIdx.x];
    rowptr[i+1] = r;
    cursor[i] = r - counts[i];
  }
  if (i == 0) rowptr[0] = 0;
}
__global__ void k_scatter(const int* __restrict__ src, const int* __restrict__ dst,
                          const float* __restrict__ ew, const float* __restrict__ dinv,
                          int* cursor, uint2* e2){
  int e = blockIdx.x*blockDim.x + threadIdx.x;
  if (e < EE){
    int s = src[e], d = dst[e];
    float nv = dinv[s]*ew[e]*dinv[d];
    int slot = atomicAdd(&cursor[d], 1);
    e2[slot] = make_uint2((uint)s, __float_as_uint(nv));
  }
}

// ---------------- GCN ----------------
__global__ __launch_bounds__(256) void k_agg_x(const ushort* __restrict__ xb,
        const float* __restrict__ dinv, const int* __restrict__ rowptr,
        const uint2* __restrict__ e2, float* __restrict__ AX){
  int lane = threadIdx.x & 63, w = threadIdx.x >> 6;
  int i = blockIdx.x*4 + w;
  int beg = rowptr[i], end = rowptr[i+1];
  float di = dinv[i];
  float acc = 0.f;
  if (lane < 49) acc = di*di*bfu(xb[(size_t)i*49 + lane]);
  for (int s = beg; s < end; ++s){
    uint2 e = e2[s];
    int cs = (int)e.x; float wv = __uint_as_float(e.y);
    if (lane < 49) acc += wv * bfu(xb[(size_t)cs*49 + lane]);
  }
  if (lane < 49) AX[(size_t)i*49 + lane] = acc;
}
__global__ __launch_bounds__(256) void k_gcn2_mfma(const float* __restrict__ AX,
        const float* __restrict__ Wg1, const float* __restrict__ bg1,
        const uint4* __restrict__ WG2F, ushort* __restrict__ Z2p){
  __shared__ float sw1[448];
  __shared__ float sb1[64];
  __shared__ float sax[8*56];
  __shared__ __align__(16) ushort srb[64*68];
  int tid = threadIdx.x;
  int lane = tid & 63, w = tid >> 6;
  bf16x8 bw[4][2];
  #pragma unroll
  for (int ct = 0; ct < 4; ++ct)
    #pragma unroll
    for (int s = 0; s < 2; ++s){
      uint4 v = WG2F[(ct*2+s)*64 + lane];
      bw[ct][s] = *(bf16x8*)&v;
    }
  for (int i = tid; i < 448; i += 256) sw1[i] = Wg1[i];
  if (tid < 64) sb1[tid] = bg1[tid];
  int nbase = blockIdx.x*8;
  for (int i = tid; i < 448; i += 256){
    int n = i/56, c = i%56;
    sax[i] = (c < 49) ? AX[(size_t)(nbase+n)*49 + c] : 0.f;
  }
  __syncthreads();
  {
    int node = lane >> 3, t = lane & 7;
    float a[7];
    #pragma unroll
    for (int kk = 0; kk < 7; ++kk) a[kk] = sax[node*56 + t*7 + kk];
    ushort hv[16];
    #pragma unroll
    for (int j = 0; j < 16; ++j){
      int k = w*16 + j;
      float acc = sb1[k];
      #pragma unroll
      for (int kk = 0; kk < 7; ++kk) acc += a[kk]*sw1[kk*64+k];
      hv[j] = (ushort)bf16rne(leaky01(acc));
    }
    uint2* dst = (uint2*)&srb[lane*68 + w*16];
    #pragma unroll
    for (int q = 0; q < 4; ++q){
      uint2 v;
      v.x = (uint)hv[q*4+0] | ((uint)hv[q*4+1]<<16);
      v.y = (uint)hv[q*4+2] | ((uint)hv[q*4+3]<<16);
      dst[q] = v;
    }
  }
  __syncthreads();
  int col = lane & 15, quad = lane >> 4;
  bf16x8 afr[2];
  #pragma unroll
  for (int s = 0; s < 2; ++s){
    const ushort* pr = &srb[(w*16 + col)*68 + s*32 + quad*8];
    uint2 lo = *(const uint2*)pr;
    uint2 hi = *(const uint2*)(pr + 4);
    union { uint u[4]; bf16x8 b; } cv;
    cv.u[0]=lo.x; cv.u[1]=lo.y; cv.u[2]=hi.x; cv.u[3]=hi.y;
    afr[s] = cv.b;
  }
  f32x4 acc[4];
  #pragma unroll
  for (int ct = 0; ct < 4; ++ct) acc[ct] = (f32x4){0.f,0.f,0.f,0.f};
  #pragma unroll
  for (int ct = 0; ct < 4; ++ct)
    #pragma unroll
    for (int s = 0; s < 2; ++s)
      acc[ct] = __builtin_amdgcn_mfma_f32_16x16x32_bf16(afr[s], bw[ct][s], acc[ct], 0,0,0);
  int node = nbase + w*2 + (quad>>1);
  #pragma unroll
  for (int ct = 0; ct < 4; ++ct){
    uint2 v;
    v.x = bf16rne(acc[ct][0]) | (bf16rne(acc[ct][1])<<16);
    v.y = bf16rne(acc[ct][2]) | (bf16rne(acc[ct][3])<<16);
    size_t o = ((size_t)node*64 + ct*16 + col)*8 + (quad&1)*4;
    *(uint2*)(Z2p + o) = v;
  }
}
__global__ __launch_bounds__(256) void k_agg_ln_all(const ushort* __restrict__ Z2p,
        const float* __restrict__ dinv, const int* __restrict__ rowptr,
        const uint2* __restrict__ e2,
        const float* __restrict__ bg2, const float* __restrict__ lng,
        const float* __restrict__ lnb, ushort* __restrict__ XT){
  int lane = threadIdx.x & 63, w = threadIdx.x >> 6;
  int i = blockIdx.x*4 + w;
  int beg = rowptr[i], end = rowptr[i+1];
  float di = dinv[i];
  float swt = di*di;
  const uint4* zp = (const uint4*)Z2p;
  float acc[7];
  {
    uint4 v = zp[(size_t)i*64 + lane];
    acc[0] = swt*bfu(v.x); acc[1] = swt*bfhi(v.x);
    acc[2] = swt*bfu(v.y); acc[3] = swt*bfhi(v.y);
    acc[4] = swt*bfu(v.z); acc[5] = swt*bfhi(v.z);
    acc[6] = swt*bfu(v.w);
  }
  for (int s = beg; s < end; ++s){
    uint2 e = e2[s];
    int cs = (int)e.x; float wv = __uint_as_float(e.y);
    uint4 v = zp[(size_t)cs*64 + lane];
    acc[0] = fmaf(wv, bfu(v.x),  acc[0]);
    acc[1] = fmaf(wv, bfhi(v.x), acc[1]);
    acc[2] = fmaf(wv, bfu(v.y),  acc[2]);
    acc[3] = fmaf(wv, bfhi(v.y), acc[3]);
    acc[4] = fmaf(wv, bfu(v.z),  acc[4]);
    acc[5] = fmaf(wv, bfhi(v.z), acc[5]);
    acc[6] = fmaf(wv, bfu(v.w),  acc[6]);
  }
  float b2 = bg2[lane], gl = lng[lane], bl = lnb[lane];
  #pragma unroll
  for (int t = 0; t < 7; ++t){
    float a = leaky01(acc[t] + b2);
    float sum = a;
    #pragma unroll
    for (int off = 32; off >= 1; off >>= 1) sum += __shfl_xor(sum, off, 64);
    float mu = sum * (1.f/64.f);
    float d = a - mu;
    float vs = d*d;
    #pragma unroll
    for (int off = 32; off >= 1; off >>= 1) vs += __shfl_xor(vs, off, 64);
    float rs = rsqrtf(vs*(1.f/64.f) + LN_EPS);
    XT[(size_t)t*NP*64 + (size_t)i*64 + lane] = (ushort)bf16rne(d*rs*gl + bl);
  }
}

// ---------------- LSTM (both layers) + heads, fused ----------------
// 16 nodes/block, 4 waves split gate-column tiles. Layer-0 h planes in LDS,
// layer-1 consumes in place; heads computed from XL[6] at the end (no h1 round-trip).
// L0 needs only ONE barrier per t (plane t has no prior readers).
__global__ __launch_bounds__(256) void k_lstm_heads(const ushort* __restrict__ xin,
        const uint4* __restrict__ WF, const float* __restrict__ BS,
        const float* __restrict__ Wm1, const float* __restrict__ bm1,
        const float* __restrict__ Wm2, const float* __restrict__ bm2,
        const float* __restrict__ Wd1, const float* __restrict__ bd1,
        const float* __restrict__ Wd2, const float* __restrict__ bd2,
        float* __restrict__ out){
  __shared__ __align__(16) ushort XL[7][16][72];   // 15.75 KB
  __shared__ float swm1[2048];
  __shared__ float swd1[1024];
  __shared__ float swm2[128];
  __shared__ float swd2[64];
  __shared__ float sbm1[32], sbd1[16], sbm2[4], sbd2[4];
  __shared__ float sm1[16][33];
  __shared__ float sd1[16][17];
  int tid = threadIdx.x;
  int lane = tid & 63, cp = tid >> 6;
  int base = blockIdx.x*16;
  int col = lane & 15, quad = lane >> 4;
  // stage head weights (read-once, L2-broadcast across blocks); consumed after
  // >=21 barriers so no explicit sync needed here.
  for (int i = tid; i < 2048; i += 256) swm1[i] = Wm1[i];
  for (int i = tid; i < 1024; i += 256) swd1[i] = Wd1[i];
  if (tid < 128) swm2[tid] = Wm2[tid];
  if (tid < 64) swd2[tid] = Wd2[tid];
  if (tid < 32) sbm1[tid] = bm1[tid];
  if (tid < 16) sbd1[tid] = bd1[tid];
  if (tid < 4){ sbm2[tid] = bm2[tid]; sbd2[tid] = bd2[tid]; }

  for (int L = 0; L < 2; ++L){
    bf16x8 bwi[4][2], bwh[4][2];
    const uint4* wf = WF + L*4096;
    #pragma unroll
    for (int g = 0; g < 4; ++g){
      int ct = cp + 4*g;
      #pragma unroll
      for (int s = 0; s < 2; ++s){
        uint4 wi = wf[((ct*2+s)*2+0)*64 + lane];
        uint4 wh = wf[((ct*2+s)*2+1)*64 + lane];
        bwi[g][s] = *(bf16x8*)&wi;
        bwh[g][s] = *(bf16x8*)&wh;
      }
    }
    float bias[4];
    #pragma unroll
    for (int g = 0; g < 4; ++g) bias[g] = BS[L*256 + (cp + 4*g)*16 + col];
    f32x4 cst = (f32x4){0.f,0.f,0.f,0.f};
    bf16x8 hfr[2];
    hfr[0] = (bf16x8){0,0,0,0,0,0,0,0};
    hfr[1] = (bf16x8){0,0,0,0,0,0,0,0};

    for (int t = 0; t < 7; ++t){
      bf16x8 ax[2];
      if (L == 0){
        #pragma unroll
        for (int s = 0; s < 2; ++s)
          ax[s] = *(const bf16x8*)(xin + (size_t)t*NP*64
                          + (size_t)(base + col)*64 + s*32 + quad*8);
      } else {
        #pragma unroll
        for (int s = 0; s < 2; ++s)
          ax[s] = *(const bf16x8*)&XL[t][col][s*32 + quad*8];
      }
      f32x4 acc[4];
      #pragma unroll
      for (int g = 0; g < 4; ++g){
        float b = bias[g];
        acc[g] = (f32x4){b,b,b,b};
      }
      #pragma unroll
      for (int g = 0; g < 4; ++g){
        #pragma unroll
        for (int s = 0; s < 2; ++s){
          acc[g] = __builtin_amdgcn_mfma_f32_16x16x32_bf16(ax[s], bwi[g][s], acc[g], 0,0,0);
          acc[g] = __builtin_amdgcn_mfma_f32_16x16x32_bf16(hfr[s], bwh[g][s], acc[g], 0,0,0);
        }
      }
      if (L) __syncthreads();   // L1 only: all reads of plane t done before overwrite
      #pragma unroll
      for (int r = 0; r < 4; ++r){
        float ig = fastrcp(1.f + exp2fast(acc[0][r]));
        float fg = fastrcp(1.f + exp2fast(acc[1][r]));
        float gg = fmaf(-2.f, fastrcp(1.f + exp2fast(acc[2][r])), 1.f);
        float og = fastrcp(1.f + exp2fast(acc[3][r]));
        float cn = fmaf(fg, cst[r], ig*gg);
        cst[r] = cn;
        float tc = fmaf(-2.f, fastrcp(1.f + exp2fast(TANH_SC*cn)), 1.f);
        XL[t][quad*4 + r][cp*16 + col] = (ushort)bf16rne(og*tc);
      }
      __syncthreads();
      hfr[0] = *(const bf16x8*)&XL[t][col][quad*8];
      hfr[1] = *(const bf16x8*)&XL[t][col][32 + quad*8];
    }
  }
  // ---- heads from XL[6] (= layer-1 h at t=6) ----
  int node = tid >> 4, sub = tid & 15;
  int gn = base + node;
  float m1a = sbm1[sub], m1b = sbm1[sub+16], d1v = sbd1[sub];
  #pragma unroll 8
  for (int k = 0; k < 64; ++k){
    float fv = bfu(XL[6][node][k]);
    m1a = fmaf(fv, swm1[k*32 + sub], m1a);
    m1b = fmaf(fv, swm1[k*32 + sub + 16], m1b);
    d1v = fmaf(fv, swd1[k*16 + sub], d1v);
  }
  sm1[node][sub] = leaky01(m1a);
  sm1[node][sub+16] = leaky01(m1b);
  sd1[node][sub] = fmaxf(d1v, 0.f);
  __syncthreads();
  if (sub < 4 && gn < NN){
    float mo = sbm2[sub];
    #pragma unroll 8
    for (int c = 0; c < 32; ++c) mo = fmaf(sm1[node][c], swm2[c*4+sub], mo);
    float dv = sbd2[sub];
    #pragma unroll 8
    for (int c = 0; c < 16; ++c) dv = fmaf(sd1[node][c], swd2[c*4+sub], dv);
    out[(size_t)gn*4 + sub] = fmaxf(mo, 0.f) + 1e-4f;
    out[(size_t)NN*4 + (size_t)gn*4 + sub] = dv;
  }
}

extern "C" void kernel_launch(void* const* d_in, const int* in_sizes, int n_in,
                              void* d_out, int out_size, void* d_ws, size_t ws_size,
                              hipStream_t stream){
  const float* x    = (const float*)d_in[0];
  const int*   eidx = (const int*)d_in[1];
  const float* ew   = (const float*)d_in[2];
  const float* Wg1  = (const float*)d_in[3];
  const float* bg1  = (const float*)d_in[4];
  const float* Wg2  = (const float*)d_in[5];
  const float* bg2  = (const float*)d_in[6];
  const float* lng  = (const float*)d_in[7];
  const float* lnb  = (const float*)d_in[8];
  const float* Wih0 = (const float*)d_in[9];
  const float* Whh0 = (const float*)d_in[10];
  const float* bih0 = (const float*)d_in[11];
  const float* bhh0 = (const float*)d_in[12];
  const float* Wih1 = (const float*)d_in[13];
  const float* Whh1 = (const float*)d_in[14];
  const float* bih1 = (const float*)d_in[15];
  const float* bhh1 = (const float*)d_in[16];
  const float* Wm1  = (const float*)d_in[17];
  const float* bm1  = (const float*)d_in[18];
  const float* Wm2  = (const float*)d_in[19];
  const float* bm2  = (const float*)d_in[20];
  const float* Wd1  = (const float*)d_in[21];
  const float* bd1  = (const float*)d_in[22];
  const float* Wd2  = (const float*)d_in[23];
  const float* bd2  = (const float*)d_in[24];
  const int* src = eidx;
  const int* dst = eidx + EE;
  float* out = (float*)d_out;

  char* p = (char*)d_ws;
  auto alloc = [&](size_t bytes)->char*{ char* r = p; p += (bytes + 255) & ~(size_t)255; return r; };
  float*  deg     = (float*)alloc((size_t)NN*4);       // becomes dinv
  int*    counts  = (int*)  alloc((size_t)NN*4);
  int*    rowptr  = (int*)  alloc((size_t)(NN+1)*4);
  int*    cursor  = (int*)  alloc((size_t)NN*4);
  int*    locincl = (int*)  alloc((size_t)NN*4);
  int*    bsum    = (int*)  alloc((size_t)256*4);
  int*    boff    = (int*)  alloc((size_t)256*4);
  uint2*  e2      = (uint2*)alloc((size_t)EE*8);
  uint4*  WF      = (uint4*)alloc((size_t)2*4096*16);
  uint4*  WG2F    = (uint4*)alloc((size_t)512*16);
  float*  BS      = (float*)alloc((size_t)2*256*4);
  ushort* xb      = (ushort*)alloc((size_t)NN*49*2);
  ushort* XT      = (ushort*)alloc((size_t)TT*NP*64*2);
  float*  AX      = (float*)alloc((size_t)NN*49*4);
  ushort* Z2p     = (ushort*)alloc((size_t)NN*64*8*2);

  int xblocks = (NN*49 + 255)/256;                 // 9571
  k_prep_all<<<232 + xblocks, 256, 0, stream>>>(Wih0, Whh0, Wih1, Whh1, Wg2,
      bih0, bhh0, bih1, bhh1, x, WF, WG2F, BS, xb, deg, counts);
  k_edge_count<<<(EE+255)/256, 256, 0, stream>>>(src, dst, ew, deg, counts);
  k_scan_blk<<<196, 256, 0, stream>>>(counts, locincl, bsum, deg);
  k_scan_top<<<1, 256, 0, stream>>>(bsum, boff);
  k_scan_fix<<<196, 256, 0, stream>>>(locincl, boff, counts, rowptr, cursor);
  k_scatter<<<(EE+255)/256, 256, 0, stream>>>(src, dst, ew, deg, cursor, e2);
  k_agg_x<<<NN/4, 256, 0, stream>>>(xb, deg, rowptr, e2, AX);
  k_gcn2_mfma<<<NN/8, 256, 0, stream>>>(AX, Wg1, bg1, WG2F, Z2p);
  k_agg_ln_all<<<NN/4, 256, 0, stream>>>(Z2p, deg, rowptr, e2, bg2, lng, lnb, XT);
  k_lstm_heads<<<NP/16, 256, 0, stream>>>(XT, WF, BS,
      Wm1, bm1, Wm2, bm2, Wd1, bd1, Wd2, bd2, out);
}

// Round 10
// 399.747 us; speedup vs baseline: 2.7064x; 1.0140x over previous
//
#include <hip/hip_runtime.h>
#include <stdint.h>

#define NN 50000
#define NP 50048          // padded to 64 for the MFMA LSTM kernel
#define EE 400000
#define TT 7
#define LN_EPS 1e-5f
#define SIG_SC (-1.4426950408889634f)   // -log2(e): sigmoid prescale
#define TANH_SC (2.8853900817779268f)   // +2*log2(e): tanh prescale

typedef __attribute__((ext_vector_type(8))) short bf16x8;
typedef __attribute__((ext_vector_type(4))) float f32x4;

__device__ __forceinline__ float leaky01(float x){ return x > 0.f ? x : 0.01f*x; }
__device__ __forceinline__ float fastrcp(float x){ return __builtin_amdgcn_rcpf(x); }
__device__ __forceinline__ float exp2fast(float x){ return __builtin_amdgcn_exp2f(x); }
__device__ __forceinline__ unsigned bf16rne(float f){
  unsigned u = __float_as_uint(f);
  return (u + 0x7fffu + ((u>>16)&1u)) >> 16;
}
__device__ __forceinline__ float bfu(unsigned u){ return __uint_as_float(u<<16); }
__device__ __forceinline__ float bfhi(unsigned u){ return __uint_as_float(u & 0xffff0000u); }

// ---------------- one-shot prep: weight packing + inits + x->bf16 ----------------
// LSTM weights/biases PRE-SCALED: i/f/o rows * SIG_SC, g rows * TANH_SC.
// Also packs [Wm1|Wd1] (64x48) into B-fragment order (WHF) for MFMA heads.
__global__ __launch_bounds__(256) void k_prep_all(
    const float* __restrict__ Wih0, const float* __restrict__ Whh0,
    const float* __restrict__ Wih1, const float* __restrict__ Whh1,
    const float* __restrict__ Wg2,
    const float* __restrict__ bih0, const float* __restrict__ bhh0,
    const float* __restrict__ bih1, const float* __restrict__ bhh1,
    const float* __restrict__ Wm1, const float* __restrict__ Wd1,
    const float* __restrict__ x,
    uint4* __restrict__ WF, uint4* __restrict__ WG2F, uint4* __restrict__ WHF,
    float* __restrict__ BS,
    ushort* __restrict__ xb, float* __restrict__ deg, int* __restrict__ counts){
  int b = blockIdx.x, tid = threadIdx.x;
  if (b < 32){
    int idx = b*256 + tid;
    int L = idx >> 12;
    int r = idx & 4095;
    int lane = r & 63;
    int e = r >> 6;
    int which = e & 1;
    int cs = e >> 1;
    int s = cs & 1, ct = cs >> 1;
    int row = ct*16 + (lane & 15);
    float sc = ((row >> 6) == 2) ? TANH_SC : SIG_SC;
    int kb = s*32 + (lane >> 4)*8;
    const float* W = L ? (which ? Whh1 : Wih1) : (which ? Whh0 : Wih0);
    const float* p = W + row*64 + kb;
    uint4 v;
    v.x = bf16rne(sc*p[0]) | (bf16rne(sc*p[1])<<16);
    v.y = bf16rne(sc*p[2]) | (bf16rne(sc*p[3])<<16);
    v.z = bf16rne(sc*p[4]) | (bf16rne(sc*p[5])<<16);
    v.w = bf16rne(sc*p[6]) | (bf16rne(sc*p[7])<<16);
    WF[idx] = v;
  } else if (b < 34){
    int idx = (b-32)*256 + tid;   // 0..511
    int lane = idx & 63, e = idx >> 6;   // e = ct*2+s
    int s = e & 1, ct = e >> 1;
    int kb = s*32 + (lane>>4)*8;
    int c = ct*16 + (lane&15);
    uint4 v;
    v.x = bf16rne(Wg2[(kb+0)*64+c]) | (bf16rne(Wg2[(kb+1)*64+c])<<16);
    v.y = bf16rne(Wg2[(kb+2)*64+c]) | (bf16rne(Wg2[(kb+3)*64+c])<<16);
    v.z = bf16rne(Wg2[(kb+4)*64+c]) | (bf16rne(Wg2[(kb+5)*64+c])<<16);
    v.w = bf16rne(Wg2[(kb+6)*64+c]) | (bf16rne(Wg2[(kb+7)*64+c])<<16);
    WG2F[idx] = v;
  } else if (b < 36){
    int L = b - 34;
    float sc = ((tid >> 6) == 2) ? TANH_SC : SIG_SC;
    BS[L*256+tid] = sc * (L ? (bih1[tid]+bhh1[tid]) : (bih0[tid]+bhh0[tid]));
  } else if (b < 38){
    int idx = (b-36)*256 + tid;   // 0..383 used
    if (idx < 384){
      int lane = idx & 63, e = idx >> 6;   // e = ct*2+s, ct in 0..2
      int s = e & 1, ct = e >> 1;
      int kb = s*32 + (lane>>4)*8;
      int c = ct*16 + (lane&15);
      float w[8];
      #pragma unroll
      for (int j = 0; j < 8; ++j)
        w[j] = (c < 32) ? Wm1[(kb+j)*32 + c] : Wd1[(kb+j)*16 + (c-32)];
      uint4 v;
      v.x = bf16rne(w[0]) | (bf16rne(w[1])<<16);
      v.y = bf16rne(w[2]) | (bf16rne(w[3])<<16);
      v.z = bf16rne(w[4]) | (bf16rne(w[5])<<16);
      v.w = bf16rne(w[6]) | (bf16rne(w[7])<<16);
      WHF[idx] = v;
    }
  } else if (b < 234){
    int i = (b-38)*256 + tid;
    if (i < NN){ deg[i] = 1.0f; counts[i] = 0; }
  } else {
    int i = (b-234)*256 + tid;
    if (i < NN*49) xb[i] = (ushort)bf16rne(x[i]);
  }
}

// ---------------- graph norm / CSR build ----------------
__global__ void k_edge_count(const int* __restrict__ src, const int* __restrict__ dst,
                             const float* __restrict__ ew, float* deg, int* counts){
  int e = blockIdx.x*blockDim.x + threadIdx.x;
  if (e < EE){
    int d = dst[e];
    atomicAdd(&deg[d], ew[e]);
    atomicAdd(&counts[d], 1);
  }
}
__global__ __launch_bounds__(256) void k_scan_blk(const int* __restrict__ counts,
                                                  int* locincl, int* bsum, float* deg){
  int tid = threadIdx.x; int i = blockIdx.x*256 + tid;
  if (i < NN) deg[i] = rsqrtf(deg[i]);      // deg >= 1 always
  int v = (i < NN) ? counts[i] : 0;
  int lane = tid & 63;
  int val = v;
  #pragma unroll
  for (int off = 1; off < 64; off <<= 1){
    int u = __shfl_up(val, off, 64);
    if (lane >= off) val += u;
  }
  __shared__ int wsum[4];
  if (lane == 63) wsum[tid>>6] = val;
  __syncthreads();
  int w = tid >> 6, pre = 0;
  #pragma unroll
  for (int k = 0; k < 4; ++k) if (k < w) pre += wsum[k];
  int incl = val + pre;
  if (i < NN) locincl[i] = incl;
  if (tid == 255) bsum[blockIdx.x] = incl;
}
__global__ __launch_bounds__(256) void k_scan_top(const int* __restrict__ bsum, int* boff){
  int tid = threadIdx.x;
  int v = (tid < 196) ? bsum[tid] : 0;
  int lane = tid & 63;
  int val = v;
  #pragma unroll
  for (int off = 1; off < 64; off <<= 1){
    int u = __shfl_up(val, off, 64);
    if (lane >= off) val += u;
  }
  __shared__ int wsum[4];
  if (lane == 63) wsum[tid>>6] = val;
  __syncthreads();
  int w = tid >> 6, pre = 0;
  #pragma unroll
  for (int k = 0; k < 4; ++k) if (k < w) pre += wsum[k];
  if (tid < 196) boff[tid] = val + pre - v;   // exclusive prefix
}
__global__ __launch_bounds__(256) void k_scan_fix(const int* __restrict__ locincl,
        const int* __restrict__ boff, const int* __restrict__ counts,
        int* rowptr, int* cursor){
  int i = blockIdx.x*256 + threadIdx.x;
  if (i < NN){
    int r = locincl[i] + boff[blockIdx.x];
    rowptr[i+1] = r;
    cursor[i] = r - counts[i];
  }
  if (i == 0) rowptr[0] = 0;
}
__global__ void k_scatter(const int* __restrict__ src, const int* __restrict__ dst,
                          const float* __restrict__ ew, const float* __restrict__ dinv,
                          int* cursor, uint2* e2){
  int e = blockIdx.x*blockDim.x + threadIdx.x;
  if (e < EE){
    int s = src[e], d = dst[e];
    float nv = dinv[s]*ew[e]*dinv[d];
    int slot = atomicAdd(&cursor[d], 1);
    e2[slot] = make_uint2((uint)s, __float_as_uint(nv));
  }
}

// ---------------- GCN ----------------
__global__ __launch_bounds__(256) void k_agg_x(const ushort* __restrict__ xb,
        const float* __restrict__ dinv, const int* __restrict__ rowptr,
        const uint2* __restrict__ e2, float* __restrict__ AX){
  int lane = threadIdx.x & 63, w = threadIdx.x >> 6;
  int i = blockIdx.x*4 + w;
  int beg = rowptr[i], end = rowptr[i+1];
  float di = dinv[i];
  float acc = 0.f;
  if (lane < 49) acc = di*di*bfu(xb[(size_t)i*49 + lane]);
  for (int s = beg; s < end; ++s){
    uint2 e = e2[s];
    int cs = (int)e.x; float wv = __uint_as_float(e.y);
    if (lane < 49) acc += wv * bfu(xb[(size_t)cs*49 + lane]);
  }
  if (lane < 49) AX[(size_t)i*49 + lane] = acc;
}
__global__ __launch_bounds__(256) void k_gcn2_mfma(const float* __restrict__ AX,
        const float* __restrict__ Wg1, const float* __restrict__ bg1,
        const uint4* __restrict__ WG2F, ushort* __restrict__ Z2p){
  __shared__ float sw1[448];
  __shared__ float sb1[64];
  __shared__ float sax[8*56];
  __shared__ __align__(16) ushort srb[64*68];
  int tid = threadIdx.x;
  int lane = tid & 63, w = tid >> 6;
  bf16x8 bw[4][2];
  #pragma unroll
  for (int ct = 0; ct < 4; ++ct)
    #pragma unroll
    for (int s = 0; s < 2; ++s){
      uint4 v = WG2F[(ct*2+s)*64 + lane];
      bw[ct][s] = *(bf16x8*)&v;
    }
  for (int i = tid; i < 448; i += 256) sw1[i] = Wg1[i];
  if (tid < 64) sb1[tid] = bg1[tid];
  int nbase = blockIdx.x*8;
  for (int i = tid; i < 448; i += 256){
    int n = i/56, c = i%56;
    sax[i] = (c < 49) ? AX[(size_t)(nbase+n)*49 + c] : 0.f;
  }
  __syncthreads();
  {
    int node = lane >> 3, t = lane & 7;
    float a[7];
    #pragma unroll
    for (int kk = 0; kk < 7; ++kk) a[kk] = sax[node*56 + t*7 + kk];
    ushort hv[16];
    #pragma unroll
    for (int j = 0; j < 16; ++j){
      int k = w*16 + j;
      float acc = sb1[k];
      #pragma unroll
      for (int kk = 0; kk < 7; ++kk) acc += a[kk]*sw1[kk*64+k];
      hv[j] = (ushort)bf16rne(leaky01(acc));
    }
    uint2* dst = (uint2*)&srb[lane*68 + w*16];
    #pragma unroll
    for (int q = 0; q < 4; ++q){
      uint2 v;
      v.x = (uint)hv[q*4+0] | ((uint)hv[q*4+1]<<16);
      v.y = (uint)hv[q*4+2] | ((uint)hv[q*4+3]<<16);
      dst[q] = v;
    }
  }
  __syncthreads();
  int col = lane & 15, quad = lane >> 4;
  bf16x8 afr[2];
  #pragma unroll
  for (int s = 0; s < 2; ++s){
    const ushort* pr = &srb[(w*16 + col)*68 + s*32 + quad*8];
    uint2 lo = *(const uint2*)pr;
    uint2 hi = *(const uint2*)(pr + 4);
    union { uint u[4]; bf16x8 b; } cv;
    cv.u[0]=lo.x; cv.u[1]=lo.y; cv.u[2]=hi.x; cv.u[3]=hi.y;
    afr[s] = cv.b;
  }
  f32x4 acc[4];
  #pragma unroll
  for (int ct = 0; ct < 4; ++ct) acc[ct] = (f32x4){0.f,0.f,0.f,0.f};
  #pragma unroll
  for (int ct = 0; ct < 4; ++ct)
    #pragma unroll
    for (int s = 0; s < 2; ++s)
      acc[ct] = __builtin_amdgcn_mfma_f32_16x16x32_bf16(afr[s], bw[ct][s], acc[ct], 0,0,0);
  int node = nbase + w*2 + (quad>>1);
  #pragma unroll
  for (int ct = 0; ct < 4; ++ct){
    uint2 v;
    v.x = bf16rne(acc[ct][0]) | (bf16rne(acc[ct][1])<<16);
    v.y = bf16rne(acc[ct][2]) | (bf16rne(acc[ct][3])<<16);
    size_t o = ((size_t)node*64 + ct*16 + col)*8 + (quad&1)*4;
    *(uint2*)(Z2p + o) = v;
  }
}
__global__ __launch_bounds__(256) void k_agg_ln_all(const ushort* __restrict__ Z2p,
        const float* __restrict__ dinv, const int* __restrict__ rowptr,
        const uint2* __restrict__ e2,
        const float* __restrict__ bg2, const float* __restrict__ lng,
        const float* __restrict__ lnb, ushort* __restrict__ XT){
  int lane = threadIdx.x & 63, w = threadIdx.x >> 6;
  int i = blockIdx.x*4 + w;
  int beg = rowptr[i], end = rowptr[i+1];
  float di = dinv[i];
  float swt = di*di;
  const uint4* zp = (const uint4*)Z2p;
  float acc[7];
  {
    uint4 v = zp[(size_t)i*64 + lane];
    acc[0] = swt*bfu(v.x); acc[1] = swt*bfhi(v.x);
    acc[2] = swt*bfu(v.y); acc[3] = swt*bfhi(v.y);
    acc[4] = swt*bfu(v.z); acc[5] = swt*bfhi(v.z);
    acc[6] = swt*bfu(v.w);
  }
  for (int s = beg; s < end; ++s){
    uint2 e = e2[s];
    int cs = (int)e.x; float wv = __uint_as_float(e.y);
    uint4 v = zp[(size_t)cs*64 + lane];
    acc[0] = fmaf(wv, bfu(v.x),  acc[0]);
    acc[1] = fmaf(wv, bfhi(v.x), acc[1]);
    acc[2] = fmaf(wv, bfu(v.y),  acc[2]);
    acc[3] = fmaf(wv, bfhi(v.y), acc[3]);
    acc[4] = fmaf(wv, bfu(v.z),  acc[4]);
    acc[5] = fmaf(wv, bfhi(v.z), acc[5]);
    acc[6] = fmaf(wv, bfu(v.w),  acc[6]);
  }
  float b2 = bg2[lane], gl = lng[lane], bl = lnb[lane];
  #pragma unroll
  for (int t = 0; t < 7; ++t){
    float a = leaky01(acc[t] + b2);
    float sum = a;
    #pragma unroll
    for (int off = 32; off >= 1; off >>= 1) sum += __shfl_xor(sum, off, 64);
    float mu = sum * (1.f/64.f);
    float d = a - mu;
    float vs = d*d;
    #pragma unroll
    for (int off = 32; off >= 1; off >>= 1) vs += __shfl_xor(vs, off, 64);
    float rs = rsqrtf(vs*(1.f/64.f) + LN_EPS);
    XT[(size_t)t*NP*64 + (size_t)i*64 + lane] = (ushort)bf16rne(d*rs*gl + bl);
  }
}

// ---------------- LSTM (both layers) + MFMA heads, fused ----------------
// 16 nodes/block, 4 waves split gate-column tiles. Layer-0 h planes in LDS,
// layer-1 consumes in place. At the end, hfr = final h1 A-frags -> heads via
// 2 MFMAs/wave (waves 0-2) against pre-packed [Wm1|Wd1] B-frags; tiny 2nd
// layer via 16-lane shfl reduction. SH1 aliases dead XL planes 0-1.
__global__ __launch_bounds__(256) void k_lstm_heads(const ushort* __restrict__ xin,
        const uint4* __restrict__ WF, const float* __restrict__ BS,
        const uint4* __restrict__ WHF,
        const float* __restrict__ bm1, const float* __restrict__ bd1,
        const float* __restrict__ Wm2, const float* __restrict__ bm2,
        const float* __restrict__ Wd2, const float* __restrict__ bd2,
        float* __restrict__ out){
  __shared__ __align__(16) ushort XL[7][16][72];   // 15.75 KB
  int tid = threadIdx.x;
  int lane = tid & 63, cp = tid >> 6;
  int base = blockIdx.x*16;
  int col = lane & 15, quad = lane >> 4;
  bf16x8 hfr[2];
  hfr[0] = (bf16x8){0,0,0,0,0,0,0,0};
  hfr[1] = (bf16x8){0,0,0,0,0,0,0,0};

  for (int L = 0; L < 2; ++L){
    bf16x8 bwi[4][2], bwh[4][2];
    const uint4* wf = WF + L*4096;
    #pragma unroll
    for (int g = 0; g < 4; ++g){
      int ct = cp + 4*g;
      #pragma unroll
      for (int s = 0; s < 2; ++s){
        uint4 wi = wf[((ct*2+s)*2+0)*64 + lane];
        uint4 wh = wf[((ct*2+s)*2+1)*64 + lane];
        bwi[g][s] = *(bf16x8*)&wi;
        bwh[g][s] = *(bf16x8*)&wh;
      }
    }
    float bias[4];
    #pragma unroll
    for (int g = 0; g < 4; ++g) bias[g] = BS[L*256 + (cp + 4*g)*16 + col];
    f32x4 cst = (f32x4){0.f,0.f,0.f,0.f};
    if (L){
      hfr[0] = (bf16x8){0,0,0,0,0,0,0,0};
      hfr[1] = (bf16x8){0,0,0,0,0,0,0,0};
    }

    for (int t = 0; t < 7; ++t){
      bf16x8 ax[2];
      if (L == 0){
        #pragma unroll
        for (int s = 0; s < 2; ++s)
          ax[s] = *(const bf16x8*)(xin + (size_t)t*NP*64
                          + (size_t)(base + col)*64 + s*32 + quad*8);
      } else {
        #pragma unroll
        for (int s = 0; s < 2; ++s)
          ax[s] = *(const bf16x8*)&XL[t][col][s*32 + quad*8];
      }
      f32x4 acc[4];
      #pragma unroll
      for (int g = 0; g < 4; ++g){
        float b = bias[g];
        acc[g] = (f32x4){b,b,b,b};
      }
      #pragma unroll
      for (int g = 0; g < 4; ++g){
        #pragma unroll
        for (int s = 0; s < 2; ++s){
          acc[g] = __builtin_amdgcn_mfma_f32_16x16x32_bf16(ax[s], bwi[g][s], acc[g], 0,0,0);
          acc[g] = __builtin_amdgcn_mfma_f32_16x16x32_bf16(hfr[s], bwh[g][s], acc[g], 0,0,0);
        }
      }
      if (L) __syncthreads();   // L1 only: all reads of plane t done before overwrite
      #pragma unroll
      for (int r = 0; r < 4; ++r){
        float ig = fastrcp(1.f + exp2fast(acc[0][r]));
        float fg = fastrcp(1.f + exp2fast(acc[1][r]));
        float gg = fmaf(-2.f, fastrcp(1.f + exp2fast(acc[2][r])), 1.f);
        float og = fastrcp(1.f + exp2fast(acc[3][r]));
        float cn = fmaf(fg, cst[r], ig*gg);
        cst[r] = cn;
        float tc = fmaf(-2.f, fastrcp(1.f + exp2fast(TANH_SC*cn)), 1.f);
        XL[t][quad*4 + r][cp*16 + col] = (ushort)bf16rne(og*tc);
      }
      __syncthreads();
      hfr[0] = *(const bf16x8*)&XL[t][col][quad*8];
      hfr[1] = *(const bf16x8*)&XL[t][col][32 + quad*8];
    }
  }
  // ---- heads: hfr = final h1 A-frags. First layer (64->48) via MFMA. ----
  float* SH1 = (float*)&XL[0][0][0];   // planes 0-1 (4.6 KB) dead; [16][52] = 3.3 KB
  if (cp < 3){
    uint4 w0 = WHF[(cp*2+0)*64 + lane];
    uint4 w1 = WHF[(cp*2+1)*64 + lane];
    float hb = (cp < 2) ? bm1[cp*16+col] : bd1[col];
    f32x4 hacc = (f32x4){hb,hb,hb,hb};
    hacc = __builtin_amdgcn_mfma_f32_16x16x32_bf16(hfr[0], *(bf16x8*)&w0, hacc, 0,0,0);
    hacc = __builtin_amdgcn_mfma_f32_16x16x32_bf16(hfr[1], *(bf16x8*)&w1, hacc, 0,0,0);
    #pragma unroll
    for (int r = 0; r < 4; ++r){
      float v = hacc[r];
      v = (cp < 2) ? leaky01(v) : fmaxf(v, 0.f);
      SH1[(quad*4 + r)*52 + cp*16 + col] = v;
    }
  }
  __syncthreads();
  // ---- second layer: 16 threads/node, shfl-reduce over the 16-lane group ----
  int node = tid >> 4, sub = tid & 15;
  int gn = base + node;
  float m1a = SH1[node*52 + sub];
  float m1b = SH1[node*52 + 16 + sub];
  float d1v = SH1[node*52 + 32 + sub];
  float4 wa = *(const float4*)&Wm2[sub*4];
  float4 wb = *(const float4*)&Wm2[(sub+16)*4];
  float4 wc = *(const float4*)&Wd2[sub*4];
  float pm0 = m1a*wa.x + m1b*wb.x, pm1 = m1a*wa.y + m1b*wb.y;
  float pm2 = m1a*wa.z + m1b*wb.z, pm3 = m1a*wa.w + m1b*wb.w;
  float pd0 = d1v*wc.x, pd1 = d1v*wc.y, pd2 = d1v*wc.z, pd3 = d1v*wc.w;
  #pragma unroll
  for (int off = 1; off < 16; off <<= 1){
    pm0 += __shfl_xor(pm0, off, 16); pm1 += __shfl_xor(pm1, off, 16);
    pm2 += __shfl_xor(pm2, off, 16); pm3 += __shfl_xor(pm3, off, 16);
    pd0 += __shfl_xor(pd0, off, 16); pd1 += __shfl_xor(pd1, off, 16);
    pd2 += __shfl_xor(pd2, off, 16); pd3 += __shfl_xor(pd3, off, 16);
  }
  if (sub < 4 && gn < NN){
    float mo = (sub==0)?pm0:(sub==1)?pm1:(sub==2)?pm2:pm3;
    float dv = (sub==0)?pd0:(sub==1)?pd1:(sub==2)?pd2:pd3;
    mo += bm2[sub]; dv += bd2[sub];
    out[(size_t)gn*4 + sub] = fmaxf(mo, 0.f) + 1e-4f;
    out[(size_t)NN*4 + (size_t)gn*4 + sub] = dv;
  }
}

extern "C" void kernel_launch(void* const* d_in, const int* in_sizes, int n_in,
                              void* d_out, int out_size, void* d_ws, size_t ws_size,
                              hipStream_t stream){
  const float* x    = (const float*)d_in[0];
  const int*   eidx = (const int*)d_in[1];
  const float* ew   = (const float*)d_in[2];
  const float* Wg1  = (const float*)d_in[3];
  const float* bg1  = (const float*)d_in[4];
  const float* Wg2  = (const float*)d_in[5];
  const float* bg2  = (const float*)d_in[6];
  const float* lng  = (const float*)d_in[7];
  const float* lnb  = (const float*)d_in[8];
  const float* Wih0 = (const float*)d_in[9];
  const float* Whh0 = (const float*)d_in[10];
  const float* bih0 = (const float*)d_in[11];
  const float* bhh0 = (const float*)d_in[12];
  const float* Wih1 = (const float*)d_in[13];
  const float* Whh1 = (const float*)d_in[14];
  const float* bih1 = (const float*)d_in[15];
  const float* bhh1 = (const float*)d_in[16];
  const float* Wm1  = (const float*)d_in[17];
  const float* bm1  = (const float*)d_in[18];
  const float* Wm2  = (const float*)d_in[19];
  const float* bm2  = (const float*)d_in[20];
  const float* Wd1  = (const float*)d_in[21];
  const float* bd1  = (const float*)d_in[22];
  const float* Wd2  = (const float*)d_in[23];
  const float* bd2  = (const float*)d_in[24];
  const int* src = eidx;
  const int* dst = eidx + EE;
  float* out = (float*)d_out;

  char* p = (char*)d_ws;
  auto alloc = [&](size_t bytes)->char*{ char* r = p; p += (bytes + 255) & ~(size_t)255; return r; };
  float*  deg     = (float*)alloc((size_t)NN*4);       // becomes dinv
  int*    counts  = (int*)  alloc((size_t)NN*4);
  int*    rowptr  = (int*)  alloc((size_t)(NN+1)*4);
  int*    cursor  = (int*)  alloc((size_t)NN*4);
  int*    locincl = (int*)  alloc((size_t)NN*4);
  int*    bsum    = (int*)  alloc((size_t)256*4);
  int*    boff    = (int*)  alloc((size_t)256*4);
  uint2*  e2      = (uint2*)alloc((size_t)EE*8);
  uint4*  WF      = (uint4*)alloc((size_t)2*4096*16);
  uint4*  WG2F    = (uint4*)alloc((size_t)512*16);
  uint4*  WHF     = (uint4*)alloc((size_t)384*16);
  float*  BS      = (float*)alloc((size_t)2*256*4);
  ushort* xb      = (ushort*)alloc((size_t)NN*49*2);
  ushort* XT      = (ushort*)alloc((size_t)TT*NP*64*2);
  float*  AX      = (float*)alloc((size_t)NN*49*4);
  ushort* Z2p     = (ushort*)alloc((size_t)NN*64*8*2);

  int xblocks = (NN*49 + 255)/256;                 // 9571
  k_prep_all<<<234 + xblocks, 256, 0, stream>>>(Wih0, Whh0, Wih1, Whh1, Wg2,
      bih0, bhh0, bih1, bhh1, Wm1, Wd1, x, WF, WG2F, WHF, BS, xb, deg, counts);
  k_edge_count<<<(EE+255)/256, 256, 0, stream>>>(src, dst, ew, deg, counts);
  k_scan_blk<<<196, 256, 0, stream>>>(counts, locincl, bsum, deg);
  k_scan_top<<<1, 256, 0, stream>>>(bsum, boff);
  k_scan_fix<<<196, 256, 0, stream>>>(locincl, boff, counts, rowptr, cursor);
  k_scatter<<<(EE+255)/256, 256, 0, stream>>>(src, dst, ew, deg, cursor, e2);
  k_agg_x<<<NN/4, 256, 0, stream>>>(xb, deg, rowptr, e2, AX);
  k_gcn2_mfma<<<NN/8, 256, 0, stream>>>(AX, Wg1, bg1, WG2F, Z2p);
  k_agg_ln_all<<<NN/4, 256, 0, stream>>>(Z2p, deg, rowptr, e2, bg2, lng, lnb, XT);
  k_lstm_heads<<<NP/16, 256, 0, stream>>>(XT, WF, BS, WHF,
      bm1, bd1, Wm2, bm2, Wd2, bd2, out);
}